// Round 1
// 4027.578 us; speedup vs baseline: 1.4046x; 1.4046x over previous
//
#include <hip/hip_runtime.h>
#include <hip/hip_bf16.h>
#include <math.h>

using bf16 = __hip_bfloat16;
typedef __bf16 bf16x8 __attribute__((ext_vector_type(8)));
typedef float f32x4 __attribute__((ext_vector_type(4)));

#define B2F(x) __bfloat162float(x)
#define F2B(x) __float2bfloat16(x)

__device__ inline short f2bs(float x) { bf16 b = F2B(x); return *(short*)&b; }
__device__ inline float bs2f(short x) { bf16 b; *(short*)&b = x; return B2F(b); }

// Problem constants: B=8, L=2048, H=512, D_INNER=1024, NH=16, P=64, N=64
static constexpr int D_PROJ = 2192, CONV_DIM = 1152;
static constexpr int NCHUNK = 8, CLEN = 256;   // 8 chunks x 256 steps

// Workspace layout (bytes). y_f/y_b live in d_out (67.1 MB).
static constexpr size_t OFF_H    = 0;                    // 16384x512  bf16  16.8 MB
static constexpr size_t OFF_ZX   = 16777216;             // 16384x2192 bf16  71.8 MB (comb aliases)
static constexpr size_t OFF_XC   = 88604672;             // 16384x1152 bf16  37.7 MB (outbuf aliases)
static constexpr size_t OFF_S    = 126353408;            // 1024x4096  f32   16.8 MB
static constexpr size_t OFF_PT   = 143130624;            // 16384x16   f32    1.0 MB
static constexpr size_t OFF_PC   = 144179200;            // 1024       f32    4 KB
static constexpr size_t OFF_DTV  = 144183296;            // 16384x16   f32    1.0 MB
static constexpr size_t OFF_DAV  = 145231872;            // 16384x16   f32    1.0 MB
static constexpr size_t OFF_GIDX = 146280448;            // 16384      i32
static constexpr size_t OFF_POOL = 146345984;            // 8x1024     f32 (ends 146378752)
// bf16 weight cache (one-time conversion). Guarded by ws_size with full fallback.
static constexpr size_t OFF_WBF   = 146378752;
static constexpr size_t WBF_WIN   = 0;          // 8 x 2192x512 bf16 = 17,956,864
static constexpr size_t WBF_WOUT  = 17956864;   // 8 x 512x1024 bf16 =  8,388,608
static constexpr size_t WBF_BLK   = 26345472;   // 4 x 512x1024 bf16 =  4,194,304
static constexpr size_t WBF_ENC   = 30539776;   // 1024x512     bf16 =  1,048,576
static constexpr size_t WBF_BYTES = 31588352;

// ---------------------------------------------------------------------------
// f32 -> bf16 weight conversion (one-time per launch)
// ---------------------------------------------------------------------------
__global__ void k_wcvt(const float* __restrict__ src, bf16* __restrict__ dst, long n8)
{
    long i = (long)blockIdx.x * 256 + threadIdx.x;
    if (i >= n8) return;
    const float4* s = (const float4*)(src + i * 8);
    float4 f0 = s[0], f1 = s[1];
    short o[8];
    o[0] = f2bs(f0.x); o[1] = f2bs(f0.y); o[2] = f2bs(f0.z); o[3] = f2bs(f0.w);
    o[4] = f2bs(f1.x); o[5] = f2bs(f1.y); o[6] = f2bs(f1.z); o[7] = f2bs(f1.w);
    *(int4*)&dst[i * 8] = *(int4*)o;
}

// ---------------------------------------------------------------------------
// async global->LDS, 16B per lane (wave-uniform LDS base + lane*16 dest)
// ---------------------------------------------------------------------------
__device__ inline void gl_lds16(const void* g, void* l)
{
    __builtin_amdgcn_global_load_lds(
        (const __attribute__((address_space(1))) unsigned int*)g,
        (__attribute__((address_space(3))) unsigned int*)l,
        16, 0, 0);
}

// ---------------------------------------------------------------------------
// Fast MFMA GEMM (bf16 A, bf16 W): C[M,N] = A[M,K] @ W[N,K]^T + bias
// m97 structure: 128x128 tile, 4 waves, BK=64, global_load_lds width-16
// staging into linear LDS, XOR-swizzled (slot ^= row&7) on BOTH the global
// source address and the ds_read_b128 address -> conflict-free fragment reads.
// Epilogue stages C through LDS for full-256B-segment global writes.
// ---------------------------------------------------------------------------
template<bool CF32>
__global__ __launch_bounds__(256, 2)
void k_gemm_bf(const bf16* __restrict__ A, const int* __restrict__ gatherIdx,
               const bf16* __restrict__ Wb, const float* __restrict__ bias,
               void* __restrict__ Cp, int M, int N, int K, int ldc, int coff)
{
    __shared__ union UU {
        struct { __align__(16) short As[128 * 64]; __align__(16) short Bs[128 * 64]; } ab;
        __align__(16) short Cs2[128 * 136];                 // bf16 epilogue
        __align__(16) float Cs4[CF32 ? 128 * 132 : 4];      // f32 epilogue
    } u;

    const int tid  = threadIdx.x;
    const int m0   = blockIdx.y * 128;
    const int n0   = blockIdx.x * 128;
    const int wave = tid >> 6, lane = tid & 63;
    const int l15  = lane & 15, quad = lane >> 4;
    const int wm   = (wave & 1) * 64, wn = (wave >> 1) * 64;

    // staging: wave-instruction t covers 8 rows x 128B starting at row wave*32+t*8.
    // lane l -> LDS (row0 + l/8, slot l%8); its global source is slot^(row&7)
    // of its row, so LDS(row,s) holds global slot s^(row&7)  (inverse-swizzled src).
    const int sr   = lane >> 3;   // 0..7 sub-row within the 8-row chunk
    const int slot = lane & 7;    // 16B slot within row
    const bf16* asrc[4];
    const bf16* bsrc[4];
    int ldsoff[4];
#pragma unroll
    for (int t = 0; t < 4; ++t) {
        int row = wave * 32 + t * 8 + sr;            // 0..127
        long arow = m0 + row;
        if (gatherIdx) arow = gatherIdx[m0 + row];
        int sl = ((slot ^ (row & 7)) * 8);           // swizzled source col (elems)
        asrc[t] = A + arow * (long)K + sl;
        int wr = n0 + row; if (wr > N - 1) wr = N - 1;   // clamp; garbage cols never stored
        bsrc[t] = Wb + (long)wr * K + sl;
        ldsoff[t] = (wave * 32 + t * 8) * 64;        // shorts, wave-uniform
    }

    // fragment read offsets (shorts): row = frag row, col chunk = ks*32+quad*8,
    // swizzle-compensated: slot index (ks*4+quad) ^ (row&7), row&7 == l15&7.
    int aoff[2][4], boff[2][4];
#pragma unroll
    for (int ks = 0; ks < 2; ++ks) {
        int swz = (((ks << 2) | quad) ^ (l15 & 7)) * 8;
#pragma unroll
        for (int i = 0; i < 4; ++i) {
            aoff[ks][i] = (wm + i * 16 + l15) * 64 + swz;
            boff[ks][i] = (wn + i * 16 + l15) * 64 + swz;
        }
    }

    f32x4 acc[4][4];
#pragma unroll
    for (int i = 0; i < 4; ++i)
#pragma unroll
        for (int j = 0; j < 4; ++j) acc[i][j] = f32x4{0.f, 0.f, 0.f, 0.f};

    for (int k0 = 0; k0 < K; k0 += 64) {
#pragma unroll
        for (int t = 0; t < 4; ++t) gl_lds16(asrc[t] + k0, &u.ab.As[ldsoff[t]]);
#pragma unroll
        for (int t = 0; t < 4; ++t) gl_lds16(bsrc[t] + k0, &u.ab.Bs[ldsoff[t]]);
        __syncthreads();   // drains vmcnt(0): LDS tile ready

        bf16x8 af[2][4], bfr[2][4];
#pragma unroll
        for (int ks = 0; ks < 2; ++ks)
#pragma unroll
            for (int i = 0; i < 4; ++i) {
                af[ks][i]  = *(const bf16x8*)&u.ab.As[aoff[ks][i]];
                bfr[ks][i] = *(const bf16x8*)&u.ab.Bs[boff[ks][i]];
            }
#pragma unroll
        for (int ks = 0; ks < 2; ++ks)
#pragma unroll
            for (int i = 0; i < 4; ++i)
#pragma unroll
                for (int j = 0; j < 4; ++j)
                    acc[i][j] = __builtin_amdgcn_mfma_f32_16x16x32_bf16(af[ks][i], bfr[ks][j], acc[i][j], 0, 0, 0);
        __syncthreads();   // all waves done reading before next-tile overwrite
    }

    // ---- epilogue: stage tile in LDS, write coalesced segments
    __syncthreads();
    if (!CF32) {
#pragma unroll
        for (int j = 0; j < 4; ++j) {
            int lcol = wn + j * 16 + l15;
            int gcol = n0 + lcol;
            float bvv = (bias && gcol < N) ? bias[gcol] : 0.f;
#pragma unroll
            for (int i = 0; i < 4; ++i)
#pragma unroll
                for (int r = 0; r < 4; ++r)
                    u.Cs2[(wm + i * 16 + quad * 4 + r) * 136 + lcol] = f2bs(acc[i][j][r] + bvv);
        }
        __syncthreads();
        for (int i2 = tid; i2 < 2048; i2 += 256) {
            int lrow = i2 >> 4, seg = i2 & 15;
            int col0 = n0 + seg * 8;               // N % 8 == 0 for all bf16 outputs
            if (col0 < N) {
                int4 v = *(int4*)&u.Cs2[lrow * 136 + seg * 8];
                *(int4*)&((bf16*)Cp)[(long)(m0 + lrow) * ldc + coff + col0] = v;
            }
        }
    } else {
#pragma unroll
        for (int j = 0; j < 4; ++j) {
            int lcol = wn + j * 16 + l15;
            int gcol = n0 + lcol;
            float bvv = (bias && gcol < N) ? bias[gcol] : 0.f;
#pragma unroll
            for (int i = 0; i < 4; ++i)
#pragma unroll
                for (int r = 0; r < 4; ++r)
                    u.Cs4[(wm + i * 16 + quad * 4 + r) * 132 + lcol] = acc[i][j][r] + bvv;
        }
        __syncthreads();
        for (int i2 = tid; i2 < 4096; i2 += 256) {
            int lrow = i2 >> 5, seg = i2 & 31;
            int col0 = n0 + seg * 4;               // N % 4 == 0
            if (col0 < N) {
                int4 v = *(int4*)&u.Cs4[lrow * 132 + seg * 4];
                *(int4*)&((float*)Cp)[(long)(m0 + lrow) * ldc + coff + col0] = v;
            }
        }
    }
}

// ---------------------------------------------------------------------------
// Legacy MFMA GEMM (f32 or bf16 A, f32 W converted in-kernel). Kept for the
// embedding GEMM (f32 A + token gather) and as full fallback if ws too small.
// ---------------------------------------------------------------------------
template<bool AF32, bool CF32>
__global__ __launch_bounds__(256, 2)
void k_gemm(const void* __restrict__ Ap, const int* __restrict__ gatherIdx,
            const float* __restrict__ W, const float* __restrict__ bias,
            void* __restrict__ Cp, int M, int N, int K, int ldc, int coff)
{
    __shared__ union UU {
        struct { __align__(16) short As[128 * 40]; __align__(16) short Bs[128 * 40]; } ab;
        __align__(16) short Cs2[128 * 136];
        __align__(16) float Cs4[CF32 ? 128 * 132 : 4];
    } u;

    const int tid  = threadIdx.x;
    const int m0   = blockIdx.y * 128;
    const int n0   = blockIdx.x * 128;
    const int wave = tid >> 6, lane = tid & 63;
    const int l15  = lane & 15, quad = lane >> 4;
    const int wm   = (wave & 1) * 64, wn = (wave >> 1) * 64;

    f32x4 acc[4][4];
#pragma unroll
    for (int i = 0; i < 4; ++i)
#pragma unroll
        for (int j = 0; j < 4; ++j) acc[i][j] = f32x4{0.f, 0.f, 0.f, 0.f};

    const int srow = tid >> 2;
    const int scol = (tid & 3) * 8;

    union V8 { int4 i4; short s[8]; };

    for (int k0 = 0; k0 < K; k0 += 32) {
        V8 av[2], bv[2];
#pragma unroll
        for (int it = 0; it < 2; ++it) {
            int r = srow + it * 64;
            long arow = m0 + r;
            if (gatherIdx) arow = gatherIdx[m0 + r];
            if (AF32) {
                const float* ap = (const float*)Ap + arow * (long)K + k0 + scol;
                float4 f0 = *(const float4*)ap;
                float4 f1 = *(const float4*)(ap + 4);
                av[it].s[0] = f2bs(f0.x); av[it].s[1] = f2bs(f0.y);
                av[it].s[2] = f2bs(f0.z); av[it].s[3] = f2bs(f0.w);
                av[it].s[4] = f2bs(f1.x); av[it].s[5] = f2bs(f1.y);
                av[it].s[6] = f2bs(f1.z); av[it].s[7] = f2bs(f1.w);
            } else {
                av[it].i4 = *(const int4*)((const bf16*)Ap + arow * (long)K + k0 + scol);
            }
            int wr = n0 + r;
            if (wr < N) {
                const float* wp = W + (long)wr * K + k0 + scol;
                float4 f0 = *(const float4*)wp;
                float4 f1 = *(const float4*)(wp + 4);
                bv[it].s[0] = f2bs(f0.x); bv[it].s[1] = f2bs(f0.y);
                bv[it].s[2] = f2bs(f0.z); bv[it].s[3] = f2bs(f0.w);
                bv[it].s[4] = f2bs(f1.x); bv[it].s[5] = f2bs(f1.y);
                bv[it].s[6] = f2bs(f1.z); bv[it].s[7] = f2bs(f1.w);
            } else {
                bv[it].i4 = int4{0, 0, 0, 0};
            }
        }
        __syncthreads();
#pragma unroll
        for (int it = 0; it < 2; ++it) {
            int r = srow + it * 64;
            *(int4*)&u.ab.As[r * 40 + scol] = av[it].i4;
            *(int4*)&u.ab.Bs[r * 40 + scol] = bv[it].i4;
        }
        __syncthreads();

        bf16x8 af[4], bfr[4];
#pragma unroll
        for (int i = 0; i < 4; ++i)
            af[i] = *(const bf16x8*)&u.ab.As[(wm + i * 16 + l15) * 40 + quad * 8];
#pragma unroll
        for (int j = 0; j < 4; ++j)
            bfr[j] = *(const bf16x8*)&u.ab.Bs[(wn + j * 16 + l15) * 40 + quad * 8];
#pragma unroll
        for (int i = 0; i < 4; ++i)
#pragma unroll
            for (int j = 0; j < 4; ++j)
                acc[i][j] = __builtin_amdgcn_mfma_f32_16x16x32_bf16(af[i], bfr[j], acc[i][j], 0, 0, 0);
    }

    __syncthreads();
    if (!CF32) {
#pragma unroll
        for (int j = 0; j < 4; ++j) {
            int lcol = wn + j * 16 + l15;
            int gcol = n0 + lcol;
            float bvv = (bias && gcol < N) ? bias[gcol] : 0.f;
#pragma unroll
            for (int i = 0; i < 4; ++i)
#pragma unroll
                for (int r = 0; r < 4; ++r)
                    u.Cs2[(wm + i * 16 + quad * 4 + r) * 136 + lcol] = f2bs(acc[i][j][r] + bvv);
        }
        __syncthreads();
        for (int i2 = tid; i2 < 2048; i2 += 256) {
            int lrow = i2 >> 4, seg = i2 & 15;
            int col0 = n0 + seg * 8;
            if (col0 < N) {
                int4 v = *(int4*)&u.Cs2[lrow * 136 + seg * 8];
                *(int4*)&((bf16*)Cp)[(long)(m0 + lrow) * ldc + coff + col0] = v;
            }
        }
    } else {
#pragma unroll
        for (int j = 0; j < 4; ++j) {
            int lcol = wn + j * 16 + l15;
            int gcol = n0 + lcol;
            float bvv = (bias && gcol < N) ? bias[gcol] : 0.f;
#pragma unroll
            for (int i = 0; i < 4; ++i)
#pragma unroll
                for (int r = 0; r < 4; ++r)
                    u.Cs4[(wm + i * 16 + quad * 4 + r) * 132 + lcol] = acc[i][j][r] + bvv;
        }
        __syncthreads();
        for (int i2 = tid; i2 < 4096; i2 += 256) {
            int lrow = i2 >> 5, seg = i2 & 31;
            int col0 = n0 + seg * 4;
            if (col0 < N) {
                int4 v = *(int4*)&u.Cs4[lrow * 132 + seg * 4];
                *(int4*)&((float*)Cp)[(long)(m0 + lrow) * ldc + coff + col0] = v;
            }
        }
    }
}

// ---------------------------------------------------------------------------
// flip row map
// ---------------------------------------------------------------------------
__global__ void k_mkidx(const int* __restrict__ lens, int* __restrict__ gidx)
{
    int idx = blockIdx.x * 256 + threadIdx.x;  // 16384
    int b = idx >> 11, t = idx & 2047;
    int len = lens[b];
    gidx[idx] = b * 2048 + ((t < len) ? (len - 1 - t) : t);
}

// ---------------------------------------------------------------------------
// Depthwise causal conv(k=4)+bias+silu: zx[:,1024:2176] -> xc[16384][1152] bf16
// ---------------------------------------------------------------------------
__global__ __launch_bounds__(256)
void k_conv(const bf16* __restrict__ zx, const float* __restrict__ w,
            const float* __restrict__ cb, bf16* __restrict__ xc)
{
    long idx = (long)blockIdx.x * 256 + threadIdx.x;   // 16384*144
    if (idx >= 16384L * 144) return;
    int  c8 = (int)(idx % 144);
    long bt = idx / 144;
    int  t  = (int)(bt & 2047);
    int  c0 = c8 * 8;

    float acc[8];
#pragma unroll
    for (int i = 0; i < 8; ++i) acc[i] = cb[c0 + i];
#pragma unroll
    for (int j = 0; j < 4; ++j) {
        if (t >= 3 - j) {
            bf16x8 v = *(const bf16x8*)&zx[(bt - 3 + j) * (long)D_PROJ + 1024 + c0];
#pragma unroll
            for (int i = 0; i < 8; ++i) acc[i] += w[(c0 + i) * 4 + j] * (float)v[i];
        }
    }
    short out[8];
#pragma unroll
    for (int i = 0; i < 8; ++i) {
        float a = acc[i];
        out[i] = f2bs(a / (1.f + expf(-a)));
    }
    *(int4*)&xc[bt * (long)CONV_DIM + c0] = *(int4*)out;
}

// ---------------------------------------------------------------------------
// dt = softplus(raw + bias); dA = exp(-exp(Alog)*dt). One dir per launch.
// ---------------------------------------------------------------------------
__global__ void k_dt(const bf16* __restrict__ zx, const float* __restrict__ dtb,
                     const float* __restrict__ alog,
                     float* __restrict__ dtv, float* __restrict__ dAv)
{
    int idx = blockIdx.x * 256 + threadIdx.x;   // 16384*16
    int hh = idx & 15;
    long bt = idx >> 4;
    float x  = B2F(zx[bt * (long)D_PROJ + 2176 + hh]) + dtb[hh];
    float sp = (x > 20.f) ? x : log1pf(expf(x));
    dtv[idx] = sp;
    dAv[idx] = expf(-expf(alog[hh]) * sp);
}

// ---------------------------------------------------------------------------
// Inclusive cumprod of dA within each chunk -> Pt; chunk totals -> Pc.
// ---------------------------------------------------------------------------
__global__ __launch_bounds__(256)
void k_cum(const float* __restrict__ dAv, float* __restrict__ Pt,
           float* __restrict__ Pc)
{
    int blk = blockIdx.x;
    int c = blk & 7, h = (blk >> 3) & 15, b = blk >> 7;
    int tid = threadIdx.x;
    int t = c * CLEN + tid;
    long gi = ((long)(b * 2048 + t) << 4) + h;
    float v = dAv[gi];
    __shared__ float sa[256], sb[256];
    sa[tid] = v; __syncthreads();
    float* src = sa; float* dst = sb;
    for (int off = 1; off < 256; off <<= 1) {
        float x = src[tid];
        if (tid >= off) x *= src[tid - off];
        dst[tid] = x;
        __syncthreads();
        float* tp = src; src = dst; dst = tp;
    }
    float incl = src[tid];
    Pt[gi] = incl;
    if (tid == 255) Pc[blk] = incl;
}

// ---------------------------------------------------------------------------
// Phase 1: local scan per chunk (zero init).
// ---------------------------------------------------------------------------
__global__ __launch_bounds__(256)
void k_ph1(const bf16* __restrict__ xc, const float* __restrict__ dtv,
           const float* __restrict__ dAv, const float* __restrict__ Dp,
           bf16* __restrict__ y, float* __restrict__ Sl)
{
    const int blk = blockIdx.x;
    const int c = blk & 7, h = (blk >> 3) & 15, b = blk >> 7;
    const float Dv = Dp[h];

    __shared__ __align__(16) short xs[32][64];
    __shared__ __align__(16) float Bsm[32][64], Csm[32][64];
    __shared__ __align__(16) short ysb[32][64];
    __shared__ float dA_s[32], dt_s[32];

    const int tid = threadIdx.x;
    const int p = tid >> 2, ng = tid & 3;
    float s[16];
#pragma unroll
    for (int i = 0; i < 16; ++i) s[i] = 0.f;
    const long base = (long)b * 2048;
    const int tcs = c * CLEN;
    const int rr = tid >> 3, sg = (tid & 7) * 8;   // staging coords

    for (int tile = 0; tile < 8; ++tile) {
        const int t0 = tcs + tile * 32;
        {
            const bf16* row = &xc[(base + t0 + rr) * (long)CONV_DIM];
            *(int4*)&xs[rr][sg] = *(const int4*)&row[h * 64 + sg];
            bf16x8 vB = *(const bf16x8*)&row[1024 + sg];
            bf16x8 vC = *(const bf16x8*)&row[1088 + sg];
#pragma unroll
            for (int j = 0; j < 8; ++j) { Bsm[rr][sg + j] = (float)vB[j]; Csm[rr][sg + j] = (float)vC[j]; }
        }
        if (tid < 32) {
            long gi = ((base + t0 + tid) << 4) + h;
            dA_s[tid] = dAv[gi];
            dt_s[tid] = dtv[gi];
        }
        __syncthreads();

#pragma unroll 4
        for (int tt = 0; tt < 32; ++tt) {
            float dA = dA_s[tt], dtt = dt_s[tt];
            float xp = bs2f(xs[tt][p]);
            float tmp = dtt * xp;
            const float4* Bp = (const float4*)&Bsm[tt][ng * 16];
            const float4* Cq = (const float4*)&Csm[tt][ng * 16];
            float ysum = 0.f;
#pragma unroll
            for (int q = 0; q < 4; ++q) {
                float4 Bv = Bp[q], Cv = Cq[q];
                s[q*4+0] = s[q*4+0] * dA + tmp * Bv.x; ysum += s[q*4+0] * Cv.x;
                s[q*4+1] = s[q*4+1] * dA + tmp * Bv.y; ysum += s[q*4+1] * Cv.y;
                s[q*4+2] = s[q*4+2] * dA + tmp * Bv.z; ysum += s[q*4+2] * Cv.z;
                s[q*4+3] = s[q*4+3] * dA + tmp * Bv.w; ysum += s[q*4+3] * Cv.w;
            }
            ysum += __shfl_xor(ysum, 1);
            ysum += __shfl_xor(ysum, 2);
            if (ng == 0) ysb[tt][p] = f2bs(ysum + Dv * xp);
        }
        __syncthreads();

        *(int4*)&y[(base + t0 + rr) * 1024L + h * 64 + sg] = *(int4*)&ysb[rr][sg];
    }

    float* Sp = Sl + (long)blk * 4096 + p * 64 + ng * 16;
#pragma unroll
    for (int q = 0; q < 4; ++q)
        *(float4*)&Sp[q * 4] = float4{s[q*4+0], s[q*4+1], s[q*4+2], s[q*4+3]};
}

// ---------------------------------------------------------------------------
// Phase 2: sequential combine of chunk states. 128 blocks (b*16+h), 256 thr.
// ---------------------------------------------------------------------------
__global__ __launch_bounds__(256)
void k_comb(float* __restrict__ Sl, const float* __restrict__ Pc)
{
    int bh = blockIdx.x;
    int tid = threadIdx.x;
    float run[16];
#pragma unroll
    for (int i = 0; i < 16; ++i) run[i] = 0.f;
    for (int c = 0; c < NCHUNK; ++c) {
        float* ptr = Sl + ((long)(bh * NCHUNK + c)) * 4096 + tid * 16;
        float pc = Pc[bh * NCHUNK + c];
#pragma unroll
        for (int q = 0; q < 4; ++q) {
            float4 v = *(float4*)&ptr[q * 4];
            float4 init = float4{run[q*4+0], run[q*4+1], run[q*4+2], run[q*4+3]};
            run[q*4+0] = v.x + pc * run[q*4+0];
            run[q*4+1] = v.y + pc * run[q*4+1];
            run[q*4+2] = v.z + pc * run[q*4+2];
            run[q*4+3] = v.w + pc * run[q*4+3];
            *(float4*)&ptr[q * 4] = init;
        }
    }
}

// ---------------------------------------------------------------------------
// Phase 3: y[t] += Pt[t] * (C_t · Sinit). Grid 1024, 256 threads.
// ---------------------------------------------------------------------------
__global__ __launch_bounds__(256)
void k_ph3(const float* __restrict__ Sl, const bf16* __restrict__ xc,
           const float* __restrict__ Pt, bf16* __restrict__ y)
{
    const int blk = blockIdx.x;
    const int c = blk & 7, h = (blk >> 3) & 15, b = blk >> 7;
    if (c == 0) return;   // Sinit = 0

    __shared__ __align__(16) float Cs[64][64];
    __shared__ __align__(16) short ysb[64][64];
    __shared__ float Pts[64];

    const int tid = threadIdx.x;
    const int p = tid >> 2, ng = tid & 3;
    const long base = (long)b * 2048;
    const int tcs = c * CLEN;

    float Sv[16];
    const float* Sp = Sl + (long)blk * 4096 + p * 64 + ng * 16;
#pragma unroll
    for (int q = 0; q < 4; ++q) {
        float4 v = *(const float4*)&Sp[q * 4];
        Sv[q*4+0] = v.x; Sv[q*4+1] = v.y; Sv[q*4+2] = v.z; Sv[q*4+3] = v.w;
    }

    for (int tile = 0; tile < 4; ++tile) {
        const int t0 = tcs + tile * 64;
        for (int i = tid; i < 512; i += 256) {
            int r = i >> 3, sg = (i & 7) * 8;
            bf16x8 v = *(const bf16x8*)&xc[(base + t0 + r) * (long)CONV_DIM + 1088 + sg];
#pragma unroll
            for (int j = 0; j < 8; ++j) Cs[r][sg + j] = (float)v[j];
        }
        if (tid < 64) Pts[tid] = Pt[((base + t0 + tid) << 4) + h];
        __syncthreads();

#pragma unroll 4
        for (int tt = 0; tt < 64; ++tt) {
            const float4* Cq = (const float4*)&Cs[tt][ng * 16];
            float dot = 0.f;
#pragma unroll
            for (int q = 0; q < 4; ++q) {
                float4 Cv = Cq[q];
                dot += Sv[q*4+0] * Cv.x + Sv[q*4+1] * Cv.y
                     + Sv[q*4+2] * Cv.z + Sv[q*4+3] * Cv.w;
            }
            dot += __shfl_xor(dot, 1);
            dot += __shfl_xor(dot, 2);
            if (ng == 0) ysb[tt][p] = f2bs(Pts[tt] * dot);
        }
        __syncthreads();

        for (int i = tid; i < 1024; i += 256) {
            int r = i >> 4, c4 = (i & 15) * 4;
            bf16* yp = &y[(base + t0 + r) * 1024L + h * 64 + c4];
            ushort4 old = *(ushort4*)yp;
            short* corr = &ysb[r][c4];
            ushort4 nw;
            nw.x = (unsigned short)f2bs(bs2f((short)old.x) + bs2f(corr[0]));
            nw.y = (unsigned short)f2bs(bs2f((short)old.y) + bs2f(corr[1]));
            nw.z = (unsigned short)f2bs(bs2f((short)old.z) + bs2f(corr[2]));
            nw.w = (unsigned short)f2bs(bs2f((short)old.w) + bs2f(corr[3]));
            *(ushort4*)yp = nw;
        }
        __syncthreads();
    }
}

// ---------------------------------------------------------------------------
// Gate (y *= silu(z)) + RMSNorm * norm_w, in-place on y.
// ---------------------------------------------------------------------------
__global__ __launch_bounds__(256)
void k_gate(bf16* __restrict__ yp, const bf16* __restrict__ zxp,
            const float* __restrict__ nw)
{
    long bt = blockIdx.x;
    bf16* y = yp + bt * 1024;
    const bf16* z = zxp + bt * (long)D_PROJ;
    int tid = threadIdx.x;
    ushort4 zv = *(const ushort4*)&z[tid * 4];
    ushort4 yv = *(const ushort4*)&y[tid * 4];
    float g[4], ss = 0.f;
    {
        float zz0 = bs2f((short)zv.x), zz1 = bs2f((short)zv.y);
        float zz2 = bs2f((short)zv.z), zz3 = bs2f((short)zv.w);
        float yy0 = bs2f((short)yv.x), yy1 = bs2f((short)yv.y);
        float yy2 = bs2f((short)yv.z), yy3 = bs2f((short)yv.w);
        g[0] = yy0 * (zz0 / (1.f + expf(-zz0)));
        g[1] = yy1 * (zz1 / (1.f + expf(-zz1)));
        g[2] = yy2 * (zz2 / (1.f + expf(-zz2)));
        g[3] = yy3 * (zz3 / (1.f + expf(-zz3)));
        ss = g[0]*g[0] + g[1]*g[1] + g[2]*g[2] + g[3]*g[3];
    }
#pragma unroll
    for (int o = 1; o < 64; o <<= 1) ss += __shfl_xor(ss, o);
    __shared__ float red[4];
    if ((tid & 63) == 0) red[tid >> 6] = ss;
    __syncthreads();
    float tot = red[0] + red[1] + red[2] + red[3];
    float sc = rsqrtf(tot * (1.f / 1024.f) + 1e-5f);
    const float* w = nw + tid * 4;
    ushort4 ov;
    ov.x = (unsigned short)f2bs(g[0] * sc * w[0]);
    ov.y = (unsigned short)f2bs(g[1] * sc * w[1]);
    ov.z = (unsigned short)f2bs(g[2] * sc * w[2]);
    ov.w = (unsigned short)f2bs(g[3] * sc * w[3]);
    *(ushort4*)&y[tid * 4] = ov;
}

// in-place flip via swaps: rows of 1024 bf16 (128 int4)
__global__ void k_swap(bf16* __restrict__ buf, const int* __restrict__ lens)
{
    int idx = blockIdx.x * 256 + threadIdx.x;
    int v = idx & 127;
    int r = idx >> 7;
    int b = r >> 10, t = r & 1023;
    int len = lens[b];
    int t2 = len - 1 - t;
    if (t < len && t < t2) {
        int4* p = (int4*)buf;
        long i1 = ((long)b * 2048 + t)  * 128 + v;
        long i2 = ((long)b * 2048 + t2) * 128 + v;
        int4 a = p[i1], c = p[i2];
        p[i1] = c; p[i2] = a;
    }
}

// LayerNorm(out + h) * g + b -> h (in place)
__global__ __launch_bounds__(256)
void k_ln(const bf16* __restrict__ outb, bf16* __restrict__ h,
          const float* __restrict__ g, const float* __restrict__ bb)
{
    long r = (long)blockIdx.x * 512;
    int tid = threadIdx.x;
    float v0 = B2F(outb[r + tid])       + B2F(h[r + tid]);
    float v1 = B2F(outb[r + tid + 256]) + B2F(h[r + tid + 256]);
    __shared__ float red[4], red2[4];
    float s = v0 + v1;
#pragma unroll
    for (int o = 1; o < 64; o <<= 1) s += __shfl_xor(s, o);
    if ((tid & 63) == 0) red[tid >> 6] = s;
    __syncthreads();
    float mu = (red[0] + red[1] + red[2] + red[3]) * (1.f / 512.f);
    float d0 = v0 - mu, d1 = v1 - mu;
    float q = d0 * d0 + d1 * d1;
#pragma unroll
    for (int o = 1; o < 64; o <<= 1) q += __shfl_xor(q, o);
    if ((tid & 63) == 0) red2[tid >> 6] = q;
    __syncthreads();
    float var = (red2[0] + red2[1] + red2[2] + red2[3]) * (1.f / 512.f);
    float rs = rsqrtf(var + 1e-5f);
    h[r + tid]       = F2B(d0 * rs * g[tid]       + bb[tid]);
    h[r + tid + 256] = F2B(d1 * rs * g[tid + 256] + bb[tid + 256]);
}

// masked-sum pooling partials
__global__ void k_pool(const float* __restrict__ enc, const int* __restrict__ lens,
                       float* __restrict__ pooled)
{
    int bid = blockIdx.x;
    int b = bid >> 6;
    int cg = (bid >> 4) & 3, tc = bid & 15;
    int c = cg * 256 + threadIdx.x;
    int len = lens[b];
    float s = 0.f;
    int tend = tc * 128 + 128;
    for (int t = tc * 128; t < tend; ++t)
        if (t < len) s += enc[((long)b * 2048 + t) * 1024 + c];
    atomicAdd(&pooled[b * 1024 + c], s);
}

// encoder_hidden = tanh(pooled/len @ W_ad^T + b_ad)
__global__ void k_adapter(const float* __restrict__ pooled, const float* __restrict__ Wad,
                          const float* __restrict__ bad, const int* __restrict__ lens,
                          float* __restrict__ outh)
{
    int idx = blockIdx.x * 256 + threadIdx.x;
    int b = idx >> 9, j = idx & 511;
    const float* wrow = Wad + (long)j * 1024;
    const float* prow = pooled + b * 1024;
    float acc = 0.f;
    for (int k = 0; k < 1024; ++k) acc += prow[k] * wrow[k];
    int li = lens[b]; if (li < 1) li = 1;
    acc = acc / (float)li + bad[j];
    outh[idx] = tanhf(acc);
}

// ---------------------------------------------------------------------------
static void gemm(const void* A, bool af32, const int* gather, const float* W,
                 const float* bias, void* C, bool cf32,
                 int M, int N, int K, int ldc, int coff, hipStream_t s)
{
    dim3 grid((N + 127) / 128, M / 128);
    if (af32) {
        if (cf32) k_gemm<true,  true ><<<grid, 256, 0, s>>>(A, gather, W, bias, C, M, N, K, ldc, coff);
        else      k_gemm<true,  false><<<grid, 256, 0, s>>>(A, gather, W, bias, C, M, N, K, ldc, coff);
    } else {
        if (cf32) k_gemm<false, true ><<<grid, 256, 0, s>>>(A, gather, W, bias, C, M, N, K, ldc, coff);
        else      k_gemm<false, false><<<grid, 256, 0, s>>>(A, gather, W, bias, C, M, N, K, ldc, coff);
    }
}

static void gemm_bf(const bf16* A, const int* gather, const bf16* Wb, const float* bias,
                    void* C, bool cf32, int M, int N, int K, int ldc, int coff, hipStream_t s)
{
    dim3 grid((N + 127) / 128, M / 128);
    if (cf32) k_gemm_bf<true ><<<grid, 256, 0, s>>>(A, gather, Wb, bias, C, M, N, K, ldc, coff);
    else      k_gemm_bf<false><<<grid, 256, 0, s>>>(A, gather, Wb, bias, C, M, N, K, ldc, coff);
}

extern "C" void kernel_launch(void* const* d_in, const int* in_sizes, int n_in,
                              void* d_out, int out_size, void* d_ws, size_t ws_size,
                              hipStream_t stream)
{
    const int*   tok    = (const int*)d_in[0];
    const int*   lens   = (const int*)d_in[1];
    const float* emb    = (const float*)d_in[2];
    const float* W_inp  = (const float*)d_in[3];
    const float* b_inp  = (const float*)d_in[4];
    const float* m_Win  = (const float*)d_in[5];
    const float* m_convw= (const float*)d_in[6];
    const float* m_convb= (const float*)d_in[7];
    const float* m_dtb  = (const float*)d_in[8];
    const float* m_Alog = (const float*)d_in[9];
    const float* m_D    = (const float*)d_in[10];
    const float* m_norm = (const float*)d_in[11];
    const float* m_Wout = (const float*)d_in[12];
    const float* blk_Wo = (const float*)d_in[13];
    const float* blk_bo = (const float*)d_in[14];
    const float* ln_g   = (const float*)d_in[15];
    const float* ln_b   = (const float*)d_in[16];
    const float* W_enc  = (const float*)d_in[17];
    const float* b_enc  = (const float*)d_in[18];
    const float* W_ad   = (const float*)d_in[19];
    const float* b_ad   = (const float*)d_in[20];

    char* ws = (char*)d_ws;
    bf16*  h      = (bf16*)(ws + OFF_H);
    bf16*  zx     = (bf16*)(ws + OFF_ZX);
    bf16*  xc     = (bf16*)(ws + OFF_XC);
    float* Sl     = (float*)(ws + OFF_S);
    float* Pt     = (float*)(ws + OFF_PT);
    float* Pc     = (float*)(ws + OFF_PC);
    float* dtv    = (float*)(ws + OFF_DTV);
    float* dAv    = (float*)(ws + OFF_DAV);
    int*   gidx   = (int*)(ws + OFF_GIDX);
    float* pooled = (float*)(ws + OFF_POOL);

    float* dout   = (float*)d_out;
    bf16*  y_f    = (bf16*)d_out;                        // 33.55 MB
    bf16*  y_b    = (bf16*)d_out + (size_t)16384 * 1024; // next 33.55 MB
    bf16*  comb   = (bf16*)(ws + OFF_ZX);                // alias zx (dead after gates)
    bf16*  outbuf = (bf16*)(ws + OFF_XC);                // alias xc (dead after ph3 bwd)

    // bf16 weight cache (fast GEMM path); fallback to legacy path if ws too small
    const bool fast = ws_size >= (size_t)(OFF_WBF + WBF_BYTES);
    bf16* wWin  = fast ? (bf16*)(ws + OFF_WBF + WBF_WIN)  : nullptr;
    bf16* wWout = fast ? (bf16*)(ws + OFF_WBF + WBF_WOUT) : nullptr;
    bf16* wBlk  = fast ? (bf16*)(ws + OFF_WBF + WBF_BLK)  : nullptr;
    bf16* wEnc  = fast ? (bf16*)(ws + OFF_WBF + WBF_ENC)  : nullptr;
    if (fast) {
        k_wcvt<<<(1122304 + 255) / 256, 256, 0, stream>>>(m_Win,  wWin,  1122304); // 8*2192*512/8
        k_wcvt<<<( 524288 + 255) / 256, 256, 0, stream>>>(m_Wout, wWout,  524288); // 8*512*1024/8
        k_wcvt<<<( 262144 + 255) / 256, 256, 0, stream>>>(blk_Wo, wBlk,   262144); // 4*512*1024/8
        k_wcvt<<<(  65536 + 255) / 256, 256, 0, stream>>>(W_enc,  wEnc,    65536); // 1024*512/8
    }

    k_mkidx<<<64, 256, 0, stream>>>(lens, gidx);

    // h = emb[tok] @ W_inp^T + b_inp   (f32 A + token gather: legacy path)
    gemm(emb, true, tok, W_inp, b_inp, h, false, 16384, 512, 512, 512, 0, stream);

    for (int l = 0; l < 4; ++l) {
        for (int dir = 0; dir < 2; ++dir) {
            const float* Wi = m_Win  + (size_t)(l * 2 + dir) * D_PROJ * 512;
            const float* cw = m_convw + (size_t)(l * 2 + dir) * CONV_DIM * 4;
            const float* cbp= m_convb + (size_t)(l * 2 + dir) * CONV_DIM;
            const float* dtb= m_dtb  + l * 32 + dir * 16;
            const float* alg= m_Alog + l * 32 + dir * 16;
            const float* Dpp= m_D    + l * 32 + dir * 16;
            const float* nw = m_norm + (size_t)(l * 2 + dir) * 1024;
            bf16* y = dir ? y_b : y_f;

            if (fast)
                gemm_bf(h, dir ? gidx : nullptr, wWin + (size_t)(l * 2 + dir) * D_PROJ * 512,
                        nullptr, zx, false, 16384, D_PROJ, 512, D_PROJ, 0, stream);
            else
                gemm(h, false, dir ? gidx : nullptr, Wi, nullptr, zx, false,
                     16384, D_PROJ, 512, D_PROJ, 0, stream);
            k_conv<<<9216, 256, 0, stream>>>(zx, cw, cbp, xc);
            k_dt<<<1024, 256, 0, stream>>>(zx, dtb, alg, dtv, dAv);
            k_cum<<<1024, 256, 0, stream>>>(dAv, Pt, Pc);
            k_ph1<<<1024, 256, 0, stream>>>(xc, dtv, dAv, Dpp, y, Sl);
            k_comb<<<128, 256, 0, stream>>>(Sl, Pc);
            k_ph3<<<1024, 256, 0, stream>>>(Sl, xc, Pt, y);
            k_gate<<<16384, 256, 0, stream>>>(y, zx, nw);
            if (dir) k_swap<<<4096, 256, 0, stream>>>(y_b, lens);
        }

        // out-projections into comb halves (comb aliases dead zx)
        if (fast) {
            gemm_bf(y_f, nullptr, wWout + (size_t)(l * 2 + 0) * 512 * 1024, nullptr, comb,
                    false, 16384, 512, 1024, 1024, 0, stream);
            gemm_bf(y_b, nullptr, wWout + (size_t)(l * 2 + 1) * 512 * 1024, nullptr, comb,
                    false, 16384, 512, 1024, 1024, 512, stream);
            gemm_bf(comb, nullptr, wBlk + (size_t)l * 512 * 1024, blk_bo + l * 512, outbuf,
                    false, 16384, 512, 1024, 512, 0, stream);
        } else {
            gemm(y_f, false, nullptr, m_Wout + (size_t)(l * 2 + 0) * 512 * 1024, nullptr, comb,
                 false, 16384, 512, 1024, 1024, 0, stream);
            gemm(y_b, false, nullptr, m_Wout + (size_t)(l * 2 + 1) * 512 * 1024, nullptr, comb,
                 false, 16384, 512, 1024, 1024, 512, stream);
            gemm(comb, false, nullptr, blk_Wo + (size_t)l * 512 * 1024, blk_bo + l * 512, outbuf,
                 false, 16384, 512, 1024, 512, 0, stream);
        }
        // residual + layernorm -> h
        k_ln<<<16384, 256, 0, stream>>>(outbuf, h, ln_g + l * 512, ln_b + l * 512);
    }

    // encoder_outputs = h @ W_enc^T + b_enc -> d_out f32 (y_f/y_b dead)
    if (fast)
        gemm_bf(h, nullptr, wEnc, b_enc, dout, true, 16384, 1024, 512, 1024, 0, stream);
    else
        gemm(h, false, nullptr, W_enc, b_enc, dout, true, 16384, 1024, 512, 1024, 0, stream);

    hipMemsetAsync(pooled, 0, 8 * 1024 * sizeof(float), stream);
    k_pool<<<512, 256, 0, stream>>>(dout, lens, pooled);
    k_adapter<<<16, 256, 0, stream>>>(pooled, W_ad, b_ad, lens, dout + (size_t)16384 * 1024);
}

// Round 3
// 3541.756 us; speedup vs baseline: 1.5973x; 1.1372x over previous
//
#include <hip/hip_runtime.h>
#include <hip/hip_bf16.h>
#include <math.h>

using bf16 = __hip_bfloat16;
typedef __bf16 bf16x8 __attribute__((ext_vector_type(8)));
typedef float f32x4 __attribute__((ext_vector_type(4)));

#define B2F(x) __bfloat162float(x)
#define F2B(x) __float2bfloat16(x)

__device__ inline short f2bs(float x) { bf16 b = F2B(x); return *(short*)&b; }
__device__ inline float bs2f(short x) { bf16 b; *(short*)&b = x; return B2F(b); }

// Problem constants: B=8, L=2048, H=512, D_INNER=1024, NH=16, P=64, N=64
static constexpr int D_PROJ = 2192, CONV_DIM = 1152;
static constexpr int NCHUNK = 8, CLEN = 256;   // 8 chunks x 256 steps

// Workspace layout (bytes). y_f/y_b live in d_out (67.1 MB).
static constexpr size_t OFF_H    = 0;                    // 16384x512  bf16  16.8 MB
static constexpr size_t OFF_ZX   = 16777216;             // 16384x2192 bf16  71.8 MB (comb aliases)
static constexpr size_t OFF_XC   = 88604672;             // 16384x1152 bf16  37.7 MB (outbuf aliases)
static constexpr size_t OFF_S    = 126353408;            // 1024x4096  f32   16.8 MB
static constexpr size_t OFF_PT   = 143130624;            // 16384x16   f32    1.0 MB
static constexpr size_t OFF_PC   = 144179200;            // 1024       f32    4 KB
static constexpr size_t OFF_DTV  = 144183296;            // 16384x16   f32    1.0 MB
static constexpr size_t OFF_DAV  = 145231872;            // 16384x16   f32    1.0 MB
static constexpr size_t OFF_GIDX = 146280448;            // 16384      i32
static constexpr size_t OFF_POOL = 146345984;            // 8x1024     f32 (ends 146378752)
// bf16 weight cache (one-time conversion). Guarded by ws_size with full fallback.
static constexpr size_t OFF_WBF   = 146378752;
static constexpr size_t WBF_WIN   = 0;          // 8 x 2192x512 bf16 = 17,956,864
static constexpr size_t WBF_WOUT  = 17956864;   // 8 x 512x1024 bf16 =  8,388,608
static constexpr size_t WBF_BLK   = 26345472;   // 4 x 512x1024 bf16 =  4,194,304
static constexpr size_t WBF_ENC   = 30539776;   // 1024x512     bf16 =  1,048,576
static constexpr size_t WBF_BYTES = 31588352;

// ---------------------------------------------------------------------------
// f32 -> bf16 weight conversion (one-time per launch)
// ---------------------------------------------------------------------------
__global__ void k_wcvt(const float* __restrict__ src, bf16* __restrict__ dst, long n8)
{
    long i = (long)blockIdx.x * 256 + threadIdx.x;
    if (i >= n8) return;
    const float4* s = (const float4*)(src + i * 8);
    float4 f0 = s[0], f1 = s[1];
    short o[8];
    o[0] = f2bs(f0.x); o[1] = f2bs(f0.y); o[2] = f2bs(f0.z); o[3] = f2bs(f0.w);
    o[4] = f2bs(f1.x); o[5] = f2bs(f1.y); o[6] = f2bs(f1.z); o[7] = f2bs(f1.w);
    *(int4*)&dst[i * 8] = *(int4*)o;
}

// ---------------------------------------------------------------------------
// async global->LDS, 16B per lane (wave-uniform LDS base + lane*16 dest)
// ---------------------------------------------------------------------------
__device__ inline void gl_lds16(const void* g, void* l)
{
    __builtin_amdgcn_global_load_lds(
        (const __attribute__((address_space(1))) unsigned int*)g,
        (__attribute__((address_space(3))) unsigned int*)l,
        16, 0, 0);
}

// ---------------------------------------------------------------------------
// Fast MFMA GEMM (bf16 A, bf16 W): C[M,N] = A[M,K] @ W[N,K]^T + bias
// ---------------------------------------------------------------------------
template<bool CF32>
__global__ __launch_bounds__(256, 2)
void k_gemm_bf(const bf16* __restrict__ A, const int* __restrict__ gatherIdx,
               const bf16* __restrict__ Wb, const float* __restrict__ bias,
               void* __restrict__ Cp, int M, int N, int K, int ldc, int coff)
{
    __shared__ union UU {
        struct { __align__(16) short As[128 * 64]; __align__(16) short Bs[128 * 64]; } ab;
        __align__(16) short Cs2[128 * 136];                 // bf16 epilogue
        __align__(16) float Cs4[CF32 ? 128 * 132 : 4];      // f32 epilogue
    } u;

    const int tid  = threadIdx.x;
    const int m0   = blockIdx.y * 128;
    const int n0   = blockIdx.x * 128;
    const int wave = tid >> 6, lane = tid & 63;
    const int l15  = lane & 15, quad = lane >> 4;
    const int wm   = (wave & 1) * 64, wn = (wave >> 1) * 64;

    const int sr   = lane >> 3;   // 0..7 sub-row within the 8-row chunk
    const int slot = lane & 7;    // 16B slot within row
    const bf16* asrc[4];
    const bf16* bsrc[4];
    int ldsoff[4];
#pragma unroll
    for (int t = 0; t < 4; ++t) {
        int row = wave * 32 + t * 8 + sr;            // 0..127
        long arow = m0 + row;
        if (gatherIdx) arow = gatherIdx[m0 + row];
        int sl = ((slot ^ (row & 7)) * 8);           // swizzled source col (elems)
        asrc[t] = A + arow * (long)K + sl;
        int wr = n0 + row; if (wr > N - 1) wr = N - 1;   // clamp; garbage cols never stored
        bsrc[t] = Wb + (long)wr * K + sl;
        ldsoff[t] = (wave * 32 + t * 8) * 64;        // shorts, wave-uniform
    }

    int aoff[2][4], boff[2][4];
#pragma unroll
    for (int ks = 0; ks < 2; ++ks) {
        int swz = (((ks << 2) | quad) ^ (l15 & 7)) * 8;
#pragma unroll
        for (int i = 0; i < 4; ++i) {
            aoff[ks][i] = (wm + i * 16 + l15) * 64 + swz;
            boff[ks][i] = (wn + i * 16 + l15) * 64 + swz;
        }
    }

    f32x4 acc[4][4];
#pragma unroll
    for (int i = 0; i < 4; ++i)
#pragma unroll
        for (int j = 0; j < 4; ++j) acc[i][j] = f32x4{0.f, 0.f, 0.f, 0.f};

    for (int k0 = 0; k0 < K; k0 += 64) {
#pragma unroll
        for (int t = 0; t < 4; ++t) gl_lds16(asrc[t] + k0, &u.ab.As[ldsoff[t]]);
#pragma unroll
        for (int t = 0; t < 4; ++t) gl_lds16(bsrc[t] + k0, &u.ab.Bs[ldsoff[t]]);
        __syncthreads();   // drains vmcnt(0): LDS tile ready

        bf16x8 af[2][4], bfr[2][4];
#pragma unroll
        for (int ks = 0; ks < 2; ++ks)
#pragma unroll
            for (int i = 0; i < 4; ++i) {
                af[ks][i]  = *(const bf16x8*)&u.ab.As[aoff[ks][i]];
                bfr[ks][i] = *(const bf16x8*)&u.ab.Bs[boff[ks][i]];
            }
#pragma unroll
        for (int ks = 0; ks < 2; ++ks)
#pragma unroll
            for (int i = 0; i < 4; ++i)
#pragma unroll
                for (int j = 0; j < 4; ++j)
                    acc[i][j] = __builtin_amdgcn_mfma_f32_16x16x32_bf16(af[ks][i], bfr[ks][j], acc[i][j], 0, 0, 0);
        __syncthreads();
    }

    __syncthreads();
    if (!CF32) {
#pragma unroll
        for (int j = 0; j < 4; ++j) {
            int lcol = wn + j * 16 + l15;
            int gcol = n0 + lcol;
            float bvv = (bias && gcol < N) ? bias[gcol] : 0.f;
#pragma unroll
            for (int i = 0; i < 4; ++i)
#pragma unroll
                for (int r = 0; r < 4; ++r)
                    u.Cs2[(wm + i * 16 + quad * 4 + r) * 136 + lcol] = f2bs(acc[i][j][r] + bvv);
        }
        __syncthreads();
        for (int i2 = tid; i2 < 2048; i2 += 256) {
            int lrow = i2 >> 4, seg = i2 & 15;
            int col0 = n0 + seg * 8;
            if (col0 < N) {
                int4 v = *(int4*)&u.Cs2[lrow * 136 + seg * 8];
                *(int4*)&((bf16*)Cp)[(long)(m0 + lrow) * ldc + coff + col0] = v;
            }
        }
    } else {
#pragma unroll
        for (int j = 0; j < 4; ++j) {
            int lcol = wn + j * 16 + l15;
            int gcol = n0 + lcol;
            float bvv = (bias && gcol < N) ? bias[gcol] : 0.f;
#pragma unroll
            for (int i = 0; i < 4; ++i)
#pragma unroll
                for (int r = 0; r < 4; ++r)
                    u.Cs4[(wm + i * 16 + quad * 4 + r) * 132 + lcol] = acc[i][j][r] + bvv;
        }
        __syncthreads();
        for (int i2 = tid; i2 < 4096; i2 += 256) {
            int lrow = i2 >> 5, seg = i2 & 31;
            int col0 = n0 + seg * 4;
            if (col0 < N) {
                int4 v = *(int4*)&u.Cs4[lrow * 132 + seg * 4];
                *(int4*)&((float*)Cp)[(long)(m0 + lrow) * ldc + coff + col0] = v;
            }
        }
    }
}

// ---------------------------------------------------------------------------
// Legacy MFMA GEMM (f32 A + gather): embedding GEMM and full fallback.
// ---------------------------------------------------------------------------
template<bool AF32, bool CF32>
__global__ __launch_bounds__(256, 2)
void k_gemm(const void* __restrict__ Ap, const int* __restrict__ gatherIdx,
            const float* __restrict__ W, const float* __restrict__ bias,
            void* __restrict__ Cp, int M, int N, int K, int ldc, int coff)
{
    __shared__ union UU {
        struct { __align__(16) short As[128 * 40]; __align__(16) short Bs[128 * 40]; } ab;
        __align__(16) short Cs2[128 * 136];
        __align__(16) float Cs4[CF32 ? 128 * 132 : 4];
    } u;

    const int tid  = threadIdx.x;
    const int m0   = blockIdx.y * 128;
    const int n0   = blockIdx.x * 128;
    const int wave = tid >> 6, lane = tid & 63;
    const int l15  = lane & 15, quad = lane >> 4;
    const int wm   = (wave & 1) * 64, wn = (wave >> 1) * 64;

    f32x4 acc[4][4];
#pragma unroll
    for (int i = 0; i < 4; ++i)
#pragma unroll
        for (int j = 0; j < 4; ++j) acc[i][j] = f32x4{0.f, 0.f, 0.f, 0.f};

    const int srow = tid >> 2;
    const int scol = (tid & 3) * 8;

    union V8 { int4 i4; short s[8]; };

    for (int k0 = 0; k0 < K; k0 += 32) {
        V8 av[2], bv[2];
#pragma unroll
        for (int it = 0; it < 2; ++it) {
            int r = srow + it * 64;
            long arow = m0 + r;
            if (gatherIdx) arow = gatherIdx[m0 + r];
            if (AF32) {
                const float* ap = (const float*)Ap + arow * (long)K + k0 + scol;
                float4 f0 = *(const float4*)ap;
                float4 f1 = *(const float4*)(ap + 4);
                av[it].s[0] = f2bs(f0.x); av[it].s[1] = f2bs(f0.y);
                av[it].s[2] = f2bs(f0.z); av[it].s[3] = f2bs(f0.w);
                av[it].s[4] = f2bs(f1.x); av[it].s[5] = f2bs(f1.y);
                av[it].s[6] = f2bs(f1.z); av[it].s[7] = f2bs(f1.w);
            } else {
                av[it].i4 = *(const int4*)((const bf16*)Ap + arow * (long)K + k0 + scol);
            }
            int wr = n0 + r;
            if (wr < N) {
                const float* wp = W + (long)wr * K + k0 + scol;
                float4 f0 = *(const float4*)wp;
                float4 f1 = *(const float4*)(wp + 4);
                bv[it].s[0] = f2bs(f0.x); bv[it].s[1] = f2bs(f0.y);
                bv[it].s[2] = f2bs(f0.z); bv[it].s[3] = f2bs(f0.w);
                bv[it].s[4] = f2bs(f1.x); bv[it].s[5] = f2bs(f1.y);
                bv[it].s[6] = f2bs(f1.z); bv[it].s[7] = f2bs(f1.w);
            } else {
                bv[it].i4 = int4{0, 0, 0, 0};
            }
        }
        __syncthreads();
#pragma unroll
        for (int it = 0; it < 2; ++it) {
            int r = srow + it * 64;
            *(int4*)&u.ab.As[r * 40 + scol] = av[it].i4;
            *(int4*)&u.ab.Bs[r * 40 + scol] = bv[it].i4;
        }
        __syncthreads();

        bf16x8 af[4], bfr[4];
#pragma unroll
        for (int i = 0; i < 4; ++i)
            af[i] = *(const bf16x8*)&u.ab.As[(wm + i * 16 + l15) * 40 + quad * 8];
#pragma unroll
        for (int j = 0; j < 4; ++j)
            bfr[j] = *(const bf16x8*)&u.ab.Bs[(wn + j * 16 + l15) * 40 + quad * 8];
#pragma unroll
        for (int i = 0; i < 4; ++i)
#pragma unroll
            for (int j = 0; j < 4; ++j)
                acc[i][j] = __builtin_amdgcn_mfma_f32_16x16x32_bf16(af[i], bfr[j], acc[i][j], 0, 0, 0);
    }

    __syncthreads();
    if (!CF32) {
#pragma unroll
        for (int j = 0; j < 4; ++j) {
            int lcol = wn + j * 16 + l15;
            int gcol = n0 + lcol;
            float bvv = (bias && gcol < N) ? bias[gcol] : 0.f;
#pragma unroll
            for (int i = 0; i < 4; ++i)
#pragma unroll
                for (int r = 0; r < 4; ++r)
                    u.Cs2[(wm + i * 16 + quad * 4 + r) * 136 + lcol] = f2bs(acc[i][j][r] + bvv);
        }
        __syncthreads();
        for (int i2 = tid; i2 < 2048; i2 += 256) {
            int lrow = i2 >> 4, seg = i2 & 15;
            int col0 = n0 + seg * 8;
            if (col0 < N) {
                int4 v = *(int4*)&u.Cs2[lrow * 136 + seg * 8];
                *(int4*)&((bf16*)Cp)[(long)(m0 + lrow) * ldc + coff + col0] = v;
            }
        }
    } else {
#pragma unroll
        for (int j = 0; j < 4; ++j) {
            int lcol = wn + j * 16 + l15;
            int gcol = n0 + lcol;
            float bvv = (bias && gcol < N) ? bias[gcol] : 0.f;
#pragma unroll
            for (int i = 0; i < 4; ++i)
#pragma unroll
                for (int r = 0; r < 4; ++r)
                    u.Cs4[(wm + i * 16 + quad * 4 + r) * 132 + lcol] = acc[i][j][r] + bvv;
        }
        __syncthreads();
        for (int i2 = tid; i2 < 4096; i2 += 256) {
            int lrow = i2 >> 5, seg = i2 & 31;
            int col0 = n0 + seg * 4;
            if (col0 < N) {
                int4 v = *(int4*)&u.Cs4[lrow * 132 + seg * 4];
                *(int4*)&((float*)Cp)[(long)(m0 + lrow) * ldc + coff + col0] = v;
            }
        }
    }
}

// ---------------------------------------------------------------------------
// flip row map
// ---------------------------------------------------------------------------
__global__ void k_mkidx(const int* __restrict__ lens, int* __restrict__ gidx)
{
    int idx = blockIdx.x * 256 + threadIdx.x;  // 16384
    int b = idx >> 11, t = idx & 2047;
    int len = lens[b];
    gidx[idx] = b * 2048 + ((t < len) ? (len - 1 - t) : t);
}

// ---------------------------------------------------------------------------
// Depthwise causal conv(k=4)+bias+silu: zx[:,1024:2176] -> xc[16384][1152] bf16
// ---------------------------------------------------------------------------
__global__ __launch_bounds__(256)
void k_conv(const bf16* __restrict__ zx, const float* __restrict__ w,
            const float* __restrict__ cb, bf16* __restrict__ xc)
{
    long idx = (long)blockIdx.x * 256 + threadIdx.x;   // 16384*144
    if (idx >= 16384L * 144) return;
    int  c8 = (int)(idx % 144);
    long bt = idx / 144;
    int  t  = (int)(bt & 2047);
    int  c0 = c8 * 8;

    float acc[8];
#pragma unroll
    for (int i = 0; i < 8; ++i) acc[i] = cb[c0 + i];
#pragma unroll
    for (int j = 0; j < 4; ++j) {
        if (t >= 3 - j) {
            bf16x8 v = *(const bf16x8*)&zx[(bt - 3 + j) * (long)D_PROJ + 1024 + c0];
#pragma unroll
            for (int i = 0; i < 8; ++i) acc[i] += w[(c0 + i) * 4 + j] * (float)v[i];
        }
    }
    short out[8];
#pragma unroll
    for (int i = 0; i < 8; ++i) {
        float a = acc[i];
        out[i] = f2bs(a / (1.f + expf(-a)));
    }
    *(int4*)&xc[bt * (long)CONV_DIM + c0] = *(int4*)out;
}

// ---------------------------------------------------------------------------
// dt = softplus(raw + bias); dA = exp(-exp(Alog)*dt). One dir per launch.
// ---------------------------------------------------------------------------
__global__ void k_dt(const bf16* __restrict__ zx, const float* __restrict__ dtb,
                     const float* __restrict__ alog,
                     float* __restrict__ dtv, float* __restrict__ dAv)
{
    int idx = blockIdx.x * 256 + threadIdx.x;   // 16384*16
    int hh = idx & 15;
    long bt = idx >> 4;
    float x  = B2F(zx[bt * (long)D_PROJ + 2176 + hh]) + dtb[hh];
    float sp = (x > 20.f) ? x : log1pf(expf(x));
    dtv[idx] = sp;
    dAv[idx] = expf(-expf(alog[hh]) * sp);
}

// ---------------------------------------------------------------------------
// Inclusive cumprod of dA within each chunk -> Pt; chunk totals -> Pc.
// ---------------------------------------------------------------------------
__global__ __launch_bounds__(256)
void k_cum(const float* __restrict__ dAv, float* __restrict__ Pt,
           float* __restrict__ Pc)
{
    int blk = blockIdx.x;
    int c = blk & 7, h = (blk >> 3) & 15, b = blk >> 7;
    int tid = threadIdx.x;
    int t = c * CLEN + tid;
    long gi = ((long)(b * 2048 + t) << 4) + h;
    float v = dAv[gi];
    __shared__ float sa[256], sb[256];
    sa[tid] = v; __syncthreads();
    float* src = sa; float* dst = sb;
    for (int off = 1; off < 256; off <<= 1) {
        float x = src[tid];
        if (tid >= off) x *= src[tid - off];
        dst[tid] = x;
        __syncthreads();
        float* tp = src; src = dst; dst = tp;
    }
    float incl = src[tid];
    Pt[gi] = incl;
    if (tid == 255) Pc[blk] = incl;
}

// ---------------------------------------------------------------------------
// Phase 1 (MFMA chunked form). One workgroup per (b, h, 256-super-chunk).
// 4 sequential sub-chunks of Q=64; per sub-chunk, 64x64x64 MFMA matmuls:
//   CB^T = B @ C^T      (k = n)
//   P[t][s] = CB[t][s] * exp(aexp*(cs_s - cs_t)) * dt_s   (s <= t, else 0)
//     stored as bf16 hi/lo pair (P_s + B_s reuse) for ~f32 precision
//   Y     = G[t]*(C @ Srun^T) + P @ X^T  (+ D*x)          (Srun = bf16 hi/lo)
//   Sloc  = X^T @ (B*w)^T;  Srun = Pc*Srun + Sloc
// Fragment layouts identical to the verified k_gemm_bf (A rows=M,k; W rows=N,k;
// C/D: row = quad*4+r, col = l15).
// ---------------------------------------------------------------------------
__global__ __launch_bounds__(256, 2)
void k_ph1(const bf16* __restrict__ xc, const float* __restrict__ dtv,
           const float* __restrict__ alog, const float* __restrict__ Dp,
           bf16* __restrict__ y, float* __restrict__ Sl)
{
    const int blk = blockIdx.x;
    const int c = blk & 7, h = (blk >> 3) & 15, b = blk >> 7;
    const float Dv   = Dp[h];
    const float aexp = expf(alog[h]);

    // stride 72 shorts = 144 B (16B-aligned rows, non-pow2 bank spread)
    __shared__ __align__(16) short B_s [64][72];   // B[s][n]; after D: P_lo[t][s]
    __shared__ __align__(16) short C_s [64][72];   // C[t][n]
    __shared__ __align__(16) short XT  [64][72];   // XT[p][s] = x_s[p]
    __shared__ __align__(16) short BTw [64][72];   // BTw[n][s] = B[s][n]*w_s
    __shared__ __align__(16) short P_s [64][72];   // P_hi[t][s]; reused as ysb[t][p]
    __shared__ __align__(16) short hi_s[64][72];   // Srun hi [p][n]
    __shared__ __align__(16) short lo_s[64][72];   // Srun lo [p][n]
    __shared__ float cs_s[64];
    __shared__ float dt_l[64];

    const int tid  = threadIdx.x;
    const int wave = tid >> 6, lane = tid & 63;
    const int l15  = lane & 15, quad = lane >> 4;
    const int rr   = tid >> 3;          // 0..31 staging row (+32 on 2nd it)
    const int sg8  = (tid & 7) * 8;     // 8-col group

    const long base = (long)b * 2048;
    const int  tcs  = c * CLEN;

    for (int sc = 0; sc < 4; ++sc) {
        const int t0 = tcs + sc * 64;

        // ---- A: stage x/B/C + dt ----------------------------------------
#pragma unroll
        for (int it = 0; it < 2; ++it) {
            int r = rr + it * 32;
            const bf16* row = &xc[(base + t0 + r) * (long)CONV_DIM];
            bf16x8 xv = *(const bf16x8*)&row[h * 64 + sg8];
            *(int4*)&B_s[r][sg8] = *(const int4*)&row[1024 + sg8];
            *(int4*)&C_s[r][sg8] = *(const int4*)&row[1088 + sg8];
#pragma unroll
            for (int j = 0; j < 8; ++j) XT[sg8 + j][r] = ((short*)&xv)[j];
        }
        if (tid < 64) dt_l[tid] = dtv[((base + t0 + tid) << 4) + h];
        __syncthreads();

        // ---- B: inclusive cumsum of dt (wave 0) -------------------------
        if (wave == 0) {
            float d = dt_l[lane];
#pragma unroll
            for (int off = 1; off < 64; off <<= 1) {
                float u = __shfl_up(d, off);
                if (lane >= off) d += u;
            }
            cs_s[lane] = d;
        }
        __syncthreads();

        // ---- C: stage BTw[n][s] = B[s][n] * w_s -------------------------
        {
            float cs63 = cs_s[63];
#pragma unroll
            for (int it = 0; it < 2; ++it) {
                int s = rr + it * 32;
                float ws = expf(aexp * (cs_s[s] - cs63)) * dt_l[s];
                bf16x8 bv = *(const bf16x8*)&B_s[s][sg8];
#pragma unroll
                for (int j = 0; j < 8; ++j) BTw[sg8 + j][s] = f2bs((float)bv[j] * ws);
            }
        }
        __syncthreads();

        // ---- D: CB^T = B @ C^T  -> mask -> P (hi into P_s, lo into B_s) -
        float pD[4][4];
        {
            const int sb = wave * 16;
            f32x4 acc[4];
#pragma unroll
            for (int tt = 0; tt < 4; ++tt) acc[tt] = f32x4{0.f, 0.f, 0.f, 0.f};
#pragma unroll
            for (int kst = 0; kst < 2; ++kst) {
                bf16x8 aB = *(const bf16x8*)&B_s[sb + l15][kst * 32 + quad * 8];
#pragma unroll
                for (int tt = 0; tt < 4; ++tt) {
                    bf16x8 wC = *(const bf16x8*)&C_s[tt * 16 + l15][kst * 32 + quad * 8];
                    acc[tt] = __builtin_amdgcn_mfma_f32_16x16x32_bf16(aB, wC, acc[tt], 0, 0, 0);
                }
            }
            float csS[4], dtS[4];
            int sIdx[4];
#pragma unroll
            for (int r = 0; r < 4; ++r) {
                sIdx[r] = sb + quad * 4 + r;
                csS[r] = cs_s[sIdx[r]];
                dtS[r] = dt_l[sIdx[r]];
            }
#pragma unroll
            for (int tt = 0; tt < 4; ++tt) {
                int t = tt * 16 + l15;
                float csT = cs_s[t];
#pragma unroll
                for (int r = 0; r < 4; ++r) {
                    float m = (sIdx[r] <= t) ? expf(aexp * (csS[r] - csT)) * dtS[r] : 0.f;
                    pD[tt][r] = acc[tt][r] * m;
                }
            }
        }
        __syncthreads();   // all reads of B_s done before P_lo overwrite
        {
            const int sb = wave * 16;
#pragma unroll
            for (int tt = 0; tt < 4; ++tt) {
                int t = tt * 16 + l15;
#pragma unroll
                for (int r = 0; r < 4; ++r) {
                    int s = sb + quad * 4 + r;
                    short hb = f2bs(pD[tt][r]);
                    P_s[t][s] = hb;
                    B_s[t][s] = f2bs(pD[tt][r] - bs2f(hb));   // P_lo
                }
            }
        }
        __syncthreads();

        // ---- E: Y = G[t]*(C @ Srun^T) + (P_hi+P_lo) @ X^T + D*x -> ysb --
        {
            const int tb = wave * 16;
            f32x4 acc[4];
#pragma unroll
            for (int pp = 0; pp < 4; ++pp) acc[pp] = f32x4{0.f, 0.f, 0.f, 0.f};
            if (sc > 0) {
#pragma unroll
                for (int kst = 0; kst < 2; ++kst) {
                    bf16x8 aC = *(const bf16x8*)&C_s[tb + l15][kst * 32 + quad * 8];
#pragma unroll
                    for (int pp = 0; pp < 4; ++pp) {
                        bf16x8 wH = *(const bf16x8*)&hi_s[pp * 16 + l15][kst * 32 + quad * 8];
                        acc[pp] = __builtin_amdgcn_mfma_f32_16x16x32_bf16(aC, wH, acc[pp], 0, 0, 0);
                        bf16x8 wL = *(const bf16x8*)&lo_s[pp * 16 + l15][kst * 32 + quad * 8];
                        acc[pp] = __builtin_amdgcn_mfma_f32_16x16x32_bf16(aC, wL, acc[pp], 0, 0, 0);
                    }
                }
#pragma unroll
                for (int r = 0; r < 4; ++r) {
                    float g = expf(-aexp * cs_s[tb + quad * 4 + r]);
#pragma unroll
                    for (int pp = 0; pp < 4; ++pp) acc[pp][r] *= g;
                }
            }
#pragma unroll
            for (int kst = 0; kst < 2; ++kst) {
                bf16x8 aPh = *(const bf16x8*)&P_s[tb + l15][kst * 32 + quad * 8];
                bf16x8 aPl = *(const bf16x8*)&B_s[tb + l15][kst * 32 + quad * 8];
#pragma unroll
                for (int pp = 0; pp < 4; ++pp) {
                    bf16x8 wX = *(const bf16x8*)&XT[pp * 16 + l15][kst * 32 + quad * 8];
                    acc[pp] = __builtin_amdgcn_mfma_f32_16x16x32_bf16(aPh, wX, acc[pp], 0, 0, 0);
                    acc[pp] = __builtin_amdgcn_mfma_f32_16x16x32_bf16(aPl, wX, acc[pp], 0, 0, 0);
                }
            }
            // epilogue: + D*x, write ysb (reuse P_s as [t][p]); wave w only
            // touches rows [tb, tb+16) which it alone read as A-frags.
#pragma unroll
            for (int pp = 0; pp < 4; ++pp) {
#pragma unroll
                for (int r = 0; r < 4; ++r) {
                    int t = tb + quad * 4 + r, p = pp * 16 + l15;
                    float xv = bs2f(XT[p][t]);
                    P_s[t][p] = f2bs(acc[pp][r] + Dv * xv);
                }
            }
        }
        __syncthreads();

        // ---- copy-out y + F: Sloc, Srun update --------------------------
#pragma unroll
        for (int it = 0; it < 2; ++it) {
            int r = rr + it * 32;
            *(int4*)&y[(base + t0 + r) * 1024L + h * 64 + sg8] = *(int4*)&P_s[r][sg8];
        }
        {
            const int pb = wave * 16;
            f32x4 acc2[4];
#pragma unroll
            for (int nn = 0; nn < 4; ++nn) acc2[nn] = f32x4{0.f, 0.f, 0.f, 0.f};
#pragma unroll
            for (int kst = 0; kst < 2; ++kst) {
                bf16x8 aX = *(const bf16x8*)&XT[pb + l15][kst * 32 + quad * 8];
#pragma unroll
                for (int nn = 0; nn < 4; ++nn) {
                    bf16x8 wB = *(const bf16x8*)&BTw[nn * 16 + l15][kst * 32 + quad * 8];
                    acc2[nn] = __builtin_amdgcn_mfma_f32_16x16x32_bf16(aX, wB, acc2[nn], 0, 0, 0);
                }
            }
            float Pcv = expf(-aexp * cs_s[63]);
#pragma unroll
            for (int nn = 0; nn < 4; ++nn) {
#pragma unroll
                for (int r = 0; r < 4; ++r) {
                    int p = pb + quad * 4 + r, n = nn * 16 + l15;
                    float Sn = acc2[nn][r];
                    if (sc > 0) Sn += Pcv * (bs2f(hi_s[p][n]) + bs2f(lo_s[p][n]));
                    short hb = f2bs(Sn);
                    hi_s[p][n] = hb;
                    lo_s[p][n] = f2bs(Sn - bs2f(hb));
                }
            }
        }
        __syncthreads();
    }

    // final local state -> Sl (f32 [p][n], same layout as before)
    for (int i = tid; i < 4096; i += 256) {
        int p = i >> 6, n = i & 63;
        Sl[(long)blk * 4096 + i] = bs2f(hi_s[p][n]) + bs2f(lo_s[p][n]);
    }
}

// ---------------------------------------------------------------------------
// Phase 2: sequential combine of chunk states. 128 blocks (b*16+h), 256 thr.
// ---------------------------------------------------------------------------
__global__ __launch_bounds__(256)
void k_comb(float* __restrict__ Sl, const float* __restrict__ Pc)
{
    int bh = blockIdx.x;
    int tid = threadIdx.x;
    float run[16];
#pragma unroll
    for (int i = 0; i < 16; ++i) run[i] = 0.f;
    for (int c = 0; c < NCHUNK; ++c) {
        float* ptr = Sl + ((long)(bh * NCHUNK + c)) * 4096 + tid * 16;
        float pc = Pc[bh * NCHUNK + c];
#pragma unroll
        for (int q = 0; q < 4; ++q) {
            float4 v = *(float4*)&ptr[q * 4];
            float4 init = float4{run[q*4+0], run[q*4+1], run[q*4+2], run[q*4+3]};
            run[q*4+0] = v.x + pc * run[q*4+0];
            run[q*4+1] = v.y + pc * run[q*4+1];
            run[q*4+2] = v.z + pc * run[q*4+2];
            run[q*4+3] = v.w + pc * run[q*4+3];
            *(float4*)&ptr[q * 4] = init;
        }
    }
}

// ---------------------------------------------------------------------------
// Phase 3: y[t] += Pt[t] * (C_t · Sinit). Grid 1024, 256 threads.
// ---------------------------------------------------------------------------
__global__ __launch_bounds__(256)
void k_ph3(const float* __restrict__ Sl, const bf16* __restrict__ xc,
           const float* __restrict__ Pt, bf16* __restrict__ y)
{
    const int blk = blockIdx.x;
    const int c = blk & 7, h = (blk >> 3) & 15, b = blk >> 7;
    if (c == 0) return;   // Sinit = 0

    __shared__ __align__(16) float Cs[64][64];
    __shared__ __align__(16) short ysb[64][64];
    __shared__ float Pts[64];

    const int tid = threadIdx.x;
    const int p = tid >> 2, ng = tid & 3;
    const long base = (long)b * 2048;
    const int tcs = c * CLEN;

    float Sv[16];
    const float* Sp = Sl + (long)blk * 4096 + p * 64 + ng * 16;
#pragma unroll
    for (int q = 0; q < 4; ++q) {
        float4 v = *(const float4*)&Sp[q * 4];
        Sv[q*4+0] = v.x; Sv[q*4+1] = v.y; Sv[q*4+2] = v.z; Sv[q*4+3] = v.w;
    }

    for (int tile = 0; tile < 4; ++tile) {
        const int t0 = tcs + tile * 64;
        for (int i = tid; i < 512; i += 256) {
            int r = i >> 3, sg = (i & 7) * 8;
            bf16x8 v = *(const bf16x8*)&xc[(base + t0 + r) * (long)CONV_DIM + 1088 + sg];
#pragma unroll
            for (int j = 0; j < 8; ++j) Cs[r][sg + j] = (float)v[j];
        }
        if (tid < 64) Pts[tid] = Pt[((base + t0 + tid) << 4) + h];
        __syncthreads();

#pragma unroll 4
        for (int tt = 0; tt < 64; ++tt) {
            const float4* Cq = (const float4*)&Cs[tt][ng * 16];
            float dot = 0.f;
#pragma unroll
            for (int q = 0; q < 4; ++q) {
                float4 Cv = Cq[q];
                dot += Sv[q*4+0] * Cv.x + Sv[q*4+1] * Cv.y
                     + Sv[q*4+2] * Cv.z + Sv[q*4+3] * Cv.w;
            }
            dot += __shfl_xor(dot, 1);
            dot += __shfl_xor(dot, 2);
            if (ng == 0) ysb[tt][p] = f2bs(Pts[tt] * dot);
        }
        __syncthreads();

        for (int i = tid; i < 1024; i += 256) {
            int r = i >> 4, c4 = (i & 15) * 4;
            bf16* yp = &y[(base + t0 + r) * 1024L + h * 64 + c4];
            ushort4 old = *(ushort4*)yp;
            short* corr = &ysb[r][c4];
            ushort4 nw;
            nw.x = (unsigned short)f2bs(bs2f((short)old.x) + bs2f(corr[0]));
            nw.y = (unsigned short)f2bs(bs2f((short)old.y) + bs2f(corr[1]));
            nw.z = (unsigned short)f2bs(bs2f((short)old.z) + bs2f(corr[2]));
            nw.w = (unsigned short)f2bs(bs2f((short)old.w) + bs2f(corr[3]));
            *(ushort4*)yp = nw;
        }
        __syncthreads();
    }
}

// ---------------------------------------------------------------------------
// Gate (y *= silu(z)) + RMSNorm * norm_w, in-place on y.
// ---------------------------------------------------------------------------
__global__ __launch_bounds__(256)
void k_gate(bf16* __restrict__ yp, const bf16* __restrict__ zxp,
            const float* __restrict__ nw)
{
    long bt = blockIdx.x;
    bf16* y = yp + bt * 1024;
    const bf16* z = zxp + bt * (long)D_PROJ;
    int tid = threadIdx.x;
    ushort4 zv = *(const ushort4*)&z[tid * 4];
    ushort4 yv = *(const ushort4*)&y[tid * 4];
    float g[4], ss = 0.f;
    {
        float zz0 = bs2f((short)zv.x), zz1 = bs2f((short)zv.y);
        float zz2 = bs2f((short)zv.z), zz3 = bs2f((short)zv.w);
        float yy0 = bs2f((short)yv.x), yy1 = bs2f((short)yv.y);
        float yy2 = bs2f((short)yv.z), yy3 = bs2f((short)yv.w);
        g[0] = yy0 * (zz0 / (1.f + expf(-zz0)));
        g[1] = yy1 * (zz1 / (1.f + expf(-zz1)));
        g[2] = yy2 * (zz2 / (1.f + expf(-zz2)));
        g[3] = yy3 * (zz3 / (1.f + expf(-zz3)));
        ss = g[0]*g[0] + g[1]*g[1] + g[2]*g[2] + g[3]*g[3];
    }
#pragma unroll
    for (int o = 1; o < 64; o <<= 1) ss += __shfl_xor(ss, o);
    __shared__ float red[4];
    if ((tid & 63) == 0) red[tid >> 6] = ss;
    __syncthreads();
    float tot = red[0] + red[1] + red[2] + red[3];
    float sc = rsqrtf(tot * (1.f / 1024.f) + 1e-5f);
    const float* w = nw + tid * 4;
    ushort4 ov;
    ov.x = (unsigned short)f2bs(g[0] * sc * w[0]);
    ov.y = (unsigned short)f2bs(g[1] * sc * w[1]);
    ov.z = (unsigned short)f2bs(g[2] * sc * w[2]);
    ov.w = (unsigned short)f2bs(g[3] * sc * w[3]);
    *(ushort4*)&y[tid * 4] = ov;
}

// in-place flip via swaps: rows of 1024 bf16 (128 int4)
__global__ void k_swap(bf16* __restrict__ buf, const int* __restrict__ lens)
{
    int idx = blockIdx.x * 256 + threadIdx.x;
    int v = idx & 127;
    int r = idx >> 7;
    int b = r >> 10, t = r & 1023;
    int len = lens[b];
    int t2 = len - 1 - t;
    if (t < len && t < t2) {
        int4* p = (int4*)buf;
        long i1 = ((long)b * 2048 + t)  * 128 + v;
        long i2 = ((long)b * 2048 + t2) * 128 + v;
        int4 a = p[i1], c = p[i2];
        p[i1] = c; p[i2] = a;
    }
}

// LayerNorm(out + h) * g + b -> h (in place)
__global__ __launch_bounds__(256)
void k_ln(const bf16* __restrict__ outb, bf16* __restrict__ h,
          const float* __restrict__ g, const float* __restrict__ bb)
{
    long r = (long)blockIdx.x * 512;
    int tid = threadIdx.x;
    float v0 = B2F(outb[r + tid])       + B2F(h[r + tid]);
    float v1 = B2F(outb[r + tid + 256]) + B2F(h[r + tid + 256]);
    __shared__ float red[4], red2[4];
    float s = v0 + v1;
#pragma unroll
    for (int o = 1; o < 64; o <<= 1) s += __shfl_xor(s, o);
    if ((tid & 63) == 0) red[tid >> 6] = s;
    __syncthreads();
    float mu = (red[0] + red[1] + red[2] + red[3]) * (1.f / 512.f);
    float d0 = v0 - mu, d1 = v1 - mu;
    float q = d0 * d0 + d1 * d1;
#pragma unroll
    for (int o = 1; o < 64; o <<= 1) q += __shfl_xor(q, o);
    if ((tid & 63) == 0) red2[tid >> 6] = q;
    __syncthreads();
    float var = (red2[0] + red2[1] + red2[2] + red2[3]) * (1.f / 512.f);
    float rs = rsqrtf(var + 1e-5f);
    h[r + tid]       = F2B(d0 * rs * g[tid]       + bb[tid]);
    h[r + tid + 256] = F2B(d1 * rs * g[tid + 256] + bb[tid + 256]);
}

// masked-sum pooling partials
__global__ void k_pool(const float* __restrict__ enc, const int* __restrict__ lens,
                       float* __restrict__ pooled)
{
    int bid = blockIdx.x;
    int b = bid >> 6;
    int cg = (bid >> 4) & 3, tc = bid & 15;
    int c = cg * 256 + threadIdx.x;
    int len = lens[b];
    float s = 0.f;
    int tend = tc * 128 + 128;
    for (int t = tc * 128; t < tend; ++t)
        if (t < len) s += enc[((long)b * 2048 + t) * 1024 + c];
    atomicAdd(&pooled[b * 1024 + c], s);
}

// encoder_hidden = tanh(pooled/len @ W_ad^T + b_ad)
__global__ void k_adapter(const float* __restrict__ pooled, const float* __restrict__ Wad,
                          const float* __restrict__ bad, const int* __restrict__ lens,
                          float* __restrict__ outh)
{
    int idx = blockIdx.x * 256 + threadIdx.x;
    int b = idx >> 9, j = idx & 511;
    const float* wrow = Wad + (long)j * 1024;
    const float* prow = pooled + b * 1024;
    float acc = 0.f;
    for (int k = 0; k < 1024; ++k) acc += prow[k] * wrow[k];
    int li = lens[b]; if (li < 1) li = 1;
    acc = acc / (float)li + bad[j];
    outh[idx] = tanhf(acc);
}

// ---------------------------------------------------------------------------
static void gemm(const void* A, bool af32, const int* gather, const float* W,
                 const float* bias, void* C, bool cf32,
                 int M, int N, int K, int ldc, int coff, hipStream_t s)
{
    dim3 grid((N + 127) / 128, M / 128);
    if (af32) {
        if (cf32) k_gemm<true,  true ><<<grid, 256, 0, s>>>(A, gather, W, bias, C, M, N, K, ldc, coff);
        else      k_gemm<true,  false><<<grid, 256, 0, s>>>(A, gather, W, bias, C, M, N, K, ldc, coff);
    } else {
        if (cf32) k_gemm<false, true ><<<grid, 256, 0, s>>>(A, gather, W, bias, C, M, N, K, ldc, coff);
        else      k_gemm<false, false><<<grid, 256, 0, s>>>(A, gather, W, bias, C, M, N, K, ldc, coff);
    }
}

static void gemm_bf(const bf16* A, const int* gather, const bf16* Wb, const float* bias,
                    void* C, bool cf32, int M, int N, int K, int ldc, int coff, hipStream_t s)
{
    dim3 grid((N + 127) / 128, M / 128);
    if (cf32) k_gemm_bf<true ><<<grid, 256, 0, s>>>(A, gather, Wb, bias, C, M, N, K, ldc, coff);
    else      k_gemm_bf<false><<<grid, 256, 0, s>>>(A, gather, Wb, bias, C, M, N, K, ldc, coff);
}

extern "C" void kernel_launch(void* const* d_in, const int* in_sizes, int n_in,
                              void* d_out, int out_size, void* d_ws, size_t ws_size,
                              hipStream_t stream)
{
    const int*   tok    = (const int*)d_in[0];
    const int*   lens   = (const int*)d_in[1];
    const float* emb    = (const float*)d_in[2];
    const float* W_inp  = (const float*)d_in[3];
    const float* b_inp  = (const float*)d_in[4];
    const float* m_Win  = (const float*)d_in[5];
    const float* m_convw= (const float*)d_in[6];
    const float* m_convb= (const float*)d_in[7];
    const float* m_dtb  = (const float*)d_in[8];
    const float* m_Alog = (const float*)d_in[9];
    const float* m_D    = (const float*)d_in[10];
    const float* m_norm = (const float*)d_in[11];
    const float* m_Wout = (const float*)d_in[12];
    const float* blk_Wo = (const float*)d_in[13];
    const float* blk_bo = (const float*)d_in[14];
    const float* ln_g   = (const float*)d_in[15];
    const float* ln_b   = (const float*)d_in[16];
    const float* W_enc  = (const float*)d_in[17];
    const float* b_enc  = (const float*)d_in[18];
    const float* W_ad   = (const float*)d_in[19];
    const float* b_ad   = (const float*)d_in[20];

    char* ws = (char*)d_ws;
    bf16*  h      = (bf16*)(ws + OFF_H);
    bf16*  zx     = (bf16*)(ws + OFF_ZX);
    bf16*  xc     = (bf16*)(ws + OFF_XC);
    float* Sl     = (float*)(ws + OFF_S);
    float* Pt     = (float*)(ws + OFF_PT);
    float* Pc     = (float*)(ws + OFF_PC);
    float* dtv    = (float*)(ws + OFF_DTV);
    float* dAv    = (float*)(ws + OFF_DAV);
    int*   gidx   = (int*)(ws + OFF_GIDX);
    float* pooled = (float*)(ws + OFF_POOL);

    float* dout   = (float*)d_out;
    bf16*  y_f    = (bf16*)d_out;                        // 33.55 MB
    bf16*  y_b    = (bf16*)d_out + (size_t)16384 * 1024; // next 33.55 MB
    bf16*  comb   = (bf16*)(ws + OFF_ZX);                // alias zx (dead after gates)
    bf16*  outbuf = (bf16*)(ws + OFF_XC);                // alias xc (dead after ph3 bwd)

    // bf16 weight cache (fast GEMM path); fallback to legacy path if ws too small
    const bool fast = ws_size >= (size_t)(OFF_WBF + WBF_BYTES);
    bf16* wWin  = fast ? (bf16*)(ws + OFF_WBF + WBF_WIN)  : nullptr;
    bf16* wWout = fast ? (bf16*)(ws + OFF_WBF + WBF_WOUT) : nullptr;
    bf16* wBlk  = fast ? (bf16*)(ws + OFF_WBF + WBF_BLK)  : nullptr;
    bf16* wEnc  = fast ? (bf16*)(ws + OFF_WBF + WBF_ENC)  : nullptr;
    if (fast) {
        k_wcvt<<<(1122304 + 255) / 256, 256, 0, stream>>>(m_Win,  wWin,  1122304); // 8*2192*512/8
        k_wcvt<<<( 524288 + 255) / 256, 256, 0, stream>>>(m_Wout, wWout,  524288); // 8*512*1024/8
        k_wcvt<<<( 262144 + 255) / 256, 256, 0, stream>>>(blk_Wo, wBlk,   262144); // 4*512*1024/8
        k_wcvt<<<(  65536 + 255) / 256, 256, 0, stream>>>(W_enc,  wEnc,    65536); // 1024*512/8
    }

    k_mkidx<<<64, 256, 0, stream>>>(lens, gidx);

    // h = emb[tok] @ W_inp^T + b_inp   (f32 A + token gather: legacy path)
    gemm(emb, true, tok, W_inp, b_inp, h, false, 16384, 512, 512, 512, 0, stream);

    for (int l = 0; l < 4; ++l) {
        for (int dir = 0; dir < 2; ++dir) {
            const float* Wi = m_Win  + (size_t)(l * 2 + dir) * D_PROJ * 512;
            const float* cw = m_convw + (size_t)(l * 2 + dir) * CONV_DIM * 4;
            const float* cbp= m_convb + (size_t)(l * 2 + dir) * CONV_DIM;
            const float* dtb= m_dtb  + l * 32 + dir * 16;
            const float* alg= m_Alog + l * 32 + dir * 16;
            const float* Dpp= m_D    + l * 32 + dir * 16;
            const float* nw = m_norm + (size_t)(l * 2 + dir) * 1024;
            bf16* y = dir ? y_b : y_f;

            if (fast)
                gemm_bf(h, dir ? gidx : nullptr, wWin + (size_t)(l * 2 + dir) * D_PROJ * 512,
                        nullptr, zx, false, 16384, D_PROJ, 512, D_PROJ, 0, stream);
            else
                gemm(h, false, dir ? gidx : nullptr, Wi, nullptr, zx, false,
                     16384, D_PROJ, 512, D_PROJ, 0, stream);
            k_conv<<<9216, 256, 0, stream>>>(zx, cw, cbp, xc);
            k_dt<<<1024, 256, 0, stream>>>(zx, dtb, alg, dtv, dAv);
            k_cum<<<1024, 256, 0, stream>>>(dAv, Pt, Pc);
            k_ph1<<<1024, 256, 0, stream>>>(xc, dtv, alg, Dpp, y, Sl);
            k_comb<<<128, 256, 0, stream>>>(Sl, Pc);
            k_ph3<<<1024, 256, 0, stream>>>(Sl, xc, Pt, y);
            k_gate<<<16384, 256, 0, stream>>>(y, zx, nw);
            if (dir) k_swap<<<4096, 256, 0, stream>>>(y_b, lens);
        }

        // out-projections into comb halves (comb aliases dead zx)
        if (fast) {
            gemm_bf(y_f, nullptr, wWout + (size_t)(l * 2 + 0) * 512 * 1024, nullptr, comb,
                    false, 16384, 512, 1024, 1024, 0, stream);
            gemm_bf(y_b, nullptr, wWout + (size_t)(l * 2 + 1) * 512 * 1024, nullptr, comb,
                    false, 16384, 512, 1024, 1024, 512, stream);
            gemm_bf(comb, nullptr, wBlk + (size_t)l * 512 * 1024, blk_bo + l * 512, outbuf,
                    false, 16384, 512, 1024, 512, 0, stream);
        } else {
            gemm(y_f, false, nullptr, m_Wout + (size_t)(l * 2 + 0) * 512 * 1024, nullptr, comb,
                 false, 16384, 512, 1024, 1024, 0, stream);
            gemm(y_b, false, nullptr, m_Wout + (size_t)(l * 2 + 1) * 512 * 1024, nullptr, comb,
                 false, 16384, 512, 1024, 1024, 512, stream);
            gemm(comb, false, nullptr, blk_Wo + (size_t)l * 512 * 1024, blk_bo + l * 512, outbuf,
                 false, 16384, 512, 1024, 512, 0, stream);
        }
        // residual + layernorm -> h
        k_ln<<<16384, 256, 0, stream>>>(outbuf, h, ln_g + l * 512, ln_b + l * 512);
    }

    // encoder_outputs = h @ W_enc^T + b_enc -> d_out f32 (y_f/y_b dead)
    if (fast)
        gemm_bf(h, nullptr, wEnc, b_enc, dout, true, 16384, 1024, 512, 1024, 0, stream);
    else
        gemm(h, false, nullptr, W_enc, b_enc, dout, true, 16384, 1024, 512, 1024, 0, stream);

    hipMemsetAsync(pooled, 0, 8 * 1024 * sizeof(float), stream);
    k_pool<<<512, 256, 0, stream>>>(dout, lens, pooled);
    k_adapter<<<16, 256, 0, stream>>>(pooled, W_ad, b_ad, lens, dout + (size_t)16384 * 1024);
}

// Round 4
// 3022.501 us; speedup vs baseline: 1.8717x; 1.1718x over previous
//
#include <hip/hip_runtime.h>
#include <hip/hip_bf16.h>
#include <math.h>

using bf16 = __hip_bfloat16;
typedef __bf16 bf16x8 __attribute__((ext_vector_type(8)));
typedef float f32x4 __attribute__((ext_vector_type(4)));

#define B2F(x) __bfloat162float(x)
#define F2B(x) __float2bfloat16(x)

__device__ inline short f2bs(float x) { bf16 b = F2B(x); return *(short*)&b; }
__device__ inline float bs2f(short x) { bf16 b; *(short*)&b = x; return B2F(b); }

// Problem constants: B=8, L=2048, H=512, D_INNER=1024, NH=16, P=64, N=64
static constexpr int D_PROJ = 2192, CONV_DIM = 1152;
static constexpr int NCHUNK = 8, CLEN = 256;   // 8 chunks x 256 steps

// Workspace layout (bytes). y_f/y_b live in d_out (67.1 MB).
static constexpr size_t OFF_H    = 0;                    // 16384x512  bf16  16.8 MB
static constexpr size_t OFF_ZX   = 16777216;             // 16384x2192 bf16  71.8 MB (comb aliases)
static constexpr size_t OFF_XC   = 88604672;             // 16384x1152 bf16  37.7 MB (outbuf aliases)
static constexpr size_t OFF_S    = 126353408;            // 1024x4096  f32   16.8 MB
static constexpr size_t OFF_PT   = 143130624;            // 16384x16   f32    1.0 MB
static constexpr size_t OFF_PC   = 144179200;            // 1024       f32    4 KB
static constexpr size_t OFF_DTV  = 144183296;            // 16384x16   f32    1.0 MB
static constexpr size_t OFF_DAV  = 145231872;            // 16384x16   f32    1.0 MB
static constexpr size_t OFF_GIDX = 146280448;            // 16384      i32
static constexpr size_t OFF_POOL = 146345984;            // 8x1024     f32 (ends 146378752)
// bf16 weight cache (one-time conversion). Guarded by ws_size with full fallback.
static constexpr size_t OFF_WBF   = 146378752;
static constexpr size_t WBF_WIN   = 0;          // 8 x 2192x512 bf16 = 17,956,864
static constexpr size_t WBF_WOUT  = 17956864;   // 8 x 512x1024 bf16 =  8,388,608
static constexpr size_t WBF_BLK   = 26345472;   // 4 x 512x1024 bf16 =  4,194,304
static constexpr size_t WBF_ENC   = 30539776;   // 1024x512     bf16 =  1,048,576
static constexpr size_t WBF_BYTES = 31588352;

// ---------------------------------------------------------------------------
// f32 -> bf16 weight conversion (one-time per launch)
// ---------------------------------------------------------------------------
__global__ void k_wcvt(const float* __restrict__ src, bf16* __restrict__ dst, long n8)
{
    long i = (long)blockIdx.x * 256 + threadIdx.x;
    if (i >= n8) return;
    const float4* s = (const float4*)(src + i * 8);
    float4 f0 = s[0], f1 = s[1];
    short o[8];
    o[0] = f2bs(f0.x); o[1] = f2bs(f0.y); o[2] = f2bs(f0.z); o[3] = f2bs(f0.w);
    o[4] = f2bs(f1.x); o[5] = f2bs(f1.y); o[6] = f2bs(f1.z); o[7] = f2bs(f1.w);
    *(int4*)&dst[i * 8] = *(int4*)o;
}

// ---------------------------------------------------------------------------
// async global->LDS, 16B per lane (wave-uniform LDS base + lane*16 dest)
// ---------------------------------------------------------------------------
__device__ inline void gl_lds16(const void* g, void* l)
{
    __builtin_amdgcn_global_load_lds(
        (const __attribute__((address_space(1))) unsigned int*)g,
        (__attribute__((address_space(3))) unsigned int*)l,
        16, 0, 0);
}

// ---------------------------------------------------------------------------
// Fast MFMA GEMM (bf16 A, bf16 W): C[M,N] = A[M,K] @ W[N,K]^T + bias
// ---------------------------------------------------------------------------
template<bool CF32>
__global__ __launch_bounds__(256, 2)
void k_gemm_bf(const bf16* __restrict__ A, const int* __restrict__ gatherIdx,
               const bf16* __restrict__ Wb, const float* __restrict__ bias,
               void* __restrict__ Cp, int M, int N, int K, int ldc, int coff)
{
    __shared__ union UU {
        struct { __align__(16) short As[128 * 64]; __align__(16) short Bs[128 * 64]; } ab;
        __align__(16) short Cs2[128 * 136];                 // bf16 epilogue
        __align__(16) float Cs4[CF32 ? 128 * 132 : 4];      // f32 epilogue
    } u;

    const int tid  = threadIdx.x;
    const int m0   = blockIdx.y * 128;
    const int n0   = blockIdx.x * 128;
    const int wave = tid >> 6, lane = tid & 63;
    const int l15  = lane & 15, quad = lane >> 4;
    const int wm   = (wave & 1) * 64, wn = (wave >> 1) * 64;

    const int sr   = lane >> 3;   // 0..7 sub-row within the 8-row chunk
    const int slot = lane & 7;    // 16B slot within row
    const bf16* asrc[4];
    const bf16* bsrc[4];
    int ldsoff[4];
#pragma unroll
    for (int t = 0; t < 4; ++t) {
        int row = wave * 32 + t * 8 + sr;            // 0..127
        long arow = m0 + row;
        if (gatherIdx) arow = gatherIdx[m0 + row];
        int sl = ((slot ^ (row & 7)) * 8);           // swizzled source col (elems)
        asrc[t] = A + arow * (long)K + sl;
        int wr = n0 + row; if (wr > N - 1) wr = N - 1;   // clamp; garbage cols never stored
        bsrc[t] = Wb + (long)wr * K + sl;
        ldsoff[t] = (wave * 32 + t * 8) * 64;        // shorts, wave-uniform
    }

    int aoff[2][4], boff[2][4];
#pragma unroll
    for (int ks = 0; ks < 2; ++ks) {
        int swz = (((ks << 2) | quad) ^ (l15 & 7)) * 8;
#pragma unroll
        for (int i = 0; i < 4; ++i) {
            aoff[ks][i] = (wm + i * 16 + l15) * 64 + swz;
            boff[ks][i] = (wn + i * 16 + l15) * 64 + swz;
        }
    }

    f32x4 acc[4][4];
#pragma unroll
    for (int i = 0; i < 4; ++i)
#pragma unroll
        for (int j = 0; j < 4; ++j) acc[i][j] = f32x4{0.f, 0.f, 0.f, 0.f};

    for (int k0 = 0; k0 < K; k0 += 64) {
#pragma unroll
        for (int t = 0; t < 4; ++t) gl_lds16(asrc[t] + k0, &u.ab.As[ldsoff[t]]);
#pragma unroll
        for (int t = 0; t < 4; ++t) gl_lds16(bsrc[t] + k0, &u.ab.Bs[ldsoff[t]]);
        __syncthreads();   // drains vmcnt(0): LDS tile ready

        bf16x8 af[2][4], bfr[2][4];
#pragma unroll
        for (int ks = 0; ks < 2; ++ks)
#pragma unroll
            for (int i = 0; i < 4; ++i) {
                af[ks][i]  = *(const bf16x8*)&u.ab.As[aoff[ks][i]];
                bfr[ks][i] = *(const bf16x8*)&u.ab.Bs[boff[ks][i]];
            }
#pragma unroll
        for (int ks = 0; ks < 2; ++ks)
#pragma unroll
            for (int i = 0; i < 4; ++i)
#pragma unroll
                for (int j = 0; j < 4; ++j)
                    acc[i][j] = __builtin_amdgcn_mfma_f32_16x16x32_bf16(af[ks][i], bfr[ks][j], acc[i][j], 0, 0, 0);
        __syncthreads();
    }

    __syncthreads();
    if (!CF32) {
#pragma unroll
        for (int j = 0; j < 4; ++j) {
            int lcol = wn + j * 16 + l15;
            int gcol = n0 + lcol;
            float bvv = (bias && gcol < N) ? bias[gcol] : 0.f;
#pragma unroll
            for (int i = 0; i < 4; ++i)
#pragma unroll
                for (int r = 0; r < 4; ++r)
                    u.Cs2[(wm + i * 16 + quad * 4 + r) * 136 + lcol] = f2bs(acc[i][j][r] + bvv);
        }
        __syncthreads();
        for (int i2 = tid; i2 < 2048; i2 += 256) {
            int lrow = i2 >> 4, seg = i2 & 15;
            int col0 = n0 + seg * 8;
            if (col0 < N) {
                int4 v = *(int4*)&u.Cs2[lrow * 136 + seg * 8];
                *(int4*)&((bf16*)Cp)[(long)(m0 + lrow) * ldc + coff + col0] = v;
            }
        }
    } else {
#pragma unroll
        for (int j = 0; j < 4; ++j) {
            int lcol = wn + j * 16 + l15;
            int gcol = n0 + lcol;
            float bvv = (bias && gcol < N) ? bias[gcol] : 0.f;
#pragma unroll
            for (int i = 0; i < 4; ++i)
#pragma unroll
                for (int r = 0; r < 4; ++r)
                    u.Cs4[(wm + i * 16 + quad * 4 + r) * 132 + lcol] = acc[i][j][r] + bvv;
        }
        __syncthreads();
        for (int i2 = tid; i2 < 4096; i2 += 256) {
            int lrow = i2 >> 5, seg = i2 & 31;
            int col0 = n0 + seg * 4;
            if (col0 < N) {
                int4 v = *(int4*)&u.Cs4[lrow * 132 + seg * 4];
                *(int4*)&((float*)Cp)[(long)(m0 + lrow) * ldc + coff + col0] = v;
            }
        }
    }
}

// ---------------------------------------------------------------------------
// Legacy MFMA GEMM (f32 A + gather): embedding GEMM and full fallback.
// ---------------------------------------------------------------------------
template<bool AF32, bool CF32>
__global__ __launch_bounds__(256, 2)
void k_gemm(const void* __restrict__ Ap, const int* __restrict__ gatherIdx,
            const float* __restrict__ W, const float* __restrict__ bias,
            void* __restrict__ Cp, int M, int N, int K, int ldc, int coff)
{
    __shared__ union UU {
        struct { __align__(16) short As[128 * 40]; __align__(16) short Bs[128 * 40]; } ab;
        __align__(16) short Cs2[128 * 136];
        __align__(16) float Cs4[CF32 ? 128 * 132 : 4];
    } u;

    const int tid  = threadIdx.x;
    const int m0   = blockIdx.y * 128;
    const int n0   = blockIdx.x * 128;
    const int wave = tid >> 6, lane = tid & 63;
    const int l15  = lane & 15, quad = lane >> 4;
    const int wm   = (wave & 1) * 64, wn = (wave >> 1) * 64;

    f32x4 acc[4][4];
#pragma unroll
    for (int i = 0; i < 4; ++i)
#pragma unroll
        for (int j = 0; j < 4; ++j) acc[i][j] = f32x4{0.f, 0.f, 0.f, 0.f};

    const int srow = tid >> 2;
    const int scol = (tid & 3) * 8;

    union V8 { int4 i4; short s[8]; };

    for (int k0 = 0; k0 < K; k0 += 32) {
        V8 av[2], bv[2];
#pragma unroll
        for (int it = 0; it < 2; ++it) {
            int r = srow + it * 64;
            long arow = m0 + r;
            if (gatherIdx) arow = gatherIdx[m0 + r];
            if (AF32) {
                const float* ap = (const float*)Ap + arow * (long)K + k0 + scol;
                float4 f0 = *(const float4*)ap;
                float4 f1 = *(const float4*)(ap + 4);
                av[it].s[0] = f2bs(f0.x); av[it].s[1] = f2bs(f0.y);
                av[it].s[2] = f2bs(f0.z); av[it].s[3] = f2bs(f0.w);
                av[it].s[4] = f2bs(f1.x); av[it].s[5] = f2bs(f1.y);
                av[it].s[6] = f2bs(f1.z); av[it].s[7] = f2bs(f1.w);
            } else {
                av[it].i4 = *(const int4*)((const bf16*)Ap + arow * (long)K + k0 + scol);
            }
            int wr = n0 + r;
            if (wr < N) {
                const float* wp = W + (long)wr * K + k0 + scol;
                float4 f0 = *(const float4*)wp;
                float4 f1 = *(const float4*)(wp + 4);
                bv[it].s[0] = f2bs(f0.x); bv[it].s[1] = f2bs(f0.y);
                bv[it].s[2] = f2bs(f0.z); bv[it].s[3] = f2bs(f0.w);
                bv[it].s[4] = f2bs(f1.x); bv[it].s[5] = f2bs(f1.y);
                bv[it].s[6] = f2bs(f1.z); bv[it].s[7] = f2bs(f1.w);
            } else {
                bv[it].i4 = int4{0, 0, 0, 0};
            }
        }
        __syncthreads();
#pragma unroll
        for (int it = 0; it < 2; ++it) {
            int r = srow + it * 64;
            *(int4*)&u.ab.As[r * 40 + scol] = av[it].i4;
            *(int4*)&u.ab.Bs[r * 40 + scol] = bv[it].i4;
        }
        __syncthreads();

        bf16x8 af[4], bfr[4];
#pragma unroll
        for (int i = 0; i < 4; ++i)
            af[i] = *(const bf16x8*)&u.ab.As[(wm + i * 16 + l15) * 40 + quad * 8];
#pragma unroll
        for (int j = 0; j < 4; ++j)
            bfr[j] = *(const bf16x8*)&u.ab.Bs[(wn + j * 16 + l15) * 40 + quad * 8];
#pragma unroll
        for (int i = 0; i < 4; ++i)
#pragma unroll
            for (int j = 0; j < 4; ++j)
                acc[i][j] = __builtin_amdgcn_mfma_f32_16x16x32_bf16(af[i], bfr[j], acc[i][j], 0, 0, 0);
    }

    __syncthreads();
    if (!CF32) {
#pragma unroll
        for (int j = 0; j < 4; ++j) {
            int lcol = wn + j * 16 + l15;
            int gcol = n0 + lcol;
            float bvv = (bias && gcol < N) ? bias[gcol] : 0.f;
#pragma unroll
            for (int i = 0; i < 4; ++i)
#pragma unroll
                for (int r = 0; r < 4; ++r)
                    u.Cs2[(wm + i * 16 + quad * 4 + r) * 136 + lcol] = f2bs(acc[i][j][r] + bvv);
        }
        __syncthreads();
        for (int i2 = tid; i2 < 2048; i2 += 256) {
            int lrow = i2 >> 4, seg = i2 & 15;
            int col0 = n0 + seg * 8;
            if (col0 < N) {
                int4 v = *(int4*)&u.Cs2[lrow * 136 + seg * 8];
                *(int4*)&((bf16*)Cp)[(long)(m0 + lrow) * ldc + coff + col0] = v;
            }
        }
    } else {
#pragma unroll
        for (int j = 0; j < 4; ++j) {
            int lcol = wn + j * 16 + l15;
            int gcol = n0 + lcol;
            float bvv = (bias && gcol < N) ? bias[gcol] : 0.f;
#pragma unroll
            for (int i = 0; i < 4; ++i)
#pragma unroll
                for (int r = 0; r < 4; ++r)
                    u.Cs4[(wm + i * 16 + quad * 4 + r) * 132 + lcol] = acc[i][j][r] + bvv;
        }
        __syncthreads();
        for (int i2 = tid; i2 < 4096; i2 += 256) {
            int lrow = i2 >> 5, seg = i2 & 31;
            int col0 = n0 + seg * 4;
            if (col0 < N) {
                int4 v = *(int4*)&u.Cs4[lrow * 132 + seg * 4];
                *(int4*)&((float*)Cp)[(long)(m0 + lrow) * ldc + coff + col0] = v;
            }
        }
    }
}

// ---------------------------------------------------------------------------
// flip row map
// ---------------------------------------------------------------------------
__global__ void k_mkidx(const int* __restrict__ lens, int* __restrict__ gidx)
{
    int idx = blockIdx.x * 256 + threadIdx.x;  // 16384
    int b = idx >> 11, t = idx & 2047;
    int len = lens[b];
    gidx[idx] = b * 2048 + ((t < len) ? (len - 1 - t) : t);
}

// ---------------------------------------------------------------------------
// Depthwise causal conv(k=4)+bias+silu: zx[:,1024:2176] -> xc[16384][1152] bf16
// Register-resident weights: each thread owns a fixed 8-channel group across
// 256 timesteps (16 iters x 16 rows). Grid 576 = 9 ch-macroblocks x 64 chunks.
// Kills the per-row 40-scalar-gather pattern (was latency-bound at 139 us).
// ---------------------------------------------------------------------------
__global__ __launch_bounds__(256)
void k_conv(const bf16* __restrict__ zx, const float* __restrict__ w,
            const float* __restrict__ cb, bf16* __restrict__ xc)
{
    const int bid = blockIdx.x;          // 0..575
    const int mb  = bid % 9;             // channel macroblock (16 c8-groups)
    const int seg = bid / 9;             // 0..63
    const int b   = seg >> 3, tch = seg & 7;
    const int c0  = (mb * 16 + (threadIdx.x & 15)) * 8;   // 8-ch group, fixed
    const int trow = threadIdx.x >> 4;   // 0..15

    // weights/bias in registers, loaded once (amortized over 256 timesteps)
    float wr[4][8], cbr[8];
#pragma unroll
    for (int i = 0; i < 8; i += 4) {
        float4 cv = *(const float4*)&cb[c0 + i];
        cbr[i] = cv.x; cbr[i+1] = cv.y; cbr[i+2] = cv.z; cbr[i+3] = cv.w;
    }
#pragma unroll
    for (int i = 0; i < 8; ++i) {
        float4 wv = *(const float4*)&w[(c0 + i) * 4];   // all 4 taps, channel c0+i
        wr[0][i] = wv.x; wr[1][i] = wv.y; wr[2][i] = wv.z; wr[3][i] = wv.w;
    }

    const long base = (long)b * 2048 + tch * 256;
    for (int it = 0; it < 16; ++it) {
        const int t = it * 16 + trow;          // 0..255 within chunk
        const long bt = base + t;
        const int tseq = tch * 256 + t;        // timestep within sequence
        float acc[8];
#pragma unroll
        for (int i = 0; i < 8; ++i) acc[i] = cbr[i];
#pragma unroll
        for (int j = 0; j < 4; ++j) {
            if (tseq >= 3 - j) {
                bf16x8 v = *(const bf16x8*)&zx[(bt - 3 + j) * (long)D_PROJ + 1024 + c0];
#pragma unroll
                for (int i = 0; i < 8; ++i) acc[i] += wr[j][i] * (float)v[i];
            }
        }
        short out[8];
#pragma unroll
        for (int i = 0; i < 8; ++i) {
            float a = acc[i];
            out[i] = f2bs(a / (1.f + expf(-a)));
        }
        *(int4*)&xc[bt * (long)CONV_DIM + c0] = *(int4*)out;
    }
}

// ---------------------------------------------------------------------------
// dt = softplus(raw + bias); dA = exp(-exp(Alog)*dt). One dir per launch.
// ---------------------------------------------------------------------------
__global__ void k_dt(const bf16* __restrict__ zx, const float* __restrict__ dtb,
                     const float* __restrict__ alog,
                     float* __restrict__ dtv, float* __restrict__ dAv)
{
    int idx = blockIdx.x * 256 + threadIdx.x;   // 16384*16
    int hh = idx & 15;
    long bt = idx >> 4;
    float x  = B2F(zx[bt * (long)D_PROJ + 2176 + hh]) + dtb[hh];
    float sp = (x > 20.f) ? x : log1pf(expf(x));
    dtv[idx] = sp;
    dAv[idx] = expf(-expf(alog[hh]) * sp);
}

// ---------------------------------------------------------------------------
// Inclusive cumprod of dA within each chunk -> Pt; chunk totals -> Pc.
// ---------------------------------------------------------------------------
__global__ __launch_bounds__(256)
void k_cum(const float* __restrict__ dAv, float* __restrict__ Pt,
           float* __restrict__ Pc)
{
    int blk = blockIdx.x;
    int c = blk & 7, h = (blk >> 3) & 15, b = blk >> 7;
    int tid = threadIdx.x;
    int t = c * CLEN + tid;
    long gi = ((long)(b * 2048 + t) << 4) + h;
    float v = dAv[gi];
    __shared__ float sa[256], sb[256];
    sa[tid] = v; __syncthreads();
    float* src = sa; float* dst = sb;
    for (int off = 1; off < 256; off <<= 1) {
        float x = src[tid];
        if (tid >= off) x *= src[tid - off];
        dst[tid] = x;
        __syncthreads();
        float* tp = src; src = dst; dst = tp;
    }
    float incl = src[tid];
    Pt[gi] = incl;
    if (tid == 255) Pc[blk] = incl;
}

// ---------------------------------------------------------------------------
// Phase 1 (MFMA chunked form). One workgroup per (b, h, 256-super-chunk).
// 4 sequential sub-chunks of Q=64; per sub-chunk, 64x64x64 MFMA matmuls:
//   CB^T = B @ C^T      (k = n)
//   P[t][s] = CB[t][s] * exp(aexp*(cs_s - cs_t)) * dt_s   (s <= t, else 0)
//     stored as bf16 hi/lo pair (P_s + B_s reuse) for ~f32 precision
//   Y     = G[t]*(C @ Srun^T) + P @ X^T  (+ D*x)          (Srun = bf16 hi/lo)
//   Sloc  = X^T @ (B*w)^T;  Srun = Pc*Srun + Sloc
// Fragment layouts identical to the verified k_gemm_bf (A rows=M,k; W rows=N,k;
// C/D: row = quad*4+r, col = l15).
// ---------------------------------------------------------------------------
__global__ __launch_bounds__(256, 2)
void k_ph1(const bf16* __restrict__ xc, const float* __restrict__ dtv,
           const float* __restrict__ alog, const float* __restrict__ Dp,
           bf16* __restrict__ y, float* __restrict__ Sl)
{
    const int blk = blockIdx.x;
    const int c = blk & 7, h = (blk >> 3) & 15, b = blk >> 7;
    const float Dv   = Dp[h];
    const float aexp = expf(alog[h]);

    // stride 72 shorts = 144 B (16B-aligned rows, non-pow2 bank spread)
    __shared__ __align__(16) short B_s [64][72];   // B[s][n]; after D: P_lo[t][s]
    __shared__ __align__(16) short C_s [64][72];   // C[t][n]
    __shared__ __align__(16) short XT  [64][72];   // XT[p][s] = x_s[p]
    __shared__ __align__(16) short BTw [64][72];   // BTw[n][s] = B[s][n]*w_s
    __shared__ __align__(16) short P_s [64][72];   // P_hi[t][s]; reused as ysb[t][p]
    __shared__ __align__(16) short hi_s[64][72];   // Srun hi [p][n]
    __shared__ __align__(16) short lo_s[64][72];   // Srun lo [p][n]
    __shared__ float cs_s[64];
    __shared__ float dt_l[64];

    const int tid  = threadIdx.x;
    const int wave = tid >> 6, lane = tid & 63;
    const int l15  = lane & 15, quad = lane >> 4;
    const int rr   = tid >> 3;          // 0..31 staging row (+32 on 2nd it)
    const int sg8  = (tid & 7) * 8;     // 8-col group

    const long base = (long)b * 2048;
    const int  tcs  = c * CLEN;

    for (int sc = 0; sc < 4; ++sc) {
        const int t0 = tcs + sc * 64;

        // ---- A: stage x/B/C + dt ----------------------------------------
#pragma unroll
        for (int it = 0; it < 2; ++it) {
            int r = rr + it * 32;
            const bf16* row = &xc[(base + t0 + r) * (long)CONV_DIM];
            bf16x8 xv = *(const bf16x8*)&row[h * 64 + sg8];
            *(int4*)&B_s[r][sg8] = *(const int4*)&row[1024 + sg8];
            *(int4*)&C_s[r][sg8] = *(const int4*)&row[1088 + sg8];
#pragma unroll
            for (int j = 0; j < 8; ++j) XT[sg8 + j][r] = ((short*)&xv)[j];
        }
        if (tid < 64) dt_l[tid] = dtv[((base + t0 + tid) << 4) + h];
        __syncthreads();

        // ---- B: inclusive cumsum of dt (wave 0) -------------------------
        if (wave == 0) {
            float d = dt_l[lane];
#pragma unroll
            for (int off = 1; off < 64; off <<= 1) {
                float u = __shfl_up(d, off);
                if (lane >= off) d += u;
            }
            cs_s[lane] = d;
        }
        __syncthreads();

        // ---- C: stage BTw[n][s] = B[s][n] * w_s -------------------------
        {
            float cs63 = cs_s[63];
#pragma unroll
            for (int it = 0; it < 2; ++it) {
                int s = rr + it * 32;
                float ws = expf(aexp * (cs_s[s] - cs63)) * dt_l[s];
                bf16x8 bv = *(const bf16x8*)&B_s[s][sg8];
#pragma unroll
                for (int j = 0; j < 8; ++j) BTw[sg8 + j][s] = f2bs((float)bv[j] * ws);
            }
        }
        __syncthreads();

        // ---- D: CB^T = B @ C^T  -> mask -> P (hi into P_s, lo into B_s) -
        float pD[4][4];
        {
            const int sb = wave * 16;
            f32x4 acc[4];
#pragma unroll
            for (int tt = 0; tt < 4; ++tt) acc[tt] = f32x4{0.f, 0.f, 0.f, 0.f};
#pragma unroll
            for (int kst = 0; kst < 2; ++kst) {
                bf16x8 aB = *(const bf16x8*)&B_s[sb + l15][kst * 32 + quad * 8];
#pragma unroll
                for (int tt = 0; tt < 4; ++tt) {
                    bf16x8 wC = *(const bf16x8*)&C_s[tt * 16 + l15][kst * 32 + quad * 8];
                    acc[tt] = __builtin_amdgcn_mfma_f32_16x16x32_bf16(aB, wC, acc[tt], 0, 0, 0);
                }
            }
            float csS[4], dtS[4];
            int sIdx[4];
#pragma unroll
            for (int r = 0; r < 4; ++r) {
                sIdx[r] = sb + quad * 4 + r;
                csS[r] = cs_s[sIdx[r]];
                dtS[r] = dt_l[sIdx[r]];
            }
#pragma unroll
            for (int tt = 0; tt < 4; ++tt) {
                int t = tt * 16 + l15;
                float csT = cs_s[t];
#pragma unroll
                for (int r = 0; r < 4; ++r) {
                    float m = (sIdx[r] <= t) ? expf(aexp * (csS[r] - csT)) * dtS[r] : 0.f;
                    pD[tt][r] = acc[tt][r] * m;
                }
            }
        }
        __syncthreads();   // all reads of B_s done before P_lo overwrite
        {
            const int sb = wave * 16;
#pragma unroll
            for (int tt = 0; tt < 4; ++tt) {
                int t = tt * 16 + l15;
#pragma unroll
                for (int r = 0; r < 4; ++r) {
                    int s = sb + quad * 4 + r;
                    short hb = f2bs(pD[tt][r]);
                    P_s[t][s] = hb;
                    B_s[t][s] = f2bs(pD[tt][r] - bs2f(hb));   // P_lo
                }
            }
        }
        __syncthreads();

        // ---- E: Y = G[t]*(C @ Srun^T) + (P_hi+P_lo) @ X^T + D*x -> ysb --
        {
            const int tb = wave * 16;
            f32x4 acc[4];
#pragma unroll
            for (int pp = 0; pp < 4; ++pp) acc[pp] = f32x4{0.f, 0.f, 0.f, 0.f};
            if (sc > 0) {
#pragma unroll
                for (int kst = 0; kst < 2; ++kst) {
                    bf16x8 aC = *(const bf16x8*)&C_s[tb + l15][kst * 32 + quad * 8];
#pragma unroll
                    for (int pp = 0; pp < 4; ++pp) {
                        bf16x8 wH = *(const bf16x8*)&hi_s[pp * 16 + l15][kst * 32 + quad * 8];
                        acc[pp] = __builtin_amdgcn_mfma_f32_16x16x32_bf16(aC, wH, acc[pp], 0, 0, 0);
                        bf16x8 wL = *(const bf16x8*)&lo_s[pp * 16 + l15][kst * 32 + quad * 8];
                        acc[pp] = __builtin_amdgcn_mfma_f32_16x16x32_bf16(aC, wL, acc[pp], 0, 0, 0);
                    }
                }
#pragma unroll
                for (int r = 0; r < 4; ++r) {
                    float g = expf(-aexp * cs_s[tb + quad * 4 + r]);
#pragma unroll
                    for (int pp = 0; pp < 4; ++pp) acc[pp][r] *= g;
                }
            }
#pragma unroll
            for (int kst = 0; kst < 2; ++kst) {
                bf16x8 aPh = *(const bf16x8*)&P_s[tb + l15][kst * 32 + quad * 8];
                bf16x8 aPl = *(const bf16x8*)&B_s[tb + l15][kst * 32 + quad * 8];
#pragma unroll
                for (int pp = 0; pp < 4; ++pp) {
                    bf16x8 wX = *(const bf16x8*)&XT[pp * 16 + l15][kst * 32 + quad * 8];
                    acc[pp] = __builtin_amdgcn_mfma_f32_16x16x32_bf16(aPh, wX, acc[pp], 0, 0, 0);
                    acc[pp] = __builtin_amdgcn_mfma_f32_16x16x32_bf16(aPl, wX, acc[pp], 0, 0, 0);
                }
            }
            // epilogue: + D*x, write ysb (reuse P_s as [t][p]); wave w only
            // touches rows [tb, tb+16) which it alone read as A-frags.
#pragma unroll
            for (int pp = 0; pp < 4; ++pp) {
#pragma unroll
                for (int r = 0; r < 4; ++r) {
                    int t = tb + quad * 4 + r, p = pp * 16 + l15;
                    float xv = bs2f(XT[p][t]);
                    P_s[t][p] = f2bs(acc[pp][r] + Dv * xv);
                }
            }
        }
        __syncthreads();

        // ---- copy-out y + F: Sloc, Srun update --------------------------
#pragma unroll
        for (int it = 0; it < 2; ++it) {
            int r = rr + it * 32;
            *(int4*)&y[(base + t0 + r) * 1024L + h * 64 + sg8] = *(int4*)&P_s[r][sg8];
        }
        {
            const int pb = wave * 16;
            f32x4 acc2[4];
#pragma unroll
            for (int nn = 0; nn < 4; ++nn) acc2[nn] = f32x4{0.f, 0.f, 0.f, 0.f};
#pragma unroll
            for (int kst = 0; kst < 2; ++kst) {
                bf16x8 aX = *(const bf16x8*)&XT[pb + l15][kst * 32 + quad * 8];
#pragma unroll
                for (int nn = 0; nn < 4; ++nn) {
                    bf16x8 wB = *(const bf16x8*)&BTw[nn * 16 + l15][kst * 32 + quad * 8];
                    acc2[nn] = __builtin_amdgcn_mfma_f32_16x16x32_bf16(aX, wB, acc2[nn], 0, 0, 0);
                }
            }
            float Pcv = expf(-aexp * cs_s[63]);
#pragma unroll
            for (int nn = 0; nn < 4; ++nn) {
#pragma unroll
                for (int r = 0; r < 4; ++r) {
                    int p = pb + quad * 4 + r, n = nn * 16 + l15;
                    float Sn = acc2[nn][r];
                    if (sc > 0) Sn += Pcv * (bs2f(hi_s[p][n]) + bs2f(lo_s[p][n]));
                    short hb = f2bs(Sn);
                    hi_s[p][n] = hb;
                    lo_s[p][n] = f2bs(Sn - bs2f(hb));
                }
            }
        }
        __syncthreads();
    }

    // final local state -> Sl (f32 [p][n], same layout as before)
    for (int i = tid; i < 4096; i += 256) {
        int p = i >> 6, n = i & 63;
        Sl[(long)blk * 4096 + i] = bs2f(hi_s[p][n]) + bs2f(lo_s[p][n]);
    }
}

// ---------------------------------------------------------------------------
// Phase 2: sequential combine of chunk states. 128 blocks (b*16+h), 256 thr.
// ---------------------------------------------------------------------------
__global__ __launch_bounds__(256)
void k_comb(float* __restrict__ Sl, const float* __restrict__ Pc)
{
    int bh = blockIdx.x;
    int tid = threadIdx.x;
    float run[16];
#pragma unroll
    for (int i = 0; i < 16; ++i) run[i] = 0.f;
    for (int c = 0; c < NCHUNK; ++c) {
        float* ptr = Sl + ((long)(bh * NCHUNK + c)) * 4096 + tid * 16;
        float pc = Pc[bh * NCHUNK + c];
#pragma unroll
        for (int q = 0; q < 4; ++q) {
            float4 v = *(float4*)&ptr[q * 4];
            float4 init = float4{run[q*4+0], run[q*4+1], run[q*4+2], run[q*4+3]};
            run[q*4+0] = v.x + pc * run[q*4+0];
            run[q*4+1] = v.y + pc * run[q*4+1];
            run[q*4+2] = v.z + pc * run[q*4+2];
            run[q*4+3] = v.w + pc * run[q*4+3];
            *(float4*)&ptr[q * 4] = init;
        }
    }
}

// ---------------------------------------------------------------------------
// Phase 3: y[t] += Pt[t] * (C_t · Sinit). Grid 1024, 256 threads.
// ---------------------------------------------------------------------------
__global__ __launch_bounds__(256)
void k_ph3(const float* __restrict__ Sl, const bf16* __restrict__ xc,
           const float* __restrict__ Pt, bf16* __restrict__ y)
{
    const int blk = blockIdx.x;
    const int c = blk & 7, h = (blk >> 3) & 15, b = blk >> 7;
    if (c == 0) return;   // Sinit = 0

    __shared__ __align__(16) float Cs[64][64];
    __shared__ __align__(16) short ysb[64][64];
    __shared__ float Pts[64];

    const int tid = threadIdx.x;
    const int p = tid >> 2, ng = tid & 3;
    const long base = (long)b * 2048;
    const int tcs = c * CLEN;

    float Sv[16];
    const float* Sp = Sl + (long)blk * 4096 + p * 64 + ng * 16;
#pragma unroll
    for (int q = 0; q < 4; ++q) {
        float4 v = *(const float4*)&Sp[q * 4];
        Sv[q*4+0] = v.x; Sv[q*4+1] = v.y; Sv[q*4+2] = v.z; Sv[q*4+3] = v.w;
    }

    for (int tile = 0; tile < 4; ++tile) {
        const int t0 = tcs + tile * 64;
        for (int i = tid; i < 512; i += 256) {
            int r = i >> 3, sg = (i & 7) * 8;
            bf16x8 v = *(const bf16x8*)&xc[(base + t0 + r) * (long)CONV_DIM + 1088 + sg];
#pragma unroll
            for (int j = 0; j < 8; ++j) Cs[r][sg + j] = (float)v[j];
        }
        if (tid < 64) Pts[tid] = Pt[((base + t0 + tid) << 4) + h];
        __syncthreads();

#pragma unroll 4
        for (int tt = 0; tt < 64; ++tt) {
            const float4* Cq = (const float4*)&Cs[tt][ng * 16];
            float dot = 0.f;
#pragma unroll
            for (int q = 0; q < 4; ++q) {
                float4 Cv = Cq[q];
                dot += Sv[q*4+0] * Cv.x + Sv[q*4+1] * Cv.y
                     + Sv[q*4+2] * Cv.z + Sv[q*4+3] * Cv.w;
            }
            dot += __shfl_xor(dot, 1);
            dot += __shfl_xor(dot, 2);
            if (ng == 0) ysb[tt][p] = f2bs(Pts[tt] * dot);
        }
        __syncthreads();

        for (int i = tid; i < 1024; i += 256) {
            int r = i >> 4, c4 = (i & 15) * 4;
            bf16* yp = &y[(base + t0 + r) * 1024L + h * 64 + c4];
            ushort4 old = *(ushort4*)yp;
            short* corr = &ysb[r][c4];
            ushort4 nw;
            nw.x = (unsigned short)f2bs(bs2f((short)old.x) + bs2f(corr[0]));
            nw.y = (unsigned short)f2bs(bs2f((short)old.y) + bs2f(corr[1]));
            nw.z = (unsigned short)f2bs(bs2f((short)old.z) + bs2f(corr[2]));
            nw.w = (unsigned short)f2bs(bs2f((short)old.w) + bs2f(corr[3]));
            *(ushort4*)yp = nw;
        }
        __syncthreads();
    }
}

// ---------------------------------------------------------------------------
// Gate (y *= silu(z)) + RMSNorm * norm_w, in-place on y.
// ---------------------------------------------------------------------------
__global__ __launch_bounds__(256)
void k_gate(bf16* __restrict__ yp, const bf16* __restrict__ zxp,
            const float* __restrict__ nw)
{
    long bt = blockIdx.x;
    bf16* y = yp + bt * 1024;
    const bf16* z = zxp + bt * (long)D_PROJ;
    int tid = threadIdx.x;
    ushort4 zv = *(const ushort4*)&z[tid * 4];
    ushort4 yv = *(const ushort4*)&y[tid * 4];
    float g[4], ss = 0.f;
    {
        float zz0 = bs2f((short)zv.x), zz1 = bs2f((short)zv.y);
        float zz2 = bs2f((short)zv.z), zz3 = bs2f((short)zv.w);
        float yy0 = bs2f((short)yv.x), yy1 = bs2f((short)yv.y);
        float yy2 = bs2f((short)yv.z), yy3 = bs2f((short)yv.w);
        g[0] = yy0 * (zz0 / (1.f + expf(-zz0)));
        g[1] = yy1 * (zz1 / (1.f + expf(-zz1)));
        g[2] = yy2 * (zz2 / (1.f + expf(-zz2)));
        g[3] = yy3 * (zz3 / (1.f + expf(-zz3)));
        ss = g[0]*g[0] + g[1]*g[1] + g[2]*g[2] + g[3]*g[3];
    }
#pragma unroll
    for (int o = 1; o < 64; o <<= 1) ss += __shfl_xor(ss, o);
    __shared__ float red[4];
    if ((tid & 63) == 0) red[tid >> 6] = ss;
    __syncthreads();
    float tot = red[0] + red[1] + red[2] + red[3];
    float sc = rsqrtf(tot * (1.f / 1024.f) + 1e-5f);
    const float* w = nw + tid * 4;
    ushort4 ov;
    ov.x = (unsigned short)f2bs(g[0] * sc * w[0]);
    ov.y = (unsigned short)f2bs(g[1] * sc * w[1]);
    ov.z = (unsigned short)f2bs(g[2] * sc * w[2]);
    ov.w = (unsigned short)f2bs(g[3] * sc * w[3]);
    *(ushort4*)&y[tid * 4] = ov;
}

// in-place flip via swaps: rows of 1024 bf16 (128 int4)
__global__ void k_swap(bf16* __restrict__ buf, const int* __restrict__ lens)
{
    int idx = blockIdx.x * 256 + threadIdx.x;
    int v = idx & 127;
    int r = idx >> 7;
    int b = r >> 10, t = r & 1023;
    int len = lens[b];
    int t2 = len - 1 - t;
    if (t < len && t < t2) {
        int4* p = (int4*)buf;
        long i1 = ((long)b * 2048 + t)  * 128 + v;
        long i2 = ((long)b * 2048 + t2) * 128 + v;
        int4 a = p[i1], c = p[i2];
        p[i1] = c; p[i2] = a;
    }
}

// LayerNorm(out + h) * g + b -> h (in place)
__global__ __launch_bounds__(256)
void k_ln(const bf16* __restrict__ outb, bf16* __restrict__ h,
          const float* __restrict__ g, const float* __restrict__ bb)
{
    long r = (long)blockIdx.x * 512;
    int tid = threadIdx.x;
    float v0 = B2F(outb[r + tid])       + B2F(h[r + tid]);
    float v1 = B2F(outb[r + tid + 256]) + B2F(h[r + tid + 256]);
    __shared__ float red[4], red2[4];
    float s = v0 + v1;
#pragma unroll
    for (int o = 1; o < 64; o <<= 1) s += __shfl_xor(s, o);
    if ((tid & 63) == 0) red[tid >> 6] = s;
    __syncthreads();
    float mu = (red[0] + red[1] + red[2] + red[3]) * (1.f / 512.f);
    float d0 = v0 - mu, d1 = v1 - mu;
    float q = d0 * d0 + d1 * d1;
#pragma unroll
    for (int o = 1; o < 64; o <<= 1) q += __shfl_xor(q, o);
    if ((tid & 63) == 0) red2[tid >> 6] = q;
    __syncthreads();
    float var = (red2[0] + red2[1] + red2[2] + red2[3]) * (1.f / 512.f);
    float rs = rsqrtf(var + 1e-5f);
    h[r + tid]       = F2B(d0 * rs * g[tid]       + bb[tid]);
    h[r + tid + 256] = F2B(d1 * rs * g[tid + 256] + bb[tid + 256]);
}

// masked-sum pooling partials
__global__ void k_pool(const float* __restrict__ enc, const int* __restrict__ lens,
                       float* __restrict__ pooled)
{
    int bid = blockIdx.x;
    int b = bid >> 6;
    int cg = (bid >> 4) & 3, tc = bid & 15;
    int c = cg * 256 + threadIdx.x;
    int len = lens[b];
    float s = 0.f;
    int tend = tc * 128 + 128;
    for (int t = tc * 128; t < tend; ++t)
        if (t < len) s += enc[((long)b * 2048 + t) * 1024 + c];
    atomicAdd(&pooled[b * 1024 + c], s);
}

// encoder_hidden = tanh(pooled/len @ W_ad^T + b_ad)
__global__ void k_adapter(const float* __restrict__ pooled, const float* __restrict__ Wad,
                          const float* __restrict__ bad, const int* __restrict__ lens,
                          float* __restrict__ outh)
{
    int idx = blockIdx.x * 256 + threadIdx.x;
    int b = idx >> 9, j = idx & 511;
    const float* wrow = Wad + (long)j * 1024;
    const float* prow = pooled + b * 1024;
    float acc = 0.f;
    for (int k = 0; k < 1024; ++k) acc += prow[k] * wrow[k];
    int li = lens[b]; if (li < 1) li = 1;
    acc = acc / (float)li + bad[j];
    outh[idx] = tanhf(acc);
}

// ---------------------------------------------------------------------------
static void gemm(const void* A, bool af32, const int* gather, const float* W,
                 const float* bias, void* C, bool cf32,
                 int M, int N, int K, int ldc, int coff, hipStream_t s)
{
    dim3 grid((N + 127) / 128, M / 128);
    if (af32) {
        if (cf32) k_gemm<true,  true ><<<grid, 256, 0, s>>>(A, gather, W, bias, C, M, N, K, ldc, coff);
        else      k_gemm<true,  false><<<grid, 256, 0, s>>>(A, gather, W, bias, C, M, N, K, ldc, coff);
    } else {
        if (cf32) k_gemm<false, true ><<<grid, 256, 0, s>>>(A, gather, W, bias, C, M, N, K, ldc, coff);
        else      k_gemm<false, false><<<grid, 256, 0, s>>>(A, gather, W, bias, C, M, N, K, ldc, coff);
    }
}

static void gemm_bf(const bf16* A, const int* gather, const bf16* Wb, const float* bias,
                    void* C, bool cf32, int M, int N, int K, int ldc, int coff, hipStream_t s)
{
    dim3 grid((N + 127) / 128, M / 128);
    if (cf32) k_gemm_bf<true ><<<grid, 256, 0, s>>>(A, gather, Wb, bias, C, M, N, K, ldc, coff);
    else      k_gemm_bf<false><<<grid, 256, 0, s>>>(A, gather, Wb, bias, C, M, N, K, ldc, coff);
}

extern "C" void kernel_launch(void* const* d_in, const int* in_sizes, int n_in,
                              void* d_out, int out_size, void* d_ws, size_t ws_size,
                              hipStream_t stream)
{
    const int*   tok    = (const int*)d_in[0];
    const int*   lens   = (const int*)d_in[1];
    const float* emb    = (const float*)d_in[2];
    const float* W_inp  = (const float*)d_in[3];
    const float* b_inp  = (const float*)d_in[4];
    const float* m_Win  = (const float*)d_in[5];
    const float* m_convw= (const float*)d_in[6];
    const float* m_convb= (const float*)d_in[7];
    const float* m_dtb  = (const float*)d_in[8];
    const float* m_Alog = (const float*)d_in[9];
    const float* m_D    = (const float*)d_in[10];
    const float* m_norm = (const float*)d_in[11];
    const float* m_Wout = (const float*)d_in[12];
    const float* blk_Wo = (const float*)d_in[13];
    const float* blk_bo = (const float*)d_in[14];
    const float* ln_g   = (const float*)d_in[15];
    const float* ln_b   = (const float*)d_in[16];
    const float* W_enc  = (const float*)d_in[17];
    const float* b_enc  = (const float*)d_in[18];
    const float* W_ad   = (const float*)d_in[19];
    const float* b_ad   = (const float*)d_in[20];

    char* ws = (char*)d_ws;
    bf16*  h      = (bf16*)(ws + OFF_H);
    bf16*  zx     = (bf16*)(ws + OFF_ZX);
    bf16*  xc     = (bf16*)(ws + OFF_XC);
    float* Sl     = (float*)(ws + OFF_S);
    float* Pt     = (float*)(ws + OFF_PT);
    float* Pc     = (float*)(ws + OFF_PC);
    float* dtv    = (float*)(ws + OFF_DTV);
    float* dAv    = (float*)(ws + OFF_DAV);
    int*   gidx   = (int*)(ws + OFF_GIDX);
    float* pooled = (float*)(ws + OFF_POOL);

    float* dout   = (float*)d_out;
    bf16*  y_f    = (bf16*)d_out;                        // 33.55 MB
    bf16*  y_b    = (bf16*)d_out + (size_t)16384 * 1024; // next 33.55 MB
    bf16*  comb   = (bf16*)(ws + OFF_ZX);                // alias zx (dead after gates)
    bf16*  outbuf = (bf16*)(ws + OFF_XC);                // alias xc (dead after ph3 bwd)

    // bf16 weight cache (fast GEMM path); fallback to legacy path if ws too small
    const bool fast = ws_size >= (size_t)(OFF_WBF + WBF_BYTES);
    bf16* wWin  = fast ? (bf16*)(ws + OFF_WBF + WBF_WIN)  : nullptr;
    bf16* wWout = fast ? (bf16*)(ws + OFF_WBF + WBF_WOUT) : nullptr;
    bf16* wBlk  = fast ? (bf16*)(ws + OFF_WBF + WBF_BLK)  : nullptr;
    bf16* wEnc  = fast ? (bf16*)(ws + OFF_WBF + WBF_ENC)  : nullptr;
    if (fast) {
        k_wcvt<<<(1122304 + 255) / 256, 256, 0, stream>>>(m_Win,  wWin,  1122304); // 8*2192*512/8
        k_wcvt<<<( 524288 + 255) / 256, 256, 0, stream>>>(m_Wout, wWout,  524288); // 8*512*1024/8
        k_wcvt<<<( 262144 + 255) / 256, 256, 0, stream>>>(blk_Wo, wBlk,   262144); // 4*512*1024/8
        k_wcvt<<<(  65536 + 255) / 256, 256, 0, stream>>>(W_enc,  wEnc,    65536); // 1024*512/8
    }

    k_mkidx<<<64, 256, 0, stream>>>(lens, gidx);

    // h = emb[tok] @ W_inp^T + b_inp   (f32 A + token gather: legacy path)
    gemm(emb, true, tok, W_inp, b_inp, h, false, 16384, 512, 512, 512, 0, stream);

    for (int l = 0; l < 4; ++l) {
        for (int dir = 0; dir < 2; ++dir) {
            const float* Wi = m_Win  + (size_t)(l * 2 + dir) * D_PROJ * 512;
            const float* cw = m_convw + (size_t)(l * 2 + dir) * CONV_DIM * 4;
            const float* cbp= m_convb + (size_t)(l * 2 + dir) * CONV_DIM;
            const float* dtb= m_dtb  + l * 32 + dir * 16;
            const float* alg= m_Alog + l * 32 + dir * 16;
            const float* Dpp= m_D    + l * 32 + dir * 16;
            const float* nw = m_norm + (size_t)(l * 2 + dir) * 1024;
            bf16* y = dir ? y_b : y_f;

            if (fast)
                gemm_bf(h, dir ? gidx : nullptr, wWin + (size_t)(l * 2 + dir) * D_PROJ * 512,
                        nullptr, zx, false, 16384, D_PROJ, 512, D_PROJ, 0, stream);
            else
                gemm(h, false, dir ? gidx : nullptr, Wi, nullptr, zx, false,
                     16384, D_PROJ, 512, D_PROJ, 0, stream);
            k_conv<<<576, 256, 0, stream>>>(zx, cw, cbp, xc);
            k_dt<<<1024, 256, 0, stream>>>(zx, dtb, alg, dtv, dAv);
            k_cum<<<1024, 256, 0, stream>>>(dAv, Pt, Pc);
            k_ph1<<<1024, 256, 0, stream>>>(xc, dtv, alg, Dpp, y, Sl);
            k_comb<<<128, 256, 0, stream>>>(Sl, Pc);
            k_ph3<<<1024, 256, 0, stream>>>(Sl, xc, Pt, y);
            k_gate<<<16384, 256, 0, stream>>>(y, zx, nw);
            if (dir) k_swap<<<4096, 256, 0, stream>>>(y_b, lens);
        }

        // out-projections into comb halves (comb aliases dead zx)
        if (fast) {
            gemm_bf(y_f, nullptr, wWout + (size_t)(l * 2 + 0) * 512 * 1024, nullptr, comb,
                    false, 16384, 512, 1024, 1024, 0, stream);
            gemm_bf(y_b, nullptr, wWout + (size_t)(l * 2 + 1) * 512 * 1024, nullptr, comb,
                    false, 16384, 512, 1024, 1024, 512, stream);
            gemm_bf(comb, nullptr, wBlk + (size_t)l * 512 * 1024, blk_bo + l * 512, outbuf,
                    false, 16384, 512, 1024, 512, 0, stream);
        } else {
            gemm(y_f, false, nullptr, m_Wout + (size_t)(l * 2 + 0) * 512 * 1024, nullptr, comb,
                 false, 16384, 512, 1024, 1024, 0, stream);
            gemm(y_b, false, nullptr, m_Wout + (size_t)(l * 2 + 1) * 512 * 1024, nullptr, comb,
                 false, 16384, 512, 1024, 1024, 512, stream);
            gemm(comb, false, nullptr, blk_Wo + (size_t)l * 512 * 1024, blk_bo + l * 512, outbuf,
                 false, 16384, 512, 1024, 512, 0, stream);
        }
        // residual + layernorm -> h
        k_ln<<<16384, 256, 0, stream>>>(outbuf, h, ln_g + l * 512, ln_b + l * 512);
    }

    // encoder_outputs = h @ W_enc^T + b_enc -> d_out f32 (y_f/y_b dead)
    if (fast)
        gemm_bf(h, nullptr, wEnc, b_enc, dout, true, 16384, 1024, 512, 1024, 0, stream);
    else
        gemm(h, false, nullptr, W_enc, b_enc, dout, true, 16384, 1024, 512, 1024, 0, stream);

    hipMemsetAsync(pooled, 0, 8 * 1024 * sizeof(float), stream);
    k_pool<<<512, 256, 0, stream>>>(dout, lens, pooled);
    k_adapter<<<16, 256, 0, stream>>>(pooled, W_ad, b_ad, lens, dout + (size_t)16384 * 1024);
}

// Round 5
// 2470.166 us; speedup vs baseline: 2.2902x; 1.2236x over previous
//
#include <hip/hip_runtime.h>
#include <hip/hip_bf16.h>
#include <math.h>

using bf16 = __hip_bfloat16;
typedef __bf16 bf16x8 __attribute__((ext_vector_type(8)));
typedef float f32x4 __attribute__((ext_vector_type(4)));

#define B2F(x) __bfloat162float(x)
#define F2B(x) __float2bfloat16(x)

__device__ inline short f2bs(float x) { bf16 b = F2B(x); return *(short*)&b; }
__device__ inline float bs2f(short x) { bf16 b; *(short*)&b = x; return B2F(b); }

// Problem constants: B=8, L=2048, H=512, D_INNER=1024, NH=16, P=64, N=64
static constexpr int D_PROJ = 2192, CONV_DIM = 1152;
static constexpr int NCHUNK = 8, CLEN = 256;   // 8 chunks x 256 steps

// Workspace layout (bytes). y_f/y_b live in d_out (67.1 MB).
static constexpr size_t OFF_H    = 0;                    // 16384x512  bf16  16.8 MB
static constexpr size_t OFF_ZX   = 16777216;             // 16384x2192 bf16  71.8 MB (comb aliases)
static constexpr size_t OFF_XC   = 88604672;             // 16384x1152 bf16  37.7 MB (outbuf aliases)
static constexpr size_t OFF_S    = 126353408;            // 1024x4096  f32   16.8 MB
static constexpr size_t OFF_PT   = 143130624;            // (unused)
static constexpr size_t OFF_PC   = 144179200;            // 1024       f32    4 KB
static constexpr size_t OFF_DTV  = 144183296;            // 16384x16   f32    1.0 MB
static constexpr size_t OFF_DAV  = 145231872;            // (unused)
static constexpr size_t OFF_GIDX = 146280448;            // 16384      i32
static constexpr size_t OFF_POOL = 146345984;            // 8x1024     f32 (ends 146378752)
// bf16 weight cache (one-time conversion). Guarded by ws_size with full fallback.
static constexpr size_t OFF_WBF   = 146378752;
static constexpr size_t WBF_WIN   = 0;          // 8 x 2192x512 bf16 = 17,956,864
static constexpr size_t WBF_WOUT  = 17956864;   // 8 x 512x1024 bf16 =  8,388,608
static constexpr size_t WBF_BLK   = 26345472;   // 4 x 512x1024 bf16 =  4,194,304
static constexpr size_t WBF_ENC   = 30539776;   // 1024x512     bf16 =  1,048,576
static constexpr size_t WBF_BYTES = 31588352;

// ---------------------------------------------------------------------------
// f32 -> bf16 weight conversion (one-time per launch)
// ---------------------------------------------------------------------------
__global__ void k_wcvt(const float* __restrict__ src, bf16* __restrict__ dst, long n8)
{
    long i = (long)blockIdx.x * 256 + threadIdx.x;
    if (i >= n8) return;
    const float4* s = (const float4*)(src + i * 8);
    float4 f0 = s[0], f1 = s[1];
    short o[8];
    o[0] = f2bs(f0.x); o[1] = f2bs(f0.y); o[2] = f2bs(f0.z); o[3] = f2bs(f0.w);
    o[4] = f2bs(f1.x); o[5] = f2bs(f1.y); o[6] = f2bs(f1.z); o[7] = f2bs(f1.w);
    *(int4*)&dst[i * 8] = *(int4*)o;
}

// ---------------------------------------------------------------------------
// async global->LDS, 16B per lane (wave-uniform LDS base + lane*16 dest)
// ---------------------------------------------------------------------------
__device__ inline void gl_lds16(const void* g, void* l)
{
    __builtin_amdgcn_global_load_lds(
        (const __attribute__((address_space(1))) unsigned int*)g,
        (__attribute__((address_space(3))) unsigned int*)l,
        16, 0, 0);
}

// ---------------------------------------------------------------------------
// Fast MFMA GEMM (bf16 A, bf16 W): C[M,N] = A[M,K] @ W[N,K]^T + bias
// ---------------------------------------------------------------------------
template<bool CF32>
__global__ __launch_bounds__(256, 2)
void k_gemm_bf(const bf16* __restrict__ A, const int* __restrict__ gatherIdx,
               const bf16* __restrict__ Wb, const float* __restrict__ bias,
               void* __restrict__ Cp, int M, int N, int K, int ldc, int coff)
{
    __shared__ union UU {
        struct { __align__(16) short As[128 * 64]; __align__(16) short Bs[128 * 64]; } ab;
        __align__(16) short Cs2[128 * 136];                 // bf16 epilogue
        __align__(16) float Cs4[CF32 ? 128 * 132 : 4];      // f32 epilogue
    } u;

    const int tid  = threadIdx.x;
    const int m0   = blockIdx.y * 128;
    const int n0   = blockIdx.x * 128;
    const int wave = tid >> 6, lane = tid & 63;
    const int l15  = lane & 15, quad = lane >> 4;
    const int wm   = (wave & 1) * 64, wn = (wave >> 1) * 64;

    const int sr   = lane >> 3;   // 0..7 sub-row within the 8-row chunk
    const int slot = lane & 7;    // 16B slot within row
    const bf16* asrc[4];
    const bf16* bsrc[4];
    int ldsoff[4];
#pragma unroll
    for (int t = 0; t < 4; ++t) {
        int row = wave * 32 + t * 8 + sr;            // 0..127
        long arow = m0 + row;
        if (gatherIdx) arow = gatherIdx[m0 + row];
        int sl = ((slot ^ (row & 7)) * 8);           // swizzled source col (elems)
        asrc[t] = A + arow * (long)K + sl;
        int wr = n0 + row; if (wr > N - 1) wr = N - 1;   // clamp; garbage cols never stored
        bsrc[t] = Wb + (long)wr * K + sl;
        ldsoff[t] = (wave * 32 + t * 8) * 64;        // shorts, wave-uniform
    }

    int aoff[2][4], boff[2][4];
#pragma unroll
    for (int ks = 0; ks < 2; ++ks) {
        int swz = (((ks << 2) | quad) ^ (l15 & 7)) * 8;
#pragma unroll
        for (int i = 0; i < 4; ++i) {
            aoff[ks][i] = (wm + i * 16 + l15) * 64 + swz;
            boff[ks][i] = (wn + i * 16 + l15) * 64 + swz;
        }
    }

    f32x4 acc[4][4];
#pragma unroll
    for (int i = 0; i < 4; ++i)
#pragma unroll
        for (int j = 0; j < 4; ++j) acc[i][j] = f32x4{0.f, 0.f, 0.f, 0.f};

    for (int k0 = 0; k0 < K; k0 += 64) {
#pragma unroll
        for (int t = 0; t < 4; ++t) gl_lds16(asrc[t] + k0, &u.ab.As[ldsoff[t]]);
#pragma unroll
        for (int t = 0; t < 4; ++t) gl_lds16(bsrc[t] + k0, &u.ab.Bs[ldsoff[t]]);
        __syncthreads();   // drains vmcnt(0): LDS tile ready

        bf16x8 af[2][4], bfr[2][4];
#pragma unroll
        for (int ks = 0; ks < 2; ++ks)
#pragma unroll
            for (int i = 0; i < 4; ++i) {
                af[ks][i]  = *(const bf16x8*)&u.ab.As[aoff[ks][i]];
                bfr[ks][i] = *(const bf16x8*)&u.ab.Bs[boff[ks][i]];
            }
#pragma unroll
        for (int ks = 0; ks < 2; ++ks)
#pragma unroll
            for (int i = 0; i < 4; ++i)
#pragma unroll
                for (int j = 0; j < 4; ++j)
                    acc[i][j] = __builtin_amdgcn_mfma_f32_16x16x32_bf16(af[ks][i], bfr[ks][j], acc[i][j], 0, 0, 0);
        __syncthreads();
    }

    __syncthreads();
    if (!CF32) {
#pragma unroll
        for (int j = 0; j < 4; ++j) {
            int lcol = wn + j * 16 + l15;
            int gcol = n0 + lcol;
            float bvv = (bias && gcol < N) ? bias[gcol] : 0.f;
#pragma unroll
            for (int i = 0; i < 4; ++i)
#pragma unroll
                for (int r = 0; r < 4; ++r)
                    u.Cs2[(wm + i * 16 + quad * 4 + r) * 136 + lcol] = f2bs(acc[i][j][r] + bvv);
        }
        __syncthreads();
        for (int i2 = tid; i2 < 2048; i2 += 256) {
            int lrow = i2 >> 4, seg = i2 & 15;
            int col0 = n0 + seg * 8;
            if (col0 < N) {
                int4 v = *(int4*)&u.Cs2[lrow * 136 + seg * 8];
                *(int4*)&((bf16*)Cp)[(long)(m0 + lrow) * ldc + coff + col0] = v;
            }
        }
    } else {
#pragma unroll
        for (int j = 0; j < 4; ++j) {
            int lcol = wn + j * 16 + l15;
            int gcol = n0 + lcol;
            float bvv = (bias && gcol < N) ? bias[gcol] : 0.f;
#pragma unroll
            for (int i = 0; i < 4; ++i)
#pragma unroll
                for (int r = 0; r < 4; ++r)
                    u.Cs4[(wm + i * 16 + quad * 4 + r) * 132 + lcol] = acc[i][j][r] + bvv;
        }
        __syncthreads();
        for (int i2 = tid; i2 < 4096; i2 += 256) {
            int lrow = i2 >> 5, seg = i2 & 31;
            int col0 = n0 + seg * 4;
            if (col0 < N) {
                int4 v = *(int4*)&u.Cs4[lrow * 132 + seg * 4];
                *(int4*)&((float*)Cp)[(long)(m0 + lrow) * ldc + coff + col0] = v;
            }
        }
    }
}

// ---------------------------------------------------------------------------
// Legacy MFMA GEMM (f32 A + gather): embedding GEMM and full fallback.
// ---------------------------------------------------------------------------
template<bool AF32, bool CF32>
__global__ __launch_bounds__(256, 2)
void k_gemm(const void* __restrict__ Ap, const int* __restrict__ gatherIdx,
            const float* __restrict__ W, const float* __restrict__ bias,
            void* __restrict__ Cp, int M, int N, int K, int ldc, int coff)
{
    __shared__ union UU {
        struct { __align__(16) short As[128 * 40]; __align__(16) short Bs[128 * 40]; } ab;
        __align__(16) short Cs2[128 * 136];
        __align__(16) float Cs4[CF32 ? 128 * 132 : 4];
    } u;

    const int tid  = threadIdx.x;
    const int m0   = blockIdx.y * 128;
    const int n0   = blockIdx.x * 128;
    const int wave = tid >> 6, lane = tid & 63;
    const int l15  = lane & 15, quad = lane >> 4;
    const int wm   = (wave & 1) * 64, wn = (wave >> 1) * 64;

    f32x4 acc[4][4];
#pragma unroll
    for (int i = 0; i < 4; ++i)
#pragma unroll
        for (int j = 0; j < 4; ++j) acc[i][j] = f32x4{0.f, 0.f, 0.f, 0.f};

    const int srow = tid >> 2;
    const int scol = (tid & 3) * 8;

    union V8 { int4 i4; short s[8]; };

    for (int k0 = 0; k0 < K; k0 += 32) {
        V8 av[2], bv[2];
#pragma unroll
        for (int it = 0; it < 2; ++it) {
            int r = srow + it * 64;
            long arow = m0 + r;
            if (gatherIdx) arow = gatherIdx[m0 + r];
            if (AF32) {
                const float* ap = (const float*)Ap + arow * (long)K + k0 + scol;
                float4 f0 = *(const float4*)ap;
                float4 f1 = *(const float4*)(ap + 4);
                av[it].s[0] = f2bs(f0.x); av[it].s[1] = f2bs(f0.y);
                av[it].s[2] = f2bs(f0.z); av[it].s[3] = f2bs(f0.w);
                av[it].s[4] = f2bs(f1.x); av[it].s[5] = f2bs(f1.y);
                av[it].s[6] = f2bs(f1.z); av[it].s[7] = f2bs(f1.w);
            } else {
                av[it].i4 = *(const int4*)((const bf16*)Ap + arow * (long)K + k0 + scol);
            }
            int wr = n0 + r;
            if (wr < N) {
                const float* wp = W + (long)wr * K + k0 + scol;
                float4 f0 = *(const float4*)wp;
                float4 f1 = *(const float4*)(wp + 4);
                bv[it].s[0] = f2bs(f0.x); bv[it].s[1] = f2bs(f0.y);
                bv[it].s[2] = f2bs(f0.z); bv[it].s[3] = f2bs(f0.w);
                bv[it].s[4] = f2bs(f1.x); bv[it].s[5] = f2bs(f1.y);
                bv[it].s[6] = f2bs(f1.z); bv[it].s[7] = f2bs(f1.w);
            } else {
                bv[it].i4 = int4{0, 0, 0, 0};
            }
        }
        __syncthreads();
#pragma unroll
        for (int it = 0; it < 2; ++it) {
            int r = srow + it * 64;
            *(int4*)&u.ab.As[r * 40 + scol] = av[it].i4;
            *(int4*)&u.ab.Bs[r * 40 + scol] = bv[it].i4;
        }
        __syncthreads();

        bf16x8 af[4], bfr[4];
#pragma unroll
        for (int i = 0; i < 4; ++i)
            af[i] = *(const bf16x8*)&u.ab.As[(wm + i * 16 + l15) * 40 + quad * 8];
#pragma unroll
        for (int j = 0; j < 4; ++j)
            bfr[j] = *(const bf16x8*)&u.ab.Bs[(wn + j * 16 + l15) * 40 + quad * 8];
#pragma unroll
        for (int i = 0; i < 4; ++i)
#pragma unroll
            for (int j = 0; j < 4; ++j)
                acc[i][j] = __builtin_amdgcn_mfma_f32_16x16x32_bf16(af[i], bfr[j], acc[i][j], 0, 0, 0);
    }

    __syncthreads();
    if (!CF32) {
#pragma unroll
        for (int j = 0; j < 4; ++j) {
            int lcol = wn + j * 16 + l15;
            int gcol = n0 + lcol;
            float bvv = (bias && gcol < N) ? bias[gcol] : 0.f;
#pragma unroll
            for (int i = 0; i < 4; ++i)
#pragma unroll
                for (int r = 0; r < 4; ++r)
                    u.Cs2[(wm + i * 16 + quad * 4 + r) * 136 + lcol] = f2bs(acc[i][j][r] + bvv);
        }
        __syncthreads();
        for (int i2 = tid; i2 < 2048; i2 += 256) {
            int lrow = i2 >> 4, seg = i2 & 15;
            int col0 = n0 + seg * 8;
            if (col0 < N) {
                int4 v = *(int4*)&u.Cs2[lrow * 136 + seg * 8];
                *(int4*)&((bf16*)Cp)[(long)(m0 + lrow) * ldc + coff + col0] = v;
            }
        }
    } else {
#pragma unroll
        for (int j = 0; j < 4; ++j) {
            int lcol = wn + j * 16 + l15;
            int gcol = n0 + lcol;
            float bvv = (bias && gcol < N) ? bias[gcol] : 0.f;
#pragma unroll
            for (int i = 0; i < 4; ++i)
#pragma unroll
                for (int r = 0; r < 4; ++r)
                    u.Cs4[(wm + i * 16 + quad * 4 + r) * 132 + lcol] = acc[i][j][r] + bvv;
        }
        __syncthreads();
        for (int i2 = tid; i2 < 4096; i2 += 256) {
            int lrow = i2 >> 5, seg = i2 & 31;
            int col0 = n0 + seg * 4;
            if (col0 < N) {
                int4 v = *(int4*)&u.Cs4[lrow * 132 + seg * 4];
                *(int4*)&((float*)Cp)[(long)(m0 + lrow) * ldc + coff + col0] = v;
            }
        }
    }
}

// ---------------------------------------------------------------------------
// flip row map
// ---------------------------------------------------------------------------
__global__ void k_mkidx(const int* __restrict__ lens, int* __restrict__ gidx)
{
    int idx = blockIdx.x * 256 + threadIdx.x;  // 16384
    int b = idx >> 11, t = idx & 2047;
    int len = lens[b];
    gidx[idx] = b * 2048 + ((t < len) ? (len - 1 - t) : t);
}

// ---------------------------------------------------------------------------
// Depthwise causal conv(k=4)+bias+silu: zx[:,1024:2176] -> xc[16384][1152] bf16
// Register-resident weights; each thread owns a fixed 8-channel group across
// 256 timesteps. Grid 576 = 9 ch-macroblocks x 64 chunks.
// ---------------------------------------------------------------------------
__global__ __launch_bounds__(256)
void k_conv(const bf16* __restrict__ zx, const float* __restrict__ w,
            const float* __restrict__ cb, bf16* __restrict__ xc)
{
    const int bid = blockIdx.x;          // 0..575
    const int mb  = bid % 9;             // channel macroblock (16 c8-groups)
    const int seg = bid / 9;             // 0..63
    const int b   = seg >> 3, tch = seg & 7;
    const int c0  = (mb * 16 + (threadIdx.x & 15)) * 8;   // 8-ch group, fixed
    const int trow = threadIdx.x >> 4;   // 0..15

    float wr[4][8], cbr[8];
#pragma unroll
    for (int i = 0; i < 8; i += 4) {
        float4 cv = *(const float4*)&cb[c0 + i];
        cbr[i] = cv.x; cbr[i+1] = cv.y; cbr[i+2] = cv.z; cbr[i+3] = cv.w;
    }
#pragma unroll
    for (int i = 0; i < 8; ++i) {
        float4 wv = *(const float4*)&w[(c0 + i) * 4];
        wr[0][i] = wv.x; wr[1][i] = wv.y; wr[2][i] = wv.z; wr[3][i] = wv.w;
    }

    const long base = (long)b * 2048 + tch * 256;
    for (int it = 0; it < 16; ++it) {
        const int t = it * 16 + trow;
        const long bt = base + t;
        const int tseq = tch * 256 + t;
        float acc[8];
#pragma unroll
        for (int i = 0; i < 8; ++i) acc[i] = cbr[i];
#pragma unroll
        for (int j = 0; j < 4; ++j) {
            if (tseq >= 3 - j) {
                bf16x8 v = *(const bf16x8*)&zx[(bt - 3 + j) * (long)D_PROJ + 1024 + c0];
#pragma unroll
                for (int i = 0; i < 8; ++i) acc[i] += wr[j][i] * (float)v[i];
            }
        }
        short out[8];
#pragma unroll
        for (int i = 0; i < 8; ++i) {
            float a = acc[i];
            out[i] = f2bs(a / (1.f + expf(-a)));
        }
        *(int4*)&xc[bt * (long)CONV_DIM + c0] = *(int4*)out;
    }
}

// ---------------------------------------------------------------------------
// dt = softplus(raw + bias). One dir per launch. (dA/cumprod now in-kernel.)
// ---------------------------------------------------------------------------
__global__ void k_dt(const bf16* __restrict__ zx, const float* __restrict__ dtb,
                     float* __restrict__ dtv)
{
    int idx = blockIdx.x * 256 + threadIdx.x;   // 16384*16
    int hh = idx & 15;
    long bt = idx >> 4;
    float x  = B2F(zx[bt * (long)D_PROJ + 2176 + hh]) + dtb[hh];
    dtv[idx] = (x > 20.f) ? x : log1pf(expf(x));
}

// ---------------------------------------------------------------------------
// Phase 1 (MFMA chunked form). One workgroup per (b, h, 256-chunk).
// Also writes Pc[blk] = exp(-aexp * total chunk dt-sum) (replaces k_cum).
// ---------------------------------------------------------------------------
__global__ __launch_bounds__(256, 2)
void k_ph1(const bf16* __restrict__ xc, const float* __restrict__ dtv,
           const float* __restrict__ alog, const float* __restrict__ Dp,
           bf16* __restrict__ y, float* __restrict__ Sl, float* __restrict__ Pc)
{
    const int blk = blockIdx.x;
    const int c = blk & 7, h = (blk >> 3) & 15, b = blk >> 7;
    const float Dv   = Dp[h];
    const float aexp = expf(alog[h]);

    // stride 72 shorts = 144 B (16B-aligned rows, non-pow2 bank spread)
    __shared__ __align__(16) short B_s [64][72];   // B[s][n]; after D: P_lo[t][s]
    __shared__ __align__(16) short C_s [64][72];   // C[t][n]
    __shared__ __align__(16) short XT  [64][72];   // XT[p][s] = x_s[p]
    __shared__ __align__(16) short BTw [64][72];   // BTw[n][s] = B[s][n]*w_s
    __shared__ __align__(16) short P_s [64][72];   // P_hi[t][s]; reused as ysb[t][p]
    __shared__ __align__(16) short hi_s[64][72];   // Srun hi [p][n]
    __shared__ __align__(16) short lo_s[64][72];   // Srun lo [p][n]
    __shared__ float cs_s[64];
    __shared__ float dt_l[64];

    const int tid  = threadIdx.x;
    const int wave = tid >> 6, lane = tid & 63;
    const int l15  = lane & 15, quad = lane >> 4;
    const int rr   = tid >> 3;          // 0..31 staging row (+32 on 2nd it)
    const int sg8  = (tid & 7) * 8;     // 8-col group

    const long base = (long)b * 2048;
    const int  tcs  = c * CLEN;
    float PcAcc = 1.f;

    for (int sc = 0; sc < 4; ++sc) {
        const int t0 = tcs + sc * 64;

        // ---- A: stage x/B/C + dt ----------------------------------------
#pragma unroll
        for (int it = 0; it < 2; ++it) {
            int r = rr + it * 32;
            const bf16* row = &xc[(base + t0 + r) * (long)CONV_DIM];
            bf16x8 xv = *(const bf16x8*)&row[h * 64 + sg8];
            *(int4*)&B_s[r][sg8] = *(const int4*)&row[1024 + sg8];
            *(int4*)&C_s[r][sg8] = *(const int4*)&row[1088 + sg8];
#pragma unroll
            for (int j = 0; j < 8; ++j) XT[sg8 + j][r] = ((short*)&xv)[j];
        }
        if (tid < 64) dt_l[tid] = dtv[((base + t0 + tid) << 4) + h];
        __syncthreads();

        // ---- B: inclusive cumsum of dt (wave 0) -------------------------
        if (wave == 0) {
            float d = dt_l[lane];
#pragma unroll
            for (int off = 1; off < 64; off <<= 1) {
                float u = __shfl_up(d, off);
                if (lane >= off) d += u;
            }
            cs_s[lane] = d;
        }
        __syncthreads();

        // ---- C: stage BTw[n][s] = B[s][n] * w_s -------------------------
        {
            float cs63 = cs_s[63];
#pragma unroll
            for (int it = 0; it < 2; ++it) {
                int s = rr + it * 32;
                float ws = expf(aexp * (cs_s[s] - cs63)) * dt_l[s];
                bf16x8 bv = *(const bf16x8*)&B_s[s][sg8];
#pragma unroll
                for (int j = 0; j < 8; ++j) BTw[sg8 + j][s] = f2bs((float)bv[j] * ws);
            }
        }
        __syncthreads();

        // ---- D: CB^T = B @ C^T  -> mask -> P (hi into P_s, lo into B_s) -
        float pD[4][4];
        {
            const int sb = wave * 16;
            f32x4 acc[4];
#pragma unroll
            for (int tt = 0; tt < 4; ++tt) acc[tt] = f32x4{0.f, 0.f, 0.f, 0.f};
#pragma unroll
            for (int kst = 0; kst < 2; ++kst) {
                bf16x8 aB = *(const bf16x8*)&B_s[sb + l15][kst * 32 + quad * 8];
#pragma unroll
                for (int tt = 0; tt < 4; ++tt) {
                    bf16x8 wC = *(const bf16x8*)&C_s[tt * 16 + l15][kst * 32 + quad * 8];
                    acc[tt] = __builtin_amdgcn_mfma_f32_16x16x32_bf16(aB, wC, acc[tt], 0, 0, 0);
                }
            }
            float csS[4], dtS[4];
            int sIdx[4];
#pragma unroll
            for (int r = 0; r < 4; ++r) {
                sIdx[r] = sb + quad * 4 + r;
                csS[r] = cs_s[sIdx[r]];
                dtS[r] = dt_l[sIdx[r]];
            }
#pragma unroll
            for (int tt = 0; tt < 4; ++tt) {
                int t = tt * 16 + l15;
                float csT = cs_s[t];
#pragma unroll
                for (int r = 0; r < 4; ++r) {
                    float m = (sIdx[r] <= t) ? expf(aexp * (csS[r] - csT)) * dtS[r] : 0.f;
                    pD[tt][r] = acc[tt][r] * m;
                }
            }
        }
        __syncthreads();   // all reads of B_s done before P_lo overwrite
        {
            const int sb = wave * 16;
#pragma unroll
            for (int tt = 0; tt < 4; ++tt) {
                int t = tt * 16 + l15;
#pragma unroll
                for (int r = 0; r < 4; ++r) {
                    int s = sb + quad * 4 + r;
                    short hb = f2bs(pD[tt][r]);
                    P_s[t][s] = hb;
                    B_s[t][s] = f2bs(pD[tt][r] - bs2f(hb));   // P_lo
                }
            }
        }
        __syncthreads();

        // ---- E: Y = G[t]*(C @ Srun^T) + (P_hi+P_lo) @ X^T + D*x -> ysb --
        {
            const int tb = wave * 16;
            f32x4 acc[4];
#pragma unroll
            for (int pp = 0; pp < 4; ++pp) acc[pp] = f32x4{0.f, 0.f, 0.f, 0.f};
            if (sc > 0) {
#pragma unroll
                for (int kst = 0; kst < 2; ++kst) {
                    bf16x8 aC = *(const bf16x8*)&C_s[tb + l15][kst * 32 + quad * 8];
#pragma unroll
                    for (int pp = 0; pp < 4; ++pp) {
                        bf16x8 wH = *(const bf16x8*)&hi_s[pp * 16 + l15][kst * 32 + quad * 8];
                        acc[pp] = __builtin_amdgcn_mfma_f32_16x16x32_bf16(aC, wH, acc[pp], 0, 0, 0);
                        bf16x8 wL = *(const bf16x8*)&lo_s[pp * 16 + l15][kst * 32 + quad * 8];
                        acc[pp] = __builtin_amdgcn_mfma_f32_16x16x32_bf16(aC, wL, acc[pp], 0, 0, 0);
                    }
                }
#pragma unroll
                for (int r = 0; r < 4; ++r) {
                    float g = expf(-aexp * cs_s[tb + quad * 4 + r]);
#pragma unroll
                    for (int pp = 0; pp < 4; ++pp) acc[pp][r] *= g;
                }
            }
#pragma unroll
            for (int kst = 0; kst < 2; ++kst) {
                bf16x8 aPh = *(const bf16x8*)&P_s[tb + l15][kst * 32 + quad * 8];
                bf16x8 aPl = *(const bf16x8*)&B_s[tb + l15][kst * 32 + quad * 8];
#pragma unroll
                for (int pp = 0; pp < 4; ++pp) {
                    bf16x8 wX = *(const bf16x8*)&XT[pp * 16 + l15][kst * 32 + quad * 8];
                    acc[pp] = __builtin_amdgcn_mfma_f32_16x16x32_bf16(aPh, wX, acc[pp], 0, 0, 0);
                    acc[pp] = __builtin_amdgcn_mfma_f32_16x16x32_bf16(aPl, wX, acc[pp], 0, 0, 0);
                }
            }
            // epilogue: + D*x, write ysb (reuse P_s as [t][p])
#pragma unroll
            for (int pp = 0; pp < 4; ++pp) {
#pragma unroll
                for (int r = 0; r < 4; ++r) {
                    int t = tb + quad * 4 + r, p = pp * 16 + l15;
                    float xv = bs2f(XT[p][t]);
                    P_s[t][p] = f2bs(acc[pp][r] + Dv * xv);
                }
            }
        }
        __syncthreads();

        // ---- copy-out y + F: Sloc, Srun update --------------------------
#pragma unroll
        for (int it = 0; it < 2; ++it) {
            int r = rr + it * 32;
            *(int4*)&y[(base + t0 + r) * 1024L + h * 64 + sg8] = *(int4*)&P_s[r][sg8];
        }
        {
            const int pb = wave * 16;
            f32x4 acc2[4];
#pragma unroll
            for (int nn = 0; nn < 4; ++nn) acc2[nn] = f32x4{0.f, 0.f, 0.f, 0.f};
#pragma unroll
            for (int kst = 0; kst < 2; ++kst) {
                bf16x8 aX = *(const bf16x8*)&XT[pb + l15][kst * 32 + quad * 8];
#pragma unroll
                for (int nn = 0; nn < 4; ++nn) {
                    bf16x8 wB = *(const bf16x8*)&BTw[nn * 16 + l15][kst * 32 + quad * 8];
                    acc2[nn] = __builtin_amdgcn_mfma_f32_16x16x32_bf16(aX, wB, acc2[nn], 0, 0, 0);
                }
            }
            float Pcv = expf(-aexp * cs_s[63]);
            PcAcc *= Pcv;
#pragma unroll
            for (int nn = 0; nn < 4; ++nn) {
#pragma unroll
                for (int r = 0; r < 4; ++r) {
                    int p = pb + quad * 4 + r, n = nn * 16 + l15;
                    float Sn = acc2[nn][r];
                    if (sc > 0) Sn += Pcv * (bs2f(hi_s[p][n]) + bs2f(lo_s[p][n]));
                    short hb = f2bs(Sn);
                    hi_s[p][n] = hb;
                    lo_s[p][n] = f2bs(Sn - bs2f(hb));
                }
            }
        }
        __syncthreads();
    }

    // final local state -> Sl (f32 [p][n]); chunk decay total -> Pc
    for (int i = tid; i < 4096; i += 256) {
        int p = i >> 6, n = i & 63;
        Sl[(long)blk * 4096 + i] = bs2f(hi_s[p][n]) + bs2f(lo_s[p][n]);
    }
    if (tid == 0) Pc[blk] = PcAcc;
}

// ---------------------------------------------------------------------------
// Phase 2: sequential combine of chunk states. 128 blocks (b*16+h), 256 thr.
// ---------------------------------------------------------------------------
__global__ __launch_bounds__(256)
void k_comb(float* __restrict__ Sl, const float* __restrict__ Pc)
{
    int bh = blockIdx.x;
    int tid = threadIdx.x;
    float run[16];
#pragma unroll
    for (int i = 0; i < 16; ++i) run[i] = 0.f;
    for (int c = 0; c < NCHUNK; ++c) {
        float* ptr = Sl + ((long)(bh * NCHUNK + c)) * 4096 + tid * 16;
        float pc = Pc[bh * NCHUNK + c];
#pragma unroll
        for (int q = 0; q < 4; ++q) {
            float4 v = *(float4*)&ptr[q * 4];
            float4 init = float4{run[q*4+0], run[q*4+1], run[q*4+2], run[q*4+3]};
            run[q*4+0] = v.x + pc * run[q*4+0];
            run[q*4+1] = v.y + pc * run[q*4+1];
            run[q*4+2] = v.z + pc * run[q*4+2];
            run[q*4+3] = v.w + pc * run[q*4+3];
            *(float4*)&ptr[q * 4] = init;
        }
    }
}

// ---------------------------------------------------------------------------
// Phase 3 (MFMA): y[t] += Pt[t] * (C_t · Sinit), Pt from in-kernel dt cumsum.
// Grid 1024 (c==0 exits), 256 threads, 4 waves. Per 64-t tile:
//   Ycorr = (C @ S_hi^T + C @ S_lo^T) scaled per-row by exp(-aexp*cs_incl[t]).
// Same fragment layouts as k_ph1's E-step.
// ---------------------------------------------------------------------------
__global__ __launch_bounds__(256, 2)
void k_ph3(const float* __restrict__ Sl, const bf16* __restrict__ xc,
           const float* __restrict__ dtv, const float* __restrict__ alog,
           bf16* __restrict__ y)
{
    const int blk = blockIdx.x;
    const int c = blk & 7, h = (blk >> 3) & 15, b = blk >> 7;
    if (c == 0) return;   // Sinit = 0
    const float aexp = expf(alog[h]);

    __shared__ __align__(16) short C_s [64][72];
    __shared__ __align__(16) short S_hi[64][72];   // Sinit hi [p][n]
    __shared__ __align__(16) short S_lo[64][72];   // Sinit lo [p][n]
    __shared__ __align__(16) short ysb [64][72];   // correction [t][p]
    __shared__ float dt_l[64], cs_s[64];

    const int tid  = threadIdx.x;
    const int wave = tid >> 6, lane = tid & 63;
    const int l15  = lane & 15, quad = lane >> 4;
    const int rr   = tid >> 3, sg8 = (tid & 7) * 8;

    const long base = (long)b * 2048;
    const int  tcs  = c * CLEN;

    // stage Sinit hi/lo once
    for (int i = tid; i < 4096; i += 256) {
        int p = i >> 6, n = i & 63;
        float v = Sl[(long)blk * 4096 + i];
        short hb = f2bs(v);
        S_hi[p][n] = hb;
        S_lo[p][n] = f2bs(v - bs2f(hb));
    }

    float csoff = 0.f;
    for (int tile = 0; tile < 4; ++tile) {
        const int t0 = tcs + tile * 64;
        // stage C (bf16 direct) + dt
#pragma unroll
        for (int it = 0; it < 2; ++it) {
            int r = rr + it * 32;
            *(int4*)&C_s[r][sg8] =
                *(const int4*)&xc[(base + t0 + r) * (long)CONV_DIM + 1088 + sg8];
        }
        if (tid < 64) dt_l[tid] = dtv[((base + t0 + tid) << 4) + h];
        __syncthreads();   // covers S staging (tile 0) + C/dt staging

        if (wave == 0) {
            float d = dt_l[lane];
#pragma unroll
            for (int off = 1; off < 64; off <<= 1) {
                float u = __shfl_up(d, off);
                if (lane >= off) d += u;
            }
            cs_s[lane] = d;
        }
        __syncthreads();

        // MFMA: acc[t][p] = C @ (S_hi + S_lo)^T
        {
            const int tb = wave * 16;
            f32x4 acc[4];
#pragma unroll
            for (int pp = 0; pp < 4; ++pp) acc[pp] = f32x4{0.f, 0.f, 0.f, 0.f};
#pragma unroll
            for (int kst = 0; kst < 2; ++kst) {
                bf16x8 aC = *(const bf16x8*)&C_s[tb + l15][kst * 32 + quad * 8];
#pragma unroll
                for (int pp = 0; pp < 4; ++pp) {
                    bf16x8 wH = *(const bf16x8*)&S_hi[pp * 16 + l15][kst * 32 + quad * 8];
                    acc[pp] = __builtin_amdgcn_mfma_f32_16x16x32_bf16(aC, wH, acc[pp], 0, 0, 0);
                    bf16x8 wL = *(const bf16x8*)&S_lo[pp * 16 + l15][kst * 32 + quad * 8];
                    acc[pp] = __builtin_amdgcn_mfma_f32_16x16x32_bf16(aC, wL, acc[pp], 0, 0, 0);
                }
            }
            // per-row Pt scale + write ysb[t][p]
#pragma unroll
            for (int r = 0; r < 4; ++r) {
                int t = tb + quad * 4 + r;
                float pt = expf(-aexp * (csoff + cs_s[t]));
#pragma unroll
                for (int pp = 0; pp < 4; ++pp)
                    ysb[t][pp * 16 + l15] = f2bs(acc[pp][r] * pt);
            }
        }
        __syncthreads();

        // RMW y tile (8 bf16 per iteration)
        for (int i = tid; i < 512; i += 256) {
            int r = i >> 3, cc = (i & 7) * 8;
            bf16* yp = &y[(base + t0 + r) * 1024L + h * 64 + cc];
            int4 ov = *(int4*)yp;
            short* os = (short*)&ov;
            short nv[8];
#pragma unroll
            for (int j = 0; j < 8; ++j)
                nv[j] = f2bs(bs2f(os[j]) + bs2f(ysb[r][cc + j]));
            *(int4*)yp = *(int4*)nv;
        }
        csoff += cs_s[63];
        __syncthreads();   // before next tile overwrites C_s/dt_l/cs_s
    }
}

// ---------------------------------------------------------------------------
// Gate (y *= silu(z)) + RMSNorm * norm_w, in-place on y.
// ---------------------------------------------------------------------------
__global__ __launch_bounds__(256)
void k_gate(bf16* __restrict__ yp, const bf16* __restrict__ zxp,
            const float* __restrict__ nw)
{
    long bt = blockIdx.x;
    bf16* y = yp + bt * 1024;
    const bf16* z = zxp + bt * (long)D_PROJ;
    int tid = threadIdx.x;
    ushort4 zv = *(const ushort4*)&z[tid * 4];
    ushort4 yv = *(const ushort4*)&y[tid * 4];
    float g[4], ss = 0.f;
    {
        float zz0 = bs2f((short)zv.x), zz1 = bs2f((short)zv.y);
        float zz2 = bs2f((short)zv.z), zz3 = bs2f((short)zv.w);
        float yy0 = bs2f((short)yv.x), yy1 = bs2f((short)yv.y);
        float yy2 = bs2f((short)yv.z), yy3 = bs2f((short)yv.w);
        g[0] = yy0 * (zz0 / (1.f + expf(-zz0)));
        g[1] = yy1 * (zz1 / (1.f + expf(-zz1)));
        g[2] = yy2 * (zz2 / (1.f + expf(-zz2)));
        g[3] = yy3 * (zz3 / (1.f + expf(-zz3)));
        ss = g[0]*g[0] + g[1]*g[1] + g[2]*g[2] + g[3]*g[3];
    }
#pragma unroll
    for (int o = 1; o < 64; o <<= 1) ss += __shfl_xor(ss, o);
    __shared__ float red[4];
    if ((tid & 63) == 0) red[tid >> 6] = ss;
    __syncthreads();
    float tot = red[0] + red[1] + red[2] + red[3];
    float sc = rsqrtf(tot * (1.f / 1024.f) + 1e-5f);
    const float* w = nw + tid * 4;
    ushort4 ov;
    ov.x = (unsigned short)f2bs(g[0] * sc * w[0]);
    ov.y = (unsigned short)f2bs(g[1] * sc * w[1]);
    ov.z = (unsigned short)f2bs(g[2] * sc * w[2]);
    ov.w = (unsigned short)f2bs(g[3] * sc * w[3]);
    *(ushort4*)&y[tid * 4] = ov;
}

// in-place flip via swaps: rows of 1024 bf16 (128 int4)
__global__ void k_swap(bf16* __restrict__ buf, const int* __restrict__ lens)
{
    int idx = blockIdx.x * 256 + threadIdx.x;
    int v = idx & 127;
    int r = idx >> 7;
    int b = r >> 10, t = r & 1023;
    int len = lens[b];
    int t2 = len - 1 - t;
    if (t < len && t < t2) {
        int4* p = (int4*)buf;
        long i1 = ((long)b * 2048 + t)  * 128 + v;
        long i2 = ((long)b * 2048 + t2) * 128 + v;
        int4 a = p[i1], c = p[i2];
        p[i1] = c; p[i2] = a;
    }
}

// LayerNorm(out + h) * g + b -> h (in place)
__global__ __launch_bounds__(256)
void k_ln(const bf16* __restrict__ outb, bf16* __restrict__ h,
          const float* __restrict__ g, const float* __restrict__ bb)
{
    long r = (long)blockIdx.x * 512;
    int tid = threadIdx.x;
    float v0 = B2F(outb[r + tid])       + B2F(h[r + tid]);
    float v1 = B2F(outb[r + tid + 256]) + B2F(h[r + tid + 256]);
    __shared__ float red[4], red2[4];
    float s = v0 + v1;
#pragma unroll
    for (int o = 1; o < 64; o <<= 1) s += __shfl_xor(s, o);
    if ((tid & 63) == 0) red[tid >> 6] = s;
    __syncthreads();
    float mu = (red[0] + red[1] + red[2] + red[3]) * (1.f / 512.f);
    float d0 = v0 - mu, d1 = v1 - mu;
    float q = d0 * d0 + d1 * d1;
#pragma unroll
    for (int o = 1; o < 64; o <<= 1) q += __shfl_xor(q, o);
    if ((tid & 63) == 0) red2[tid >> 6] = q;
    __syncthreads();
    float var = (red2[0] + red2[1] + red2[2] + red2[3]) * (1.f / 512.f);
    float rs = rsqrtf(var + 1e-5f);
    h[r + tid]       = F2B(d0 * rs * g[tid]       + bb[tid]);
    h[r + tid + 256] = F2B(d1 * rs * g[tid + 256] + bb[tid + 256]);
}

// masked-sum pooling partials
__global__ void k_pool(const float* __restrict__ enc, const int* __restrict__ lens,
                       float* __restrict__ pooled)
{
    int bid = blockIdx.x;
    int b = bid >> 6;
    int cg = (bid >> 4) & 3, tc = bid & 15;
    int c = cg * 256 + threadIdx.x;
    int len = lens[b];
    float s = 0.f;
    int tend = tc * 128 + 128;
    for (int t = tc * 128; t < tend; ++t)
        if (t < len) s += enc[((long)b * 2048 + t) * 1024 + c];
    atomicAdd(&pooled[b * 1024 + c], s);
}

// encoder_hidden = tanh(pooled/len @ W_ad^T + b_ad)
__global__ void k_adapter(const float* __restrict__ pooled, const float* __restrict__ Wad,
                          const float* __restrict__ bad, const int* __restrict__ lens,
                          float* __restrict__ outh)
{
    int idx = blockIdx.x * 256 + threadIdx.x;
    int b = idx >> 9, j = idx & 511;
    const float* wrow = Wad + (long)j * 1024;
    const float* prow = pooled + b * 1024;
    float acc = 0.f;
    for (int k = 0; k < 1024; ++k) acc += prow[k] * wrow[k];
    int li = lens[b]; if (li < 1) li = 1;
    acc = acc / (float)li + bad[j];
    outh[idx] = tanhf(acc);
}

// ---------------------------------------------------------------------------
static void gemm(const void* A, bool af32, const int* gather, const float* W,
                 const float* bias, void* C, bool cf32,
                 int M, int N, int K, int ldc, int coff, hipStream_t s)
{
    dim3 grid((N + 127) / 128, M / 128);
    if (af32) {
        if (cf32) k_gemm<true,  true ><<<grid, 256, 0, s>>>(A, gather, W, bias, C, M, N, K, ldc, coff);
        else      k_gemm<true,  false><<<grid, 256, 0, s>>>(A, gather, W, bias, C, M, N, K, ldc, coff);
    } else {
        if (cf32) k_gemm<false, true ><<<grid, 256, 0, s>>>(A, gather, W, bias, C, M, N, K, ldc, coff);
        else      k_gemm<false, false><<<grid, 256, 0, s>>>(A, gather, W, bias, C, M, N, K, ldc, coff);
    }
}

static void gemm_bf(const bf16* A, const int* gather, const bf16* Wb, const float* bias,
                    void* C, bool cf32, int M, int N, int K, int ldc, int coff, hipStream_t s)
{
    dim3 grid((N + 127) / 128, M / 128);
    if (cf32) k_gemm_bf<true ><<<grid, 256, 0, s>>>(A, gather, Wb, bias, C, M, N, K, ldc, coff);
    else      k_gemm_bf<false><<<grid, 256, 0, s>>>(A, gather, Wb, bias, C, M, N, K, ldc, coff);
}

extern "C" void kernel_launch(void* const* d_in, const int* in_sizes, int n_in,
                              void* d_out, int out_size, void* d_ws, size_t ws_size,
                              hipStream_t stream)
{
    const int*   tok    = (const int*)d_in[0];
    const int*   lens   = (const int*)d_in[1];
    const float* emb    = (const float*)d_in[2];
    const float* W_inp  = (const float*)d_in[3];
    const float* b_inp  = (const float*)d_in[4];
    const float* m_Win  = (const float*)d_in[5];
    const float* m_convw= (const float*)d_in[6];
    const float* m_convb= (const float*)d_in[7];
    const float* m_dtb  = (const float*)d_in[8];
    const float* m_Alog = (const float*)d_in[9];
    const float* m_D    = (const float*)d_in[10];
    const float* m_norm = (const float*)d_in[11];
    const float* m_Wout = (const float*)d_in[12];
    const float* blk_Wo = (const float*)d_in[13];
    const float* blk_bo = (const float*)d_in[14];
    const float* ln_g   = (const float*)d_in[15];
    const float* ln_b   = (const float*)d_in[16];
    const float* W_enc  = (const float*)d_in[17];
    const float* b_enc  = (const float*)d_in[18];
    const float* W_ad   = (const float*)d_in[19];
    const float* b_ad   = (const float*)d_in[20];

    char* ws = (char*)d_ws;
    bf16*  h      = (bf16*)(ws + OFF_H);
    bf16*  zx     = (bf16*)(ws + OFF_ZX);
    bf16*  xc     = (bf16*)(ws + OFF_XC);
    float* Sl     = (float*)(ws + OFF_S);
    float* Pc     = (float*)(ws + OFF_PC);
    float* dtv    = (float*)(ws + OFF_DTV);
    int*   gidx   = (int*)(ws + OFF_GIDX);
    float* pooled = (float*)(ws + OFF_POOL);

    float* dout   = (float*)d_out;
    bf16*  y_f    = (bf16*)d_out;                        // 33.55 MB
    bf16*  y_b    = (bf16*)d_out + (size_t)16384 * 1024; // next 33.55 MB
    bf16*  comb   = (bf16*)(ws + OFF_ZX);                // alias zx (dead after gates)
    bf16*  outbuf = (bf16*)(ws + OFF_XC);                // alias xc (dead after ph3 bwd)

    // bf16 weight cache (fast GEMM path); fallback to legacy path if ws too small
    const bool fast = ws_size >= (size_t)(OFF_WBF + WBF_BYTES);
    bf16* wWin  = fast ? (bf16*)(ws + OFF_WBF + WBF_WIN)  : nullptr;
    bf16* wWout = fast ? (bf16*)(ws + OFF_WBF + WBF_WOUT) : nullptr;
    bf16* wBlk  = fast ? (bf16*)(ws + OFF_WBF + WBF_BLK)  : nullptr;
    bf16* wEnc  = fast ? (bf16*)(ws + OFF_WBF + WBF_ENC)  : nullptr;
    if (fast) {
        k_wcvt<<<(1122304 + 255) / 256, 256, 0, stream>>>(m_Win,  wWin,  1122304); // 8*2192*512/8
        k_wcvt<<<( 524288 + 255) / 256, 256, 0, stream>>>(m_Wout, wWout,  524288); // 8*512*1024/8
        k_wcvt<<<( 262144 + 255) / 256, 256, 0, stream>>>(blk_Wo, wBlk,   262144); // 4*512*1024/8
        k_wcvt<<<(  65536 + 255) / 256, 256, 0, stream>>>(W_enc,  wEnc,    65536); // 1024*512/8
    }

    k_mkidx<<<64, 256, 0, stream>>>(lens, gidx);

    // h = emb[tok] @ W_inp^T + b_inp   (f32 A + token gather: legacy path)
    gemm(emb, true, tok, W_inp, b_inp, h, false, 16384, 512, 512, 512, 0, stream);

    for (int l = 0; l < 4; ++l) {
        for (int dir = 0; dir < 2; ++dir) {
            const float* Wi = m_Win  + (size_t)(l * 2 + dir) * D_PROJ * 512;
            const float* cw = m_convw + (size_t)(l * 2 + dir) * CONV_DIM * 4;
            const float* cbp= m_convb + (size_t)(l * 2 + dir) * CONV_DIM;
            const float* dtb= m_dtb  + l * 32 + dir * 16;
            const float* alg= m_Alog + l * 32 + dir * 16;
            const float* Dpp= m_D    + l * 32 + dir * 16;
            const float* nw = m_norm + (size_t)(l * 2 + dir) * 1024;
            bf16* y = dir ? y_b : y_f;

            if (fast)
                gemm_bf(h, dir ? gidx : nullptr, wWin + (size_t)(l * 2 + dir) * D_PROJ * 512,
                        nullptr, zx, false, 16384, D_PROJ, 512, D_PROJ, 0, stream);
            else
                gemm(h, false, dir ? gidx : nullptr, Wi, nullptr, zx, false,
                     16384, D_PROJ, 512, D_PROJ, 0, stream);
            k_conv<<<576, 256, 0, stream>>>(zx, cw, cbp, xc);
            k_dt<<<1024, 256, 0, stream>>>(zx, dtb, dtv);
            k_ph1<<<1024, 256, 0, stream>>>(xc, dtv, alg, Dpp, y, Sl, Pc);
            k_comb<<<128, 256, 0, stream>>>(Sl, Pc);
            k_ph3<<<1024, 256, 0, stream>>>(Sl, xc, dtv, alg, y);
            k_gate<<<16384, 256, 0, stream>>>(y, zx, nw);
            if (dir) k_swap<<<4096, 256, 0, stream>>>(y_b, lens);
        }

        // out-projections into comb halves (comb aliases dead zx)
        if (fast) {
            gemm_bf(y_f, nullptr, wWout + (size_t)(l * 2 + 0) * 512 * 1024, nullptr, comb,
                    false, 16384, 512, 1024, 1024, 0, stream);
            gemm_bf(y_b, nullptr, wWout + (size_t)(l * 2 + 1) * 512 * 1024, nullptr, comb,
                    false, 16384, 512, 1024, 1024, 512, stream);
            gemm_bf(comb, nullptr, wBlk + (size_t)l * 512 * 1024, blk_bo + l * 512, outbuf,
                    false, 16384, 512, 1024, 512, 0, stream);
        } else {
            gemm(y_f, false, nullptr, m_Wout + (size_t)(l * 2 + 0) * 512 * 1024, nullptr, comb,
                 false, 16384, 512, 1024, 1024, 0, stream);
            gemm(y_b, false, nullptr, m_Wout + (size_t)(l * 2 + 1) * 512 * 1024, nullptr, comb,
                 false, 16384, 512, 1024, 1024, 512, stream);
            gemm(comb, false, nullptr, blk_Wo + (size_t)l * 512 * 1024, blk_bo + l * 512, outbuf,
                 false, 16384, 512, 1024, 512, 0, stream);
        }
        // residual + layernorm -> h
        k_ln<<<16384, 256, 0, stream>>>(outbuf, h, ln_g + l * 512, ln_b + l * 512);
    }

    // encoder_outputs = h @ W_enc^T + b_enc -> d_out f32 (y_f/y_b dead)
    if (fast)
        gemm_bf(h, nullptr, wEnc, b_enc, dout, true, 16384, 1024, 512, 1024, 0, stream);
    else
        gemm(h, false, nullptr, W_enc, b_enc, dout, true, 16384, 1024, 512, 1024, 0, stream);

    hipMemsetAsync(pooled, 0, 8 * 1024 * sizeof(float), stream);
    k_pool<<<512, 256, 0, stream>>>(dout, lens, pooled);
    k_adapter<<<16, 256, 0, stream>>>(pooled, W_ad, b_ad, lens, dout + (size_t)16384 * 1024);
}

// Round 6
// 2365.518 us; speedup vs baseline: 2.3915x; 1.0442x over previous
//
#include <hip/hip_runtime.h>
#include <hip/hip_bf16.h>
#include <math.h>

using bf16 = __hip_bfloat16;
typedef __bf16 bf16x8 __attribute__((ext_vector_type(8)));
typedef float f32x4 __attribute__((ext_vector_type(4)));

#define B2F(x) __bfloat162float(x)
#define F2B(x) __float2bfloat16(x)

__device__ inline short f2bs(float x) { bf16 b = F2B(x); return *(short*)&b; }
__device__ inline float bs2f(short x) { bf16 b; *(short*)&b = x; return B2F(b); }

// Problem constants: B=8, L=2048, H=512, D_INNER=1024, NH=16, P=64, N=64
static constexpr int D_PROJ = 2192, CONV_DIM = 1152;
static constexpr int NCHUNK = 8, CLEN = 256;   // 8 chunks x 256 steps

// Workspace layout (bytes). y_f/y_b live in d_out (67.1 MB).
static constexpr size_t OFF_H    = 0;                    // 16384x512  bf16  16.8 MB
static constexpr size_t OFF_ZX   = 16777216;             // 16384x2192 bf16  71.8 MB (comb aliases)
static constexpr size_t OFF_XC   = 88604672;             // 16384x1152 bf16  37.7 MB (outbuf aliases)
static constexpr size_t OFF_S    = 126353408;            // 1024x4096  f32   16.8 MB
static constexpr size_t OFF_PC   = 144179200;            // 1024       f32    4 KB
static constexpr size_t OFF_DTV  = 144183296;            // 16384x16   f32    1.0 MB
static constexpr size_t OFF_GIDX = 146280448;            // 16384      i32
static constexpr size_t OFF_POOL = 146345984;            // 8x1024     f32 (ends 146378752)
// bf16 weight cache (one-time conversion). Guarded by ws_size with full fallback.
static constexpr size_t OFF_WBF   = 146378752;
static constexpr size_t WBF_WIN   = 0;          // 8 x 2192x512 bf16 = 17,956,864
static constexpr size_t WBF_WOUT  = 17956864;   // 8 x 512x1024 bf16 =  8,388,608
static constexpr size_t WBF_BLK   = 26345472;   // 4 x 512x1024 bf16 =  4,194,304
static constexpr size_t WBF_ENC   = 30539776;   // 1024x512     bf16 =  1,048,576
static constexpr size_t WBF_BYTES = 31588352;
// pre-transposed scan operands (guarded by fast2)
static constexpr size_t OFF_XT    = 177967104;  // XT_g [b*16+h][64 p][2048 t] bf16 = 33,554,432
static constexpr size_t OFF_BT    = 211521536;  // BT_g [64 n][16384 t]        bf16 =  2,097,152
static constexpr size_t WS_NEED2  = 213618688;

// LDS swizzle helpers for stride-64-short rows with XOR group swizzle
__device__ __forceinline__ int swz16(int r, int g) { return r * 64 + ((g ^ (r & 7)) << 3); }
__device__ __forceinline__ int swz1(int r, int c) { return r * 64 + ((((c) >> 3) ^ (r & 7)) << 3) + (c & 7); }

// ---------------------------------------------------------------------------
// f32 -> bf16 weight conversion (one-time per launch)
// ---------------------------------------------------------------------------
__global__ void k_wcvt(const float* __restrict__ src, bf16* __restrict__ dst, long n8)
{
    long i = (long)blockIdx.x * 256 + threadIdx.x;
    if (i >= n8) return;
    const float4* s = (const float4*)(src + i * 8);
    float4 f0 = s[0], f1 = s[1];
    short o[8];
    o[0] = f2bs(f0.x); o[1] = f2bs(f0.y); o[2] = f2bs(f0.z); o[3] = f2bs(f0.w);
    o[4] = f2bs(f1.x); o[5] = f2bs(f1.y); o[6] = f2bs(f1.z); o[7] = f2bs(f1.w);
    *(int4*)&dst[i * 8] = *(int4*)o;
}

// ---------------------------------------------------------------------------
// async global->LDS, 16B per lane (wave-uniform LDS base + lane*16 dest)
// ---------------------------------------------------------------------------
__device__ inline void gl_lds16(const void* g, void* l)
{
    __builtin_amdgcn_global_load_lds(
        (const __attribute__((address_space(1))) unsigned int*)g,
        (__attribute__((address_space(3))) unsigned int*)l,
        16, 0, 0);
}

// ---------------------------------------------------------------------------
// Fast MFMA GEMM (bf16 A, bf16 W): C[M,N] = A[M,K] @ W[N,K]^T + bias
// ---------------------------------------------------------------------------
template<bool CF32>
__global__ __launch_bounds__(256, 4)
void k_gemm_bf(const bf16* __restrict__ A, const int* __restrict__ gatherIdx,
               const bf16* __restrict__ Wb, const float* __restrict__ bias,
               void* __restrict__ Cp, int M, int N, int K, int ldc, int coff)
{
    __shared__ union UU {
        struct { __align__(16) short As[128 * 64]; __align__(16) short Bs[128 * 64]; } ab;
        __align__(16) short Cs2[128 * 136];                 // bf16 epilogue
        __align__(16) float Cs4[CF32 ? 128 * 132 : 4];      // f32 epilogue
    } u;

    const int tid  = threadIdx.x;
    const int m0   = blockIdx.y * 128;
    const int n0   = blockIdx.x * 128;
    const int wave = tid >> 6, lane = tid & 63;
    const int l15  = lane & 15, quad = lane >> 4;
    const int wm   = (wave & 1) * 64, wn = (wave >> 1) * 64;

    const int sr   = lane >> 3;   // 0..7 sub-row within the 8-row chunk
    const int slot = lane & 7;    // 16B slot within row
    const bf16* asrc[4];
    const bf16* bsrc[4];
    int ldsoff[4];
#pragma unroll
    for (int t = 0; t < 4; ++t) {
        int row = wave * 32 + t * 8 + sr;            // 0..127
        long arow = m0 + row;
        if (gatherIdx) arow = gatherIdx[m0 + row];
        int sl = ((slot ^ (row & 7)) * 8);           // swizzled source col (elems)
        asrc[t] = A + arow * (long)K + sl;
        int wr = n0 + row; if (wr > N - 1) wr = N - 1;   // clamp; garbage cols never stored
        bsrc[t] = Wb + (long)wr * K + sl;
        ldsoff[t] = (wave * 32 + t * 8) * 64;        // shorts, wave-uniform
    }

    int aoff[2][4], boff[2][4];
#pragma unroll
    for (int ks = 0; ks < 2; ++ks) {
        int swz = (((ks << 2) | quad) ^ (l15 & 7)) * 8;
#pragma unroll
        for (int i = 0; i < 4; ++i) {
            aoff[ks][i] = (wm + i * 16 + l15) * 64 + swz;
            boff[ks][i] = (wn + i * 16 + l15) * 64 + swz;
        }
    }

    f32x4 acc[4][4];
#pragma unroll
    for (int i = 0; i < 4; ++i)
#pragma unroll
        for (int j = 0; j < 4; ++j) acc[i][j] = f32x4{0.f, 0.f, 0.f, 0.f};

    for (int k0 = 0; k0 < K; k0 += 64) {
#pragma unroll
        for (int t = 0; t < 4; ++t) gl_lds16(asrc[t] + k0, &u.ab.As[ldsoff[t]]);
#pragma unroll
        for (int t = 0; t < 4; ++t) gl_lds16(bsrc[t] + k0, &u.ab.Bs[ldsoff[t]]);
        __syncthreads();   // drains vmcnt(0): LDS tile ready

        bf16x8 af[2][4], bfr[2][4];
#pragma unroll
        for (int ks = 0; ks < 2; ++ks)
#pragma unroll
            for (int i = 0; i < 4; ++i) {
                af[ks][i]  = *(const bf16x8*)&u.ab.As[aoff[ks][i]];
                bfr[ks][i] = *(const bf16x8*)&u.ab.Bs[boff[ks][i]];
            }
#pragma unroll
        for (int ks = 0; ks < 2; ++ks)
#pragma unroll
            for (int i = 0; i < 4; ++i)
#pragma unroll
                for (int j = 0; j < 4; ++j)
                    acc[i][j] = __builtin_amdgcn_mfma_f32_16x16x32_bf16(af[ks][i], bfr[ks][j], acc[i][j], 0, 0, 0);
        __syncthreads();
    }

    __syncthreads();
    if (!CF32) {
#pragma unroll
        for (int j = 0; j < 4; ++j) {
            int lcol = wn + j * 16 + l15;
            int gcol = n0 + lcol;
            float bvv = (bias && gcol < N) ? bias[gcol] : 0.f;
#pragma unroll
            for (int i = 0; i < 4; ++i)
#pragma unroll
                for (int r = 0; r < 4; ++r)
                    u.Cs2[(wm + i * 16 + quad * 4 + r) * 136 + lcol] = f2bs(acc[i][j][r] + bvv);
        }
        __syncthreads();
        for (int i2 = tid; i2 < 2048; i2 += 256) {
            int lrow = i2 >> 4, seg = i2 & 15;
            int col0 = n0 + seg * 8;
            if (col0 < N) {
                int4 v = *(int4*)&u.Cs2[lrow * 136 + seg * 8];
                *(int4*)&((bf16*)Cp)[(long)(m0 + lrow) * ldc + coff + col0] = v;
            }
        }
    } else {
#pragma unroll
        for (int j = 0; j < 4; ++j) {
            int lcol = wn + j * 16 + l15;
            int gcol = n0 + lcol;
            float bvv = (bias && gcol < N) ? bias[gcol] : 0.f;
#pragma unroll
            for (int i = 0; i < 4; ++i)
#pragma unroll
                for (int r = 0; r < 4; ++r)
                    u.Cs4[(wm + i * 16 + quad * 4 + r) * 132 + lcol] = acc[i][j][r] + bvv;
        }
        __syncthreads();
        for (int i2 = tid; i2 < 4096; i2 += 256) {
            int lrow = i2 >> 5, seg = i2 & 31;
            int col0 = n0 + seg * 4;
            if (col0 < N) {
                int4 v = *(int4*)&u.Cs4[lrow * 132 + seg * 4];
                *(int4*)&((float*)Cp)[(long)(m0 + lrow) * ldc + coff + col0] = v;
            }
        }
    }
}

// ---------------------------------------------------------------------------
// Legacy MFMA GEMM (f32 A + gather): embedding GEMM and full fallback.
// ---------------------------------------------------------------------------
template<bool AF32, bool CF32>
__global__ __launch_bounds__(256, 2)
void k_gemm(const void* __restrict__ Ap, const int* __restrict__ gatherIdx,
            const float* __restrict__ W, const float* __restrict__ bias,
            void* __restrict__ Cp, int M, int N, int K, int ldc, int coff)
{
    __shared__ union UU {
        struct { __align__(16) short As[128 * 40]; __align__(16) short Bs[128 * 40]; } ab;
        __align__(16) short Cs2[128 * 136];
        __align__(16) float Cs4[CF32 ? 128 * 132 : 4];
    } u;

    const int tid  = threadIdx.x;
    const int m0   = blockIdx.y * 128;
    const int n0   = blockIdx.x * 128;
    const int wave = tid >> 6, lane = tid & 63;
    const int l15  = lane & 15, quad = lane >> 4;
    const int wm   = (wave & 1) * 64, wn = (wave >> 1) * 64;

    f32x4 acc[4][4];
#pragma unroll
    for (int i = 0; i < 4; ++i)
#pragma unroll
        for (int j = 0; j < 4; ++j) acc[i][j] = f32x4{0.f, 0.f, 0.f, 0.f};

    const int srow = tid >> 2;
    const int scol = (tid & 3) * 8;

    union V8 { int4 i4; short s[8]; };

    for (int k0 = 0; k0 < K; k0 += 32) {
        V8 av[2], bv[2];
#pragma unroll
        for (int it = 0; it < 2; ++it) {
            int r = srow + it * 64;
            long arow = m0 + r;
            if (gatherIdx) arow = gatherIdx[m0 + r];
            if (AF32) {
                const float* ap = (const float*)Ap + arow * (long)K + k0 + scol;
                float4 f0 = *(const float4*)ap;
                float4 f1 = *(const float4*)(ap + 4);
                av[it].s[0] = f2bs(f0.x); av[it].s[1] = f2bs(f0.y);
                av[it].s[2] = f2bs(f0.z); av[it].s[3] = f2bs(f0.w);
                av[it].s[4] = f2bs(f1.x); av[it].s[5] = f2bs(f1.y);
                av[it].s[6] = f2bs(f1.z); av[it].s[7] = f2bs(f1.w);
            } else {
                av[it].i4 = *(const int4*)((const bf16*)Ap + arow * (long)K + k0 + scol);
            }
            int wr = n0 + r;
            if (wr < N) {
                const float* wp = W + (long)wr * K + k0 + scol;
                float4 f0 = *(const float4*)wp;
                float4 f1 = *(const float4*)(wp + 4);
                bv[it].s[0] = f2bs(f0.x); bv[it].s[1] = f2bs(f0.y);
                bv[it].s[2] = f2bs(f0.z); bv[it].s[3] = f2bs(f0.w);
                bv[it].s[4] = f2bs(f1.x); bv[it].s[5] = f2bs(f1.y);
                bv[it].s[6] = f2bs(f1.z); bv[it].s[7] = f2bs(f1.w);
            } else {
                bv[it].i4 = int4{0, 0, 0, 0};
            }
        }
        __syncthreads();
#pragma unroll
        for (int it = 0; it < 2; ++it) {
            int r = srow + it * 64;
            *(int4*)&u.ab.As[r * 40 + scol] = av[it].i4;
            *(int4*)&u.ab.Bs[r * 40 + scol] = bv[it].i4;
        }
        __syncthreads();

        bf16x8 af[4], bfr[4];
#pragma unroll
        for (int i = 0; i < 4; ++i)
            af[i] = *(const bf16x8*)&u.ab.As[(wm + i * 16 + l15) * 40 + quad * 8];
#pragma unroll
        for (int j = 0; j < 4; ++j)
            bfr[j] = *(const bf16x8*)&u.ab.Bs[(wn + j * 16 + l15) * 40 + quad * 8];
#pragma unroll
        for (int i = 0; i < 4; ++i)
#pragma unroll
            for (int j = 0; j < 4; ++j)
                acc[i][j] = __builtin_amdgcn_mfma_f32_16x16x32_bf16(af[i], bfr[j], acc[i][j], 0, 0, 0);
    }

    __syncthreads();
    if (!CF32) {
#pragma unroll
        for (int j = 0; j < 4; ++j) {
            int lcol = wn + j * 16 + l15;
            int gcol = n0 + lcol;
            float bvv = (bias && gcol < N) ? bias[gcol] : 0.f;
#pragma unroll
            for (int i = 0; i < 4; ++i)
#pragma unroll
                for (int r = 0; r < 4; ++r)
                    u.Cs2[(wm + i * 16 + quad * 4 + r) * 136 + lcol] = f2bs(acc[i][j][r] + bvv);
        }
        __syncthreads();
        for (int i2 = tid; i2 < 2048; i2 += 256) {
            int lrow = i2 >> 4, seg = i2 & 15;
            int col0 = n0 + seg * 8;
            if (col0 < N) {
                int4 v = *(int4*)&u.Cs2[lrow * 136 + seg * 8];
                *(int4*)&((bf16*)Cp)[(long)(m0 + lrow) * ldc + coff + col0] = v;
            }
        }
    } else {
#pragma unroll
        for (int j = 0; j < 4; ++j) {
            int lcol = wn + j * 16 + l15;
            int gcol = n0 + lcol;
            float bvv = (bias && gcol < N) ? bias[gcol] : 0.f;
#pragma unroll
            for (int i = 0; i < 4; ++i)
#pragma unroll
                for (int r = 0; r < 4; ++r)
                    u.Cs4[(wm + i * 16 + quad * 4 + r) * 132 + lcol] = acc[i][j][r] + bvv;
        }
        __syncthreads();
        for (int i2 = tid; i2 < 4096; i2 += 256) {
            int lrow = i2 >> 5, seg = i2 & 31;
            int col0 = n0 + seg * 4;
            if (col0 < N) {
                int4 v = *(int4*)&u.Cs4[lrow * 132 + seg * 4];
                *(int4*)&((float*)Cp)[(long)(m0 + lrow) * ldc + coff + col0] = v;
            }
        }
    }
}

// ---------------------------------------------------------------------------
// flip row map
// ---------------------------------------------------------------------------
__global__ void k_mkidx(const int* __restrict__ lens, int* __restrict__ gidx)
{
    int idx = blockIdx.x * 256 + threadIdx.x;  // 16384
    int b = idx >> 11, t = idx & 2047;
    int len = lens[b];
    gidx[idx] = b * 2048 + ((t < len) ? (len - 1 - t) : t);
}

// ---------------------------------------------------------------------------
// Depthwise causal conv(k=4)+bias+silu: zx[:,1024:2176] -> xc[16384][1152] bf16
// Register-resident weights; each thread owns a fixed 8-channel group across
// 256 timesteps. Grid 576 = 9 ch-macroblocks x 64 chunks.
// ---------------------------------------------------------------------------
__global__ __launch_bounds__(256)
void k_conv(const bf16* __restrict__ zx, const float* __restrict__ w,
            const float* __restrict__ cb, bf16* __restrict__ xc)
{
    const int bid = blockIdx.x;          // 0..575
    const int mb  = bid % 9;             // channel macroblock (16 c8-groups)
    const int seg = bid / 9;             // 0..63
    const int b   = seg >> 3, tch = seg & 7;
    const int c0  = (mb * 16 + (threadIdx.x & 15)) * 8;   // 8-ch group, fixed
    const int trow = threadIdx.x >> 4;   // 0..15

    float wr[4][8], cbr[8];
#pragma unroll
    for (int i = 0; i < 8; i += 4) {
        float4 cv = *(const float4*)&cb[c0 + i];
        cbr[i] = cv.x; cbr[i+1] = cv.y; cbr[i+2] = cv.z; cbr[i+3] = cv.w;
    }
#pragma unroll
    for (int i = 0; i < 8; ++i) {
        float4 wv = *(const float4*)&w[(c0 + i) * 4];
        wr[0][i] = wv.x; wr[1][i] = wv.y; wr[2][i] = wv.z; wr[3][i] = wv.w;
    }

    const long base = (long)b * 2048 + tch * 256;
    for (int it = 0; it < 16; ++it) {
        const int t = it * 16 + trow;
        const long bt = base + t;
        const int tseq = tch * 256 + t;
        float acc[8];
#pragma unroll
        for (int i = 0; i < 8; ++i) acc[i] = cbr[i];
#pragma unroll
        for (int j = 0; j < 4; ++j) {
            if (tseq >= 3 - j) {
                bf16x8 v = *(const bf16x8*)&zx[(bt - 3 + j) * (long)D_PROJ + 1024 + c0];
#pragma unroll
                for (int i = 0; i < 8; ++i) acc[i] += wr[j][i] * (float)v[i];
            }
        }
        short out[8];
#pragma unroll
        for (int i = 0; i < 8; ++i) {
            float a = acc[i];
            out[i] = f2bs(a / (1.f + expf(-a)));
        }
        *(int4*)&xc[bt * (long)CONV_DIM + c0] = *(int4*)out;
    }
}

// ---------------------------------------------------------------------------
// dt = softplus(raw + bias). One dir per launch.
// ---------------------------------------------------------------------------
__global__ void k_dt(const bf16* __restrict__ zx, const float* __restrict__ dtb,
                     float* __restrict__ dtv)
{
    int idx = blockIdx.x * 256 + threadIdx.x;   // 16384*16
    int hh = idx & 15;
    long bt = idx >> 4;
    float x  = B2F(zx[bt * (long)D_PROJ + 2176 + hh]) + dtb[hh];
    dtv[idx] = (x > 20.f) ? x : log1pf(expf(x));
}

// ---------------------------------------------------------------------------
// k_xt: global transpose of conv output. x channels -> XT_g[(b*16+h)*64+p][t],
// B channels -> BT_g[n][b*2048+t]. Grid 4352 = 17 cgroups x 32 tiles x 8 b.
// LDS tile stride 66 shorts (odd-word) keeps both sides <=4-way conflicted.
// ---------------------------------------------------------------------------
__global__ __launch_bounds__(256)
void k_xt(const bf16* __restrict__ xc, bf16* __restrict__ xtg, bf16* __restrict__ btg)
{
    __shared__ short T[64 * 66];
    const int bid  = blockIdx.x;
    const int g    = bid % 17;
    const int rest = bid / 17;
    const int tile = rest & 31;
    const int b    = rest >> 5;
    const int tid  = threadIdx.x;
    const int src0 = (g < 16) ? g * 64 : 1024;
    const long rowbase = (long)b * 2048 + tile * 64;

#pragma unroll
    for (int it = 0; it < 2; ++it) {
        int r  = (tid >> 3) + it * 32;
        int cg = (tid & 7) * 8;
        int4 v = *(const int4*)&xc[(rowbase + r) * (long)CONV_DIM + src0 + cg];
        const int* vi = (const int*)&v;
#pragma unroll
        for (int m = 0; m < 4; ++m)
            *(int*)&T[r * 66 + cg + 2 * m] = vi[m];
    }
    __syncthreads();
#pragma unroll
    for (int it = 0; it < 2; ++it) {
        int ch = (tid >> 3) + it * 32;
        int tg = (tid & 7) * 8;
        short o[8];
#pragma unroll
        for (int k = 0; k < 8; ++k) o[k] = T[(tg + k) * 66 + ch];
        bf16* dp;
        if (g < 16) dp = &xtg[((long)((b * 16 + g) * 64 + ch) << 11) + tile * 64 + tg];
        else        dp = &btg[((long)ch << 14) + (long)b * 2048 + tile * 64 + tg];
        *(int4*)dp = *(int4*)o;
    }
}

// ---------------------------------------------------------------------------
// Phase 1 v3 (fast path). Pre-transposed XT_g/BT_g inputs; stride-64 XOR-
// swizzled LDS; 6 shared arrays (BTw/P_hi/ysb share PB); Sloc MFMA hoisted
// before the P build (held in regs) so PB can be reused. D*x moved to k_gate.
// LDS ~49.9 KB -> 3 blocks/CU.
// ---------------------------------------------------------------------------
__global__ __launch_bounds__(256, 3)
void k_ph1(const bf16* __restrict__ xc, const bf16* __restrict__ xt,
           const bf16* __restrict__ btg, const float* __restrict__ dtv,
           const float* __restrict__ alog,
           bf16* __restrict__ y, float* __restrict__ Sl, float* __restrict__ Pc)
{
    const int blk = blockIdx.x;
    const int c = blk & 7, h = (blk >> 3) & 15, b = blk >> 7;
    const float aexp = expf(alog[h]);

    __shared__ __align__(16) short B_s [4096];   // B[s][n]; after D: P_lo[t][s]
    __shared__ __align__(16) short C_s [4096];   // C[t][n]
    __shared__ __align__(16) short XT_ [4096];   // X^T[p][s]
    __shared__ __align__(16) short PB  [4096];   // BTw[n][s] -> P_hi[t][s] -> ysb[t][p]
    __shared__ __align__(16) short hi_s[4096];   // Srun hi [p][n]
    __shared__ __align__(16) short lo_s[4096];   // Srun lo [p][n]
    __shared__ float cs_s[64], dt_l[64], ws_s[64];

    const int tid  = threadIdx.x;
    const int wave = tid >> 6, lane = tid & 63;
    const int l15  = lane & 15, quad = lane >> 4;
    const int rr   = tid >> 3, g8 = tid & 7;

    const long base = (long)b * 2048;
    const int  tcs  = c * CLEN;
    const bf16* xtb = xt + ((long)(b * 16 + h) << 17);   // *64*2048
    float PcAcc = 1.f;

    for (int sc = 0; sc < 4; ++sc) {
        const int t0 = tcs + sc * 64;

        // ---- stage B,C (from xc rows) + XT (from XT_g rows) + dt --------
#pragma unroll
        for (int it = 0; it < 2; ++it) {
            int r = rr + it * 32;
            const bf16* row = &xc[(base + t0 + r) * (long)CONV_DIM];
            *(int4*)&B_s[swz16(r, g8)] = *(const int4*)&row[1024 + g8 * 8];
            *(int4*)&C_s[swz16(r, g8)] = *(const int4*)&row[1088 + g8 * 8];
            *(int4*)&XT_[swz16(r, g8)] = *(const int4*)&xtb[((long)r << 11) + t0 + g8 * 8];
        }
        if (tid < 64) dt_l[tid] = dtv[((base + t0 + tid) << 4) + h];
        __syncthreads();                                             // (1)

        // ---- inclusive cumsum of dt (wave 0) ----------------------------
        if (wave == 0) {
            float d = dt_l[lane];
#pragma unroll
            for (int off = 1; off < 64; off <<= 1) {
                float u = __shfl_up(d, off);
                if (lane >= off) d += u;
            }
            cs_s[lane] = d;
        }
        __syncthreads();                                             // (2)

        if (tid < 64) ws_s[tid] = expf(aexp * (cs_s[tid] - cs_s[63])) * dt_l[tid];
        __syncthreads();                                             // (3)

        // ---- BTw[n][s] = B[s][n]*ws_s (row-staged from BT_g) into PB ----
#pragma unroll
        for (int it = 0; it < 2; ++it) {
            int n = rr + it * 32;
            bf16x8 bv = *(const bf16x8*)&btg[((long)n << 14) + base + t0 + g8 * 8];
            short o[8];
#pragma unroll
            for (int j = 0; j < 8; ++j) o[j] = f2bs((float)bv[j] * ws_s[g8 * 8 + j]);
            *(int4*)&PB[swz16(n, g8)] = *(int4*)o;
        }
        __syncthreads();                                             // (4)

        // ---- F0: Sloc = X^T @ BTw^T into regs (PB read-only here) -------
        f32x4 sl4[4];
        {
            const int pb = wave * 16;
#pragma unroll
            for (int nn = 0; nn < 4; ++nn) sl4[nn] = f32x4{0.f, 0.f, 0.f, 0.f};
#pragma unroll
            for (int kst = 0; kst < 2; ++kst) {
                bf16x8 aX = *(const bf16x8*)&XT_[swz16(pb + l15, kst * 4 + quad)];
#pragma unroll
                for (int nn = 0; nn < 4; ++nn) {
                    bf16x8 wB = *(const bf16x8*)&PB[swz16(nn * 16 + l15, kst * 4 + quad)];
                    sl4[nn] = __builtin_amdgcn_mfma_f32_16x16x32_bf16(aX, wB, sl4[nn], 0, 0, 0);
                }
            }
        }
        // ---- D: CB^T = B @ C^T -> masked pD regs ------------------------
        float pD[4][4];
        {
            const int sb = wave * 16;
            f32x4 acc[4];
#pragma unroll
            for (int tt = 0; tt < 4; ++tt) acc[tt] = f32x4{0.f, 0.f, 0.f, 0.f};
#pragma unroll
            for (int kst = 0; kst < 2; ++kst) {
                bf16x8 aB = *(const bf16x8*)&B_s[swz16(sb + l15, kst * 4 + quad)];
#pragma unroll
                for (int tt = 0; tt < 4; ++tt) {
                    bf16x8 wC = *(const bf16x8*)&C_s[swz16(tt * 16 + l15, kst * 4 + quad)];
                    acc[tt] = __builtin_amdgcn_mfma_f32_16x16x32_bf16(aB, wC, acc[tt], 0, 0, 0);
                }
            }
            float csS[4], dtS[4];
            int sIdx[4];
#pragma unroll
            for (int r = 0; r < 4; ++r) {
                sIdx[r] = sb + quad * 4 + r;
                csS[r] = cs_s[sIdx[r]];
                dtS[r] = dt_l[sIdx[r]];
            }
#pragma unroll
            for (int tt = 0; tt < 4; ++tt) {
                int t = tt * 16 + l15;
                float csT = cs_s[t];
#pragma unroll
                for (int r = 0; r < 4; ++r) {
                    float m = (sIdx[r] <= t) ? expf(aexp * (csS[r] - csT)) * dtS[r] : 0.f;
                    pD[tt][r] = acc[tt][r] * m;
                }
            }
        }
        __syncthreads();   // (5) all F0 PB-reads + D B_s-reads done
        {
            const int sb = wave * 16;
#pragma unroll
            for (int tt = 0; tt < 4; ++tt) {
                int t = tt * 16 + l15;
#pragma unroll
                for (int r = 0; r < 4; ++r) {
                    int s = sb + quad * 4 + r;
                    short hb = f2bs(pD[tt][r]);
                    PB [swz1(t, s)] = hb;                    // P_hi
                    B_s[swz1(t, s)] = f2bs(pD[tt][r] - bs2f(hb));   // P_lo
                }
            }
        }
        __syncthreads();                                             // (6)

        // ---- E: Y = G[t]*(C @ Srun^T) + (P_hi+P_lo) @ X^T -> ysb(PB) ----
        {
            const int tb = wave * 16;
            f32x4 acc[4];
#pragma unroll
            for (int pp = 0; pp < 4; ++pp) acc[pp] = f32x4{0.f, 0.f, 0.f, 0.f};
            if (sc > 0) {
#pragma unroll
                for (int kst = 0; kst < 2; ++kst) {
                    bf16x8 aC = *(const bf16x8*)&C_s[swz16(tb + l15, kst * 4 + quad)];
#pragma unroll
                    for (int pp = 0; pp < 4; ++pp) {
                        bf16x8 wH = *(const bf16x8*)&hi_s[swz16(pp * 16 + l15, kst * 4 + quad)];
                        acc[pp] = __builtin_amdgcn_mfma_f32_16x16x32_bf16(aC, wH, acc[pp], 0, 0, 0);
                        bf16x8 wL = *(const bf16x8*)&lo_s[swz16(pp * 16 + l15, kst * 4 + quad)];
                        acc[pp] = __builtin_amdgcn_mfma_f32_16x16x32_bf16(aC, wL, acc[pp], 0, 0, 0);
                    }
                }
#pragma unroll
                for (int r = 0; r < 4; ++r) {
                    float g = expf(-aexp * cs_s[tb + quad * 4 + r]);
#pragma unroll
                    for (int pp = 0; pp < 4; ++pp) acc[pp][r] *= g;
                }
            }
#pragma unroll
            for (int kst = 0; kst < 2; ++kst) {
                bf16x8 aPh = *(const bf16x8*)&PB [swz16(tb + l15, kst * 4 + quad)];
                bf16x8 aPl = *(const bf16x8*)&B_s[swz16(tb + l15, kst * 4 + quad)];
#pragma unroll
                for (int pp = 0; pp < 4; ++pp) {
                    bf16x8 wX = *(const bf16x8*)&XT_[swz16(pp * 16 + l15, kst * 4 + quad)];
                    acc[pp] = __builtin_amdgcn_mfma_f32_16x16x32_bf16(aPh, wX, acc[pp], 0, 0, 0);
                    acc[pp] = __builtin_amdgcn_mfma_f32_16x16x32_bf16(aPl, wX, acc[pp], 0, 0, 0);
                }
            }
            // ysb into PB (wave-own rows; no D*x — moved to k_gate)
#pragma unroll
            for (int pp = 0; pp < 4; ++pp) {
#pragma unroll
                for (int r = 0; r < 4; ++r) {
                    int t = tb + quad * 4 + r, p = pp * 16 + l15;
                    PB[swz1(t, p)] = f2bs(acc[pp][r]);
                }
            }
        }
        __syncthreads();                                             // (7)

        // ---- copy-out y + F1: Srun = Pcv*Srun + Sloc --------------------
#pragma unroll
        for (int it = 0; it < 2; ++it) {
            int r = rr + it * 32;
            *(int4*)&y[(base + t0 + r) * 1024L + h * 64 + g8 * 8] = *(int4*)&PB[swz16(r, g8)];
        }
        {
            const int pb = wave * 16;
            float Pcv = expf(-aexp * cs_s[63]);
            PcAcc *= Pcv;
#pragma unroll
            for (int nn = 0; nn < 4; ++nn) {
#pragma unroll
                for (int r = 0; r < 4; ++r) {
                    int p = pb + quad * 4 + r, n = nn * 16 + l15;
                    int ix = swz1(p, n);
                    float Sn = sl4[nn][r];
                    if (sc > 0) Sn += Pcv * (bs2f(hi_s[ix]) + bs2f(lo_s[ix]));
                    short hb = f2bs(Sn);
                    hi_s[ix] = hb;
                    lo_s[ix] = f2bs(Sn - bs2f(hb));
                }
            }
        }
        // next-iter barriers order the shared buffers; no trailing barrier
    }

    __syncthreads();
    for (int i = tid; i < 4096; i += 256) {
        int p = i >> 6, n = i & 63;
        int ix = swz1(p, n);
        Sl[(long)blk * 4096 + i] = bs2f(hi_s[ix]) + bs2f(lo_s[ix]);
    }
    if (tid == 0) Pc[blk] = PcAcc;
}

// ---------------------------------------------------------------------------
// Phase 1 fallback (round-5 version, includes D*x). Used when ws too small.
// ---------------------------------------------------------------------------
__global__ __launch_bounds__(256, 2)
void k_ph1_fb(const bf16* __restrict__ xc, const float* __restrict__ dtv,
              const float* __restrict__ alog, const float* __restrict__ Dp,
              bf16* __restrict__ y, float* __restrict__ Sl, float* __restrict__ Pc)
{
    const int blk = blockIdx.x;
    const int c = blk & 7, h = (blk >> 3) & 15, b = blk >> 7;
    const float Dv   = Dp[h];
    const float aexp = expf(alog[h]);

    __shared__ __align__(16) short B_s [64][72];
    __shared__ __align__(16) short C_s [64][72];
    __shared__ __align__(16) short XT  [64][72];
    __shared__ __align__(16) short BTw [64][72];
    __shared__ __align__(16) short P_s [64][72];
    __shared__ __align__(16) short hi_s[64][72];
    __shared__ __align__(16) short lo_s[64][72];
    __shared__ float cs_s[64];
    __shared__ float dt_l[64];

    const int tid  = threadIdx.x;
    const int wave = tid >> 6, lane = tid & 63;
    const int l15  = lane & 15, quad = lane >> 4;
    const int rr   = tid >> 3;
    const int sg8  = (tid & 7) * 8;

    const long base = (long)b * 2048;
    const int  tcs  = c * CLEN;
    float PcAcc = 1.f;

    for (int sc = 0; sc < 4; ++sc) {
        const int t0 = tcs + sc * 64;
#pragma unroll
        for (int it = 0; it < 2; ++it) {
            int r = rr + it * 32;
            const bf16* row = &xc[(base + t0 + r) * (long)CONV_DIM];
            bf16x8 xv = *(const bf16x8*)&row[h * 64 + sg8];
            *(int4*)&B_s[r][sg8] = *(const int4*)&row[1024 + sg8];
            *(int4*)&C_s[r][sg8] = *(const int4*)&row[1088 + sg8];
#pragma unroll
            for (int j = 0; j < 8; ++j) XT[sg8 + j][r] = ((short*)&xv)[j];
        }
        if (tid < 64) dt_l[tid] = dtv[((base + t0 + tid) << 4) + h];
        __syncthreads();

        if (wave == 0) {
            float d = dt_l[lane];
#pragma unroll
            for (int off = 1; off < 64; off <<= 1) {
                float u = __shfl_up(d, off);
                if (lane >= off) d += u;
            }
            cs_s[lane] = d;
        }
        __syncthreads();

        {
            float cs63 = cs_s[63];
#pragma unroll
            for (int it = 0; it < 2; ++it) {
                int s = rr + it * 32;
                float ws = expf(aexp * (cs_s[s] - cs63)) * dt_l[s];
                bf16x8 bv = *(const bf16x8*)&B_s[s][sg8];
#pragma unroll
                for (int j = 0; j < 8; ++j) BTw[sg8 + j][s] = f2bs((float)bv[j] * ws);
            }
        }
        __syncthreads();

        float pD[4][4];
        {
            const int sb = wave * 16;
            f32x4 acc[4];
#pragma unroll
            for (int tt = 0; tt < 4; ++tt) acc[tt] = f32x4{0.f, 0.f, 0.f, 0.f};
#pragma unroll
            for (int kst = 0; kst < 2; ++kst) {
                bf16x8 aB = *(const bf16x8*)&B_s[sb + l15][kst * 32 + quad * 8];
#pragma unroll
                for (int tt = 0; tt < 4; ++tt) {
                    bf16x8 wC = *(const bf16x8*)&C_s[tt * 16 + l15][kst * 32 + quad * 8];
                    acc[tt] = __builtin_amdgcn_mfma_f32_16x16x32_bf16(aB, wC, acc[tt], 0, 0, 0);
                }
            }
            float csS[4], dtS[4];
            int sIdx[4];
#pragma unroll
            for (int r = 0; r < 4; ++r) {
                sIdx[r] = sb + quad * 4 + r;
                csS[r] = cs_s[sIdx[r]];
                dtS[r] = dt_l[sIdx[r]];
            }
#pragma unroll
            for (int tt = 0; tt < 4; ++tt) {
                int t = tt * 16 + l15;
                float csT = cs_s[t];
#pragma unroll
                for (int r = 0; r < 4; ++r) {
                    float m = (sIdx[r] <= t) ? expf(aexp * (csS[r] - csT)) * dtS[r] : 0.f;
                    pD[tt][r] = acc[tt][r] * m;
                }
            }
        }
        __syncthreads();
        {
            const int sb = wave * 16;
#pragma unroll
            for (int tt = 0; tt < 4; ++tt) {
                int t = tt * 16 + l15;
#pragma unroll
                for (int r = 0; r < 4; ++r) {
                    int s = sb + quad * 4 + r;
                    short hb = f2bs(pD[tt][r]);
                    P_s[t][s] = hb;
                    B_s[t][s] = f2bs(pD[tt][r] - bs2f(hb));
                }
            }
        }
        __syncthreads();

        {
            const int tb = wave * 16;
            f32x4 acc[4];
#pragma unroll
            for (int pp = 0; pp < 4; ++pp) acc[pp] = f32x4{0.f, 0.f, 0.f, 0.f};
            if (sc > 0) {
#pragma unroll
                for (int kst = 0; kst < 2; ++kst) {
                    bf16x8 aC = *(const bf16x8*)&C_s[tb + l15][kst * 32 + quad * 8];
#pragma unroll
                    for (int pp = 0; pp < 4; ++pp) {
                        bf16x8 wH = *(const bf16x8*)&hi_s[pp * 16 + l15][kst * 32 + quad * 8];
                        acc[pp] = __builtin_amdgcn_mfma_f32_16x16x32_bf16(aC, wH, acc[pp], 0, 0, 0);
                        bf16x8 wL = *(const bf16x8*)&lo_s[pp * 16 + l15][kst * 32 + quad * 8];
                        acc[pp] = __builtin_amdgcn_mfma_f32_16x16x32_bf16(aC, wL, acc[pp], 0, 0, 0);
                    }
                }
#pragma unroll
                for (int r = 0; r < 4; ++r) {
                    float g = expf(-aexp * cs_s[tb + quad * 4 + r]);
#pragma unroll
                    for (int pp = 0; pp < 4; ++pp) acc[pp][r] *= g;
                }
            }
#pragma unroll
            for (int kst = 0; kst < 2; ++kst) {
                bf16x8 aPh = *(const bf16x8*)&P_s[tb + l15][kst * 32 + quad * 8];
                bf16x8 aPl = *(const bf16x8*)&B_s[tb + l15][kst * 32 + quad * 8];
#pragma unroll
                for (int pp = 0; pp < 4; ++pp) {
                    bf16x8 wX = *(const bf16x8*)&XT[pp * 16 + l15][kst * 32 + quad * 8];
                    acc[pp] = __builtin_amdgcn_mfma_f32_16x16x32_bf16(aPh, wX, acc[pp], 0, 0, 0);
                    acc[pp] = __builtin_amdgcn_mfma_f32_16x16x32_bf16(aPl, wX, acc[pp], 0, 0, 0);
                }
            }
#pragma unroll
            for (int pp = 0; pp < 4; ++pp) {
#pragma unroll
                for (int r = 0; r < 4; ++r) {
                    int t = tb + quad * 4 + r, p = pp * 16 + l15;
                    float xv = bs2f(XT[p][t]);
                    P_s[t][p] = f2bs(acc[pp][r] + Dv * xv);
                }
            }
        }
        __syncthreads();

#pragma unroll
        for (int it = 0; it < 2; ++it) {
            int r = rr + it * 32;
            *(int4*)&y[(base + t0 + r) * 1024L + h * 64 + sg8] = *(int4*)&P_s[r][sg8];
        }
        {
            const int pb = wave * 16;
            f32x4 acc2[4];
#pragma unroll
            for (int nn = 0; nn < 4; ++nn) acc2[nn] = f32x4{0.f, 0.f, 0.f, 0.f};
#pragma unroll
            for (int kst = 0; kst < 2; ++kst) {
                bf16x8 aX = *(const bf16x8*)&XT[pb + l15][kst * 32 + quad * 8];
#pragma unroll
                for (int nn = 0; nn < 4; ++nn) {
                    bf16x8 wB = *(const bf16x8*)&BTw[nn * 16 + l15][kst * 32 + quad * 8];
                    acc2[nn] = __builtin_amdgcn_mfma_f32_16x16x32_bf16(aX, wB, acc2[nn], 0, 0, 0);
                }
            }
            float Pcv = expf(-aexp * cs_s[63]);
            PcAcc *= Pcv;
#pragma unroll
            for (int nn = 0; nn < 4; ++nn) {
#pragma unroll
                for (int r = 0; r < 4; ++r) {
                    int p = pb + quad * 4 + r, n = nn * 16 + l15;
                    float Sn = acc2[nn][r];
                    if (sc > 0) Sn += Pcv * (bs2f(hi_s[p][n]) + bs2f(lo_s[p][n]));
                    short hb = f2bs(Sn);
                    hi_s[p][n] = hb;
                    lo_s[p][n] = f2bs(Sn - bs2f(hb));
                }
            }
        }
        __syncthreads();
    }

    for (int i = tid; i < 4096; i += 256) {
        int p = i >> 6, n = i & 63;
        Sl[(long)blk * 4096 + i] = bs2f(hi_s[p][n]) + bs2f(lo_s[p][n]);
    }
    if (tid == 0) Pc[blk] = PcAcc;
}

// ---------------------------------------------------------------------------
// Phase 2: sequential combine of chunk states. 128 blocks (b*16+h), 256 thr.
// ---------------------------------------------------------------------------
__global__ __launch_bounds__(256)
void k_comb(float* __restrict__ Sl, const float* __restrict__ Pc)
{
    int bh = blockIdx.x;
    int tid = threadIdx.x;
    float run[16];
#pragma unroll
    for (int i = 0; i < 16; ++i) run[i] = 0.f;
    for (int c = 0; c < NCHUNK; ++c) {
        float* ptr = Sl + ((long)(bh * NCHUNK + c)) * 4096 + tid * 16;
        float pc = Pc[bh * NCHUNK + c];
#pragma unroll
        for (int q = 0; q < 4; ++q) {
            float4 v = *(float4*)&ptr[q * 4];
            float4 init = float4{run[q*4+0], run[q*4+1], run[q*4+2], run[q*4+3]};
            run[q*4+0] = v.x + pc * run[q*4+0];
            run[q*4+1] = v.y + pc * run[q*4+1];
            run[q*4+2] = v.z + pc * run[q*4+2];
            run[q*4+3] = v.w + pc * run[q*4+3];
            *(float4*)&ptr[q * 4] = init;
        }
    }
}

// ---------------------------------------------------------------------------
// Phase 3 (MFMA): y[t] += Pt[t] * (C_t · Sinit), Pt from in-kernel dt cumsum.
// ---------------------------------------------------------------------------
__global__ __launch_bounds__(256, 2)
void k_ph3(const float* __restrict__ Sl, const bf16* __restrict__ xc,
           const float* __restrict__ dtv, const float* __restrict__ alog,
           bf16* __restrict__ y)
{
    const int blk = blockIdx.x;
    const int c = blk & 7, h = (blk >> 3) & 15, b = blk >> 7;
    if (c == 0) return;   // Sinit = 0
    const float aexp = expf(alog[h]);

    __shared__ __align__(16) short C_s [64][72];
    __shared__ __align__(16) short S_hi[64][72];
    __shared__ __align__(16) short S_lo[64][72];
    __shared__ __align__(16) short ysb [64][72];
    __shared__ float dt_l[64], cs_s[64];

    const int tid  = threadIdx.x;
    const int wave = tid >> 6, lane = tid & 63;
    const int l15  = lane & 15, quad = lane >> 4;
    const int rr   = tid >> 3, sg8 = (tid & 7) * 8;

    const long base = (long)b * 2048;
    const int  tcs  = c * CLEN;

    for (int i = tid; i < 4096; i += 256) {
        int p = i >> 6, n = i & 63;
        float v = Sl[(long)blk * 4096 + i];
        short hb = f2bs(v);
        S_hi[p][n] = hb;
        S_lo[p][n] = f2bs(v - bs2f(hb));
    }

    float csoff = 0.f;
    for (int tile = 0; tile < 4; ++tile) {
        const int t0 = tcs + tile * 64;
#pragma unroll
        for (int it = 0; it < 2; ++it) {
            int r = rr + it * 32;
            *(int4*)&C_s[r][sg8] =
                *(const int4*)&xc[(base + t0 + r) * (long)CONV_DIM + 1088 + sg8];
        }
        if (tid < 64) dt_l[tid] = dtv[((base + t0 + tid) << 4) + h];
        __syncthreads();

        if (wave == 0) {
            float d = dt_l[lane];
#pragma unroll
            for (int off = 1; off < 64; off <<= 1) {
                float u = __shfl_up(d, off);
                if (lane >= off) d += u;
            }
            cs_s[lane] = d;
        }
        __syncthreads();

        {
            const int tb = wave * 16;
            f32x4 acc[4];
#pragma unroll
            for (int pp = 0; pp < 4; ++pp) acc[pp] = f32x4{0.f, 0.f, 0.f, 0.f};
#pragma unroll
            for (int kst = 0; kst < 2; ++kst) {
                bf16x8 aC = *(const bf16x8*)&C_s[tb + l15][kst * 32 + quad * 8];
#pragma unroll
                for (int pp = 0; pp < 4; ++pp) {
                    bf16x8 wH = *(const bf16x8*)&S_hi[pp * 16 + l15][kst * 32 + quad * 8];
                    acc[pp] = __builtin_amdgcn_mfma_f32_16x16x32_bf16(aC, wH, acc[pp], 0, 0, 0);
                    bf16x8 wL = *(const bf16x8*)&S_lo[pp * 16 + l15][kst * 32 + quad * 8];
                    acc[pp] = __builtin_amdgcn_mfma_f32_16x16x32_bf16(aC, wL, acc[pp], 0, 0, 0);
                }
            }
#pragma unroll
            for (int r = 0; r < 4; ++r) {
                int t = tb + quad * 4 + r;
                float pt = expf(-aexp * (csoff + cs_s[t]));
#pragma unroll
                for (int pp = 0; pp < 4; ++pp)
                    ysb[t][pp * 16 + l15] = f2bs(acc[pp][r] * pt);
            }
        }
        __syncthreads();

        for (int i = tid; i < 512; i += 256) {
            int r = i >> 3, cc = (i & 7) * 8;
            bf16* yp = &y[(base + t0 + r) * 1024L + h * 64 + cc];
            int4 ov = *(int4*)yp;
            short* os = (short*)&ov;
            short nv[8];
#pragma unroll
            for (int j = 0; j < 8; ++j)
                nv[j] = f2bs(bs2f(os[j]) + bs2f(ysb[r][cc + j]));
            *(int4*)yp = *(int4*)nv;
        }
        csoff += cs_s[63];
        __syncthreads();
    }
}

// ---------------------------------------------------------------------------
// Gate: y' = (y [+ D*x]) * silu(z), then RMSNorm * norm_w, in-place on y.
// ---------------------------------------------------------------------------
template<bool ADDX>
__global__ __launch_bounds__(256)
void k_gate(bf16* __restrict__ yp, const bf16* __restrict__ zxp,
            const float* __restrict__ nw, const bf16* __restrict__ xcp,
            const float* __restrict__ Dp)
{
    long bt = blockIdx.x;
    bf16* y = yp + bt * 1024;
    const bf16* z = zxp + bt * (long)D_PROJ;
    int tid = threadIdx.x;
    ushort4 zv = *(const ushort4*)&z[tid * 4];
    ushort4 yv = *(const ushort4*)&y[tid * 4];
    float dx[4] = {0.f, 0.f, 0.f, 0.f};
    if (ADDX) {
        float Dv = Dp[tid >> 4];
        ushort4 xv = *(const ushort4*)&xcp[bt * (long)CONV_DIM + tid * 4];
        dx[0] = Dv * bs2f((short)xv.x);
        dx[1] = Dv * bs2f((short)xv.y);
        dx[2] = Dv * bs2f((short)xv.z);
        dx[3] = Dv * bs2f((short)xv.w);
    }
    float g[4], ss = 0.f;
    {
        float zz0 = bs2f((short)zv.x), zz1 = bs2f((short)zv.y);
        float zz2 = bs2f((short)zv.z), zz3 = bs2f((short)zv.w);
        float yy0 = bs2f((short)yv.x) + dx[0], yy1 = bs2f((short)yv.y) + dx[1];
        float yy2 = bs2f((short)yv.z) + dx[2], yy3 = bs2f((short)yv.w) + dx[3];
        g[0] = yy0 * (zz0 / (1.f + expf(-zz0)));
        g[1] = yy1 * (zz1 / (1.f + expf(-zz1)));
        g[2] = yy2 * (zz2 / (1.f + expf(-zz2)));
        g[3] = yy3 * (zz3 / (1.f + expf(-zz3)));
        ss = g[0]*g[0] + g[1]*g[1] + g[2]*g[2] + g[3]*g[3];
    }
#pragma unroll
    for (int o = 1; o < 64; o <<= 1) ss += __shfl_xor(ss, o);
    __shared__ float red[4];
    if ((tid & 63) == 0) red[tid >> 6] = ss;
    __syncthreads();
    float tot = red[0] + red[1] + red[2] + red[3];
    float sc = rsqrtf(tot * (1.f / 1024.f) + 1e-5f);
    const float* w = nw + tid * 4;
    ushort4 ov;
    ov.x = (unsigned short)f2bs(g[0] * sc * w[0]);
    ov.y = (unsigned short)f2bs(g[1] * sc * w[1]);
    ov.z = (unsigned short)f2bs(g[2] * sc * w[2]);
    ov.w = (unsigned short)f2bs(g[3] * sc * w[3]);
    *(ushort4*)&y[tid * 4] = ov;
}

// in-place flip via swaps: rows of 1024 bf16 (128 int4)
__global__ void k_swap(bf16* __restrict__ buf, const int* __restrict__ lens)
{
    int idx = blockIdx.x * 256 + threadIdx.x;
    int v = idx & 127;
    int r = idx >> 7;
    int b = r >> 10, t = r & 1023;
    int len = lens[b];
    int t2 = len - 1 - t;
    if (t < len && t < t2) {
        int4* p = (int4*)buf;
        long i1 = ((long)b * 2048 + t)  * 128 + v;
        long i2 = ((long)b * 2048 + t2) * 128 + v;
        int4 a = p[i1], c = p[i2];
        p[i1] = c; p[i2] = a;
    }
}

// LayerNorm(out + h) * g + b -> h (in place)
__global__ __launch_bounds__(256)
void k_ln(const bf16* __restrict__ outb, bf16* __restrict__ h,
          const float* __restrict__ g, const float* __restrict__ bb)
{
    long r = (long)blockIdx.x * 512;
    int tid = threadIdx.x;
    float v0 = B2F(outb[r + tid])       + B2F(h[r + tid]);
    float v1 = B2F(outb[r + tid + 256]) + B2F(h[r + tid + 256]);
    __shared__ float red[4], red2[4];
    float s = v0 + v1;
#pragma unroll
    for (int o = 1; o < 64; o <<= 1) s += __shfl_xor(s, o);
    if ((tid & 63) == 0) red[tid >> 6] = s;
    __syncthreads();
    float mu = (red[0] + red[1] + red[2] + red[3]) * (1.f / 512.f);
    float d0 = v0 - mu, d1 = v1 - mu;
    float q = d0 * d0 + d1 * d1;
#pragma unroll
    for (int o = 1; o < 64; o <<= 1) q += __shfl_xor(q, o);
    if ((tid & 63) == 0) red2[tid >> 6] = q;
    __syncthreads();
    float var = (red2[0] + red2[1] + red2[2] + red2[3]) * (1.f / 512.f);
    float rs = rsqrtf(var + 1e-5f);
    h[r + tid]       = F2B(d0 * rs * g[tid]       + bb[tid]);
    h[r + tid + 256] = F2B(d1 * rs * g[tid + 256] + bb[tid + 256]);
}

// masked-sum pooling partials
__global__ void k_pool(const float* __restrict__ enc, const int* __restrict__ lens,
                       float* __restrict__ pooled)
{
    int bid = blockIdx.x;
    int b = bid >> 6;
    int cg = (bid >> 4) & 3, tc = bid & 15;
    int c = cg * 256 + threadIdx.x;
    int len = lens[b];
    float s = 0.f;
    int tend = tc * 128 + 128;
    for (int t = tc * 128; t < tend; ++t)
        if (t < len) s += enc[((long)b * 2048 + t) * 1024 + c];
    atomicAdd(&pooled[b * 1024 + c], s);
}

// encoder_hidden = tanh(pooled/len @ W_ad^T + b_ad)
__global__ void k_adapter(const float* __restrict__ pooled, const float* __restrict__ Wad,
                          const float* __restrict__ bad, const int* __restrict__ lens,
                          float* __restrict__ outh)
{
    int idx = blockIdx.x * 256 + threadIdx.x;
    int b = idx >> 9, j = idx & 511;
    const float* wrow = Wad + (long)j * 1024;
    const float* prow = pooled + b * 1024;
    float acc = 0.f;
    for (int k = 0; k < 1024; ++k) acc += prow[k] * wrow[k];
    int li = lens[b]; if (li < 1) li = 1;
    acc = acc / (float)li + bad[j];
    outh[idx] = tanhf(acc);
}

// ---------------------------------------------------------------------------
static void gemm(const void* A, bool af32, const int* gather, const float* W,
                 const float* bias, void* C, bool cf32,
                 int M, int N, int K, int ldc, int coff, hipStream_t s)
{
    dim3 grid((N + 127) / 128, M / 128);
    if (af32) {
        if (cf32) k_gemm<true,  true ><<<grid, 256, 0, s>>>(A, gather, W, bias, C, M, N, K, ldc, coff);
        else      k_gemm<true,  false><<<grid, 256, 0, s>>>(A, gather, W, bias, C, M, N, K, ldc, coff);
    } else {
        if (cf32) k_gemm<false, true ><<<grid, 256, 0, s>>>(A, gather, W, bias, C, M, N, K, ldc, coff);
        else      k_gemm<false, false><<<grid, 256, 0, s>>>(A, gather, W, bias, C, M, N, K, ldc, coff);
    }
}

static void gemm_bf(const bf16* A, const int* gather, const bf16* Wb, const float* bias,
                    void* C, bool cf32, int M, int N, int K, int ldc, int coff, hipStream_t s)
{
    dim3 grid((N + 127) / 128, M / 128);
    if (cf32) k_gemm_bf<true ><<<grid, 256, 0, s>>>(A, gather, Wb, bias, C, M, N, K, ldc, coff);
    else      k_gemm_bf<false><<<grid, 256, 0, s>>>(A, gather, Wb, bias, C, M, N, K, ldc, coff);
}

extern "C" void kernel_launch(void* const* d_in, const int* in_sizes, int n_in,
                              void* d_out, int out_size, void* d_ws, size_t ws_size,
                              hipStream_t stream)
{
    const int*   tok    = (const int*)d_in[0];
    const int*   lens   = (const int*)d_in[1];
    const float* emb    = (const float*)d_in[2];
    const float* W_inp  = (const float*)d_in[3];
    const float* b_inp  = (const float*)d_in[4];
    const float* m_Win  = (const float*)d_in[5];
    const float* m_convw= (const float*)d_in[6];
    const float* m_convb= (const float*)d_in[7];
    const float* m_dtb  = (const float*)d_in[8];
    const float* m_Alog = (const float*)d_in[9];
    const float* m_D    = (const float*)d_in[10];
    const float* m_norm = (const float*)d_in[11];
    const float* m_Wout = (const float*)d_in[12];
    const float* blk_Wo = (const float*)d_in[13];
    const float* blk_bo = (const float*)d_in[14];
    const float* ln_g   = (const float*)d_in[15];
    const float* ln_b   = (const float*)d_in[16];
    const float* W_enc  = (const float*)d_in[17];
    const float* b_enc  = (const float*)d_in[18];
    const float* W_ad   = (const float*)d_in[19];
    const float* b_ad   = (const float*)d_in[20];

    char* ws = (char*)d_ws;
    bf16*  h      = (bf16*)(ws + OFF_H);
    bf16*  zx     = (bf16*)(ws + OFF_ZX);
    bf16*  xc     = (bf16*)(ws + OFF_XC);
    float* Sl     = (float*)(ws + OFF_S);
    float* Pc     = (float*)(ws + OFF_PC);
    float* dtv    = (float*)(ws + OFF_DTV);
    int*   gidx   = (int*)(ws + OFF_GIDX);
    float* pooled = (float*)(ws + OFF_POOL);

    float* dout   = (float*)d_out;
    bf16*  y_f    = (bf16*)d_out;                        // 33.55 MB
    bf16*  y_b    = (bf16*)d_out + (size_t)16384 * 1024; // next 33.55 MB
    bf16*  comb   = (bf16*)(ws + OFF_ZX);                // alias zx (dead after gates)
    bf16*  outbuf = (bf16*)(ws + OFF_XC);                // alias xc (dead after gates)

    // bf16 weight cache (fast GEMM path); fallback to legacy path if ws too small
    const bool fast  = ws_size >= (size_t)(OFF_WBF + WBF_BYTES);
    const bool fast2 = fast && ws_size >= (size_t)WS_NEED2;
    bf16* wWin  = fast ? (bf16*)(ws + OFF_WBF + WBF_WIN)  : nullptr;
    bf16* wWout = fast ? (bf16*)(ws + OFF_WBF + WBF_WOUT) : nullptr;
    bf16* wBlk  = fast ? (bf16*)(ws + OFF_WBF + WBF_BLK)  : nullptr;
    bf16* wEnc  = fast ? (bf16*)(ws + OFF_WBF + WBF_ENC)  : nullptr;
    bf16* xtg   = fast2 ? (bf16*)(ws + OFF_XT) : nullptr;
    bf16* btg   = fast2 ? (bf16*)(ws + OFF_BT) : nullptr;
    if (fast) {
        k_wcvt<<<(1122304 + 255) / 256, 256, 0, stream>>>(m_Win,  wWin,  1122304); // 8*2192*512/8
        k_wcvt<<<( 524288 + 255) / 256, 256, 0, stream>>>(m_Wout, wWout,  524288); // 8*512*1024/8
        k_wcvt<<<( 262144 + 255) / 256, 256, 0, stream>>>(blk_Wo, wBlk,   262144); // 4*512*1024/8
        k_wcvt<<<(  65536 + 255) / 256, 256, 0, stream>>>(W_enc,  wEnc,    65536); // 1024*512/8
    }

    k_mkidx<<<64, 256, 0, stream>>>(lens, gidx);

    // h = emb[tok] @ W_inp^T + b_inp   (f32 A + token gather: legacy path)
    gemm(emb, true, tok, W_inp, b_inp, h, false, 16384, 512, 512, 512, 0, stream);

    for (int l = 0; l < 4; ++l) {
        for (int dir = 0; dir < 2; ++dir) {
            const float* Wi = m_Win  + (size_t)(l * 2 + dir) * D_PROJ * 512;
            const float* cw = m_convw + (size_t)(l * 2 + dir) * CONV_DIM * 4;
            const float* cbp= m_convb + (size_t)(l * 2 + dir) * CONV_DIM;
            const float* dtb= m_dtb  + l * 32 + dir * 16;
            const float* alg= m_Alog + l * 32 + dir * 16;
            const float* Dpp= m_D    + l * 32 + dir * 16;
            const float* nw = m_norm + (size_t)(l * 2 + dir) * 1024;
            bf16* y = dir ? y_b : y_f;

            if (fast)
                gemm_bf(h, dir ? gidx : nullptr, wWin + (size_t)(l * 2 + dir) * D_PROJ * 512,
                        nullptr, zx, false, 16384, D_PROJ, 512, D_PROJ, 0, stream);
            else
                gemm(h, false, dir ? gidx : nullptr, Wi, nullptr, zx, false,
                     16384, D_PROJ, 512, D_PROJ, 0, stream);
            k_conv<<<576, 256, 0, stream>>>(zx, cw, cbp, xc);
            k_dt<<<1024, 256, 0, stream>>>(zx, dtb, dtv);
            if (fast2) {
                k_xt<<<4352, 256, 0, stream>>>(xc, xtg, btg);
                k_ph1<<<1024, 256, 0, stream>>>(xc, xtg, btg, dtv, alg, y, Sl, Pc);
            } else {
                k_ph1_fb<<<1024, 256, 0, stream>>>(xc, dtv, alg, Dpp, y, Sl, Pc);
            }
            k_comb<<<128, 256, 0, stream>>>(Sl, Pc);
            k_ph3<<<1024, 256, 0, stream>>>(Sl, xc, dtv, alg, y);
            if (fast2) k_gate<true ><<<16384, 256, 0, stream>>>(y, zx, nw, xc, Dpp);
            else       k_gate<false><<<16384, 256, 0, stream>>>(y, zx, nw, nullptr, nullptr);
            if (dir) k_swap<<<4096, 256, 0, stream>>>(y_b, lens);
        }

        // out-projections into comb halves (comb aliases dead zx)
        if (fast) {
            gemm_bf(y_f, nullptr, wWout + (size_t)(l * 2 + 0) * 512 * 1024, nullptr, comb,
                    false, 16384, 512, 1024, 1024, 0, stream);
            gemm_bf(y_b, nullptr, wWout + (size_t)(l * 2 + 1) * 512 * 1024, nullptr, comb,
                    false, 16384, 512, 1024, 1024, 512, stream);
            gemm_bf(comb, nullptr, wBlk + (size_t)l * 512 * 1024, blk_bo + l * 512, outbuf,
                    false, 16384, 512, 1024, 512, 0, stream);
        } else {
            gemm(y_f, false, nullptr, m_Wout + (size_t)(l * 2 + 0) * 512 * 1024, nullptr, comb,
                 false, 16384, 512, 1024, 1024, 0, stream);
            gemm(y_b, false, nullptr, m_Wout + (size_t)(l * 2 + 1) * 512 * 1024, nullptr, comb,
                 false, 16384, 512, 1024, 1024, 512, stream);
            gemm(comb, false, nullptr, blk_Wo + (size_t)l * 512 * 1024, blk_bo + l * 512, outbuf,
                 false, 16384, 512, 1024, 512, 0, stream);
        }
        // residual + layernorm -> h
        k_ln<<<16384, 256, 0, stream>>>(outbuf, h, ln_g + l * 512, ln_b + l * 512);
    }

    // encoder_outputs = h @ W_enc^T + b_enc -> d_out f32 (y_f/y_b dead)
    if (fast)
        gemm_bf(h, nullptr, wEnc, b_enc, dout, true, 16384, 1024, 512, 1024, 0, stream);
    else
        gemm(h, false, nullptr, W_enc, b_enc, dout, true, 16384, 1024, 512, 1024, 0, stream);

    hipMemsetAsync(pooled, 0, 8 * 1024 * sizeof(float), stream);
    k_pool<<<512, 256, 0, stream>>>(dout, lens, pooled);
    k_adapter<<<16, 256, 0, stream>>>(pooled, W_ad, b_ad, lens, dout + (size_t)16384 * 1024);
}